// Round 1
// baseline (1597.266 us; speedup 1.0000x reference)
//
#include <hip/hip_runtime.h>

#define LL 2048
#define BB 8
#define DD 1024
#define HH 4
#define HD 256

typedef __attribute__((ext_vector_type(8))) short short8;
typedef __attribute__((ext_vector_type(4))) float f32x4;

static __device__ __forceinline__ unsigned short f2bf(float f) {
    unsigned int u = __float_as_uint(f);
    unsigned int r = (u + 0x7fffu + ((u >> 16) & 1u)) >> 16;
    return (unsigned short)r;
}

static __device__ __forceinline__ float silu_f(float x) {
    return x / (1.0f + __expf(-x));
}

// ---------------- f32 -> bf16 convert (8 elems / thread) ----------------
__global__ __launch_bounds__(256) void cvt_bf16(const float* __restrict__ in,
                                                unsigned short* __restrict__ out, int n) {
    int i = (blockIdx.x * 256 + threadIdx.x) * 8;
    if (i >= n) return;
    float4 a = *(const float4*)(in + i);
    float4 b = *(const float4*)(in + i + 4);
    uint4 pk;
    pk.x = (unsigned int)f2bf(a.x) | ((unsigned int)f2bf(a.y) << 16);
    pk.y = (unsigned int)f2bf(a.z) | ((unsigned int)f2bf(a.w) << 16);
    pk.z = (unsigned int)f2bf(b.x) | ((unsigned int)f2bf(b.y) << 16);
    pk.w = (unsigned int)f2bf(b.z) | ((unsigned int)f2bf(b.w) << 16);
    *(uint4*)(out + i) = pk;
}

// ---------------- bf16 MFMA GEMM: C[m][n] = sum_k A[m][k] * W[n][k] ----------------
// A: [16384 x 1024] bf16 row-major, W: [1024 x 1024] bf16 row-major, C f32.
// Wave computes a 64x64 tile (4x4 of 16x16x32 MFMA). Block = 4 waves stacked in M.
// grid = (N/64, M/256). A/B fragments use the same (lane>>4)*8+j k-mapping, so any
// hardware k-permutation cancels. C/D: col=lane&15, row=(lane>>4)*4+reg.
__global__ __launch_bounds__(256) void gemm_bf16(const unsigned short* __restrict__ A,
                                                 const unsigned short* __restrict__ W,
                                                 float* __restrict__ C) {
    int wave = threadIdx.x >> 6;
    int lane = threadIdx.x & 63;
    int g = lane >> 4, c = lane & 15;
    int m0 = (blockIdx.y * 4 + wave) * 64;
    int n0 = blockIdx.x * 64;

    f32x4 acc[4][4];
#pragma unroll
    for (int i = 0; i < 4; i++)
#pragma unroll
        for (int j = 0; j < 4; j++) acc[i][j] = (f32x4){0.f, 0.f, 0.f, 0.f};

    const unsigned short* pa = A + (long)(m0 + c) * DD + g * 8;
    const unsigned short* pw = W + (long)(n0 + c) * DD + g * 8;

    for (int k0 = 0; k0 < DD; k0 += 32) {
        short8 a[4], b[4];
#pragma unroll
        for (int i = 0; i < 4; i++) a[i] = *(const short8*)(pa + (long)i * 16 * DD + k0);
#pragma unroll
        for (int j = 0; j < 4; j++) b[j] = *(const short8*)(pw + (long)j * 16 * DD + k0);
#pragma unroll
        for (int i = 0; i < 4; i++)
#pragma unroll
            for (int j = 0; j < 4; j++)
                acc[i][j] = __builtin_amdgcn_mfma_f32_16x16x32_bf16(a[i], b[j], acc[i][j], 0, 0, 0);
    }

#pragma unroll
    for (int i = 0; i < 4; i++)
#pragma unroll
        for (int j = 0; j < 4; j++)
#pragma unroll
            for (int r = 0; r < 4; r++)
                C[(long)(m0 + i * 16 + g * 4 + r) * DD + n0 + j * 16 + c] = acc[i][j][r];
}

// ---------------- causal depthwise conv (K=4) + silu + silu (+ per-head l2norm) ----------------
// block = 256 threads, one (b,l); thread t handles channels [4t, 4t+4); wave w == head w.
// lsel >= 0: grid = B blocks, process only l = lsel (used for the q tail, Lc=4).
template <bool NORM>
__global__ __launch_bounds__(256) void conv_silu(const float* __restrict__ in,
                                                 const float* __restrict__ cw,
                                                 float* __restrict__ out, int Lc, int lsel) {
    int b, l;
    if (lsel >= 0) { b = blockIdx.x; l = lsel; }
    else { b = blockIdx.x / Lc; l = blockIdx.x % Lc; }
    int t = threadIdx.x;
    int d = t * 4;

    float w0[4], w1[4], w2[4], w3[4];
    const float4* cw4 = (const float4*)cw;
    *(float4*)w0 = cw4[d + 0];
    *(float4*)w1 = cw4[d + 1];
    *(float4*)w2 = cw4[d + 2];
    *(float4*)w3 = cw4[d + 3];

    const float* base = in + (long)b * Lc * DD + d;
    float a0 = 0.f, a1 = 0.f, a2 = 0.f, a3 = 0.f;
#pragma unroll
    for (int j = 0; j < 4; j++) {
        int r = l - 3 + j;
        if (r >= 0) {
            float4 v = *(const float4*)(base + (long)r * DD);
            a0 += v.x * w0[j];
            a1 += v.y * w1[j];
            a2 += v.z * w2[j];
            a3 += v.w * w3[j];
        }
    }
    float y0 = silu_f(silu_f(a0));
    float y1 = silu_f(silu_f(a1));
    float y2 = silu_f(silu_f(a2));
    float y3 = silu_f(silu_f(a3));

    if (NORM) {
        float ss = y0 * y0 + y1 * y1 + y2 * y2 + y3 * y3;
#pragma unroll
        for (int m = 1; m < 64; m <<= 1) ss += __shfl_xor(ss, m);
        float nrm = sqrtf(ss);
        float sc = 1.0f / fmaxf(nrm, 1e-12f);
        y0 *= sc; y1 *= sc; y2 *= sc; y3 *= sc;
    }
    *(float4*)(out + ((long)b * Lc + l) * DD + d) = make_float4(y0, y1, y2, y3);
}

// ---------------- tiny q raw GEMM: Rq[m][n] = x[row(m)] . Wq[n], m = b*4+j, l = L-4+j ----------------
__global__ __launch_bounds__(256) void qraw_gemm(const float* __restrict__ x,
                                                 const float* __restrict__ Wq,
                                                 float* __restrict__ Rq) {
    int gid = blockIdx.x * 4 + (threadIdx.x >> 6);
    int lane = threadIdx.x & 63;
    int m = gid >> 10;  // 0..31
    int n = gid & 1023;
    int b = m >> 2, j = m & 3;
    int l = LL - 4 + j;
    const float* xr = x + ((long)b * LL + l) * DD + lane * 16;
    const float* wr = Wq + (long)n * DD + lane * 16;
    float s = 0.f;
#pragma unroll
    for (int u = 0; u < 4; u++) {
        float4 a = *(const float4*)(xr + u * 4);
        float4 w = *(const float4*)(wr + u * 4);
        s += a.x * w.x + a.y * w.y + a.z * w.z + a.w * w.w;
    }
#pragma unroll
    for (int mm = 1; mm < 64; mm <<= 1) s += __shfl_xor(s, mm);
    if (lane == 0) Rq[(long)m * DD + n] = s;
}

// ---------------- beta: sigmoid(x @ Wbeta.T), one wave per (b,l) ----------------
__global__ __launch_bounds__(64) void beta_kernel(const float* __restrict__ x,
                                                  const float* __restrict__ Wb,
                                                  float* __restrict__ beta) {
    int bl = blockIdx.x;
    int lane = threadIdx.x;
    const float* xr = x + (long)bl * DD + lane * 16;
    float4 xv[4];
#pragma unroll
    for (int u = 0; u < 4; u++) xv[u] = *(const float4*)(xr + u * 4);
#pragma unroll
    for (int h = 0; h < 4; h++) {
        const float* wr = Wb + (long)h * DD + lane * 16;
        float s = 0.f;
#pragma unroll
        for (int u = 0; u < 4; u++) {
            float4 w = *(const float4*)(wr + u * 4);
            s += xv[u].x * w.x + xv[u].y * w.y + xv[u].z * w.z + xv[u].w * w.w;
        }
#pragma unroll
        for (int m = 1; m < 64; m <<= 1) s += __shfl_xor(s, m);
        if (lane == 0) beta[(long)bl * HH + h] = 1.0f / (1.0f + __expf(-s));
    }
}

// ---------------- the scan: rows independent. wave = 4 rows, 16 lanes/row, 16 cols/lane ----------------
// grid = 32 (b,h) * 16 row-blocks; block = 256 threads (4 waves -> 16 rows).
__global__ __launch_bounds__(256) void scan_kernel(const float* __restrict__ Kn,
                                                   const float* __restrict__ Vn,
                                                   const float* __restrict__ beta,
                                                   const float* __restrict__ Qn,
                                                   float* __restrict__ out,
                                                   float* __restrict__ o_raw) {
    int bh = blockIdx.x >> 4;
    int rblk = blockIdx.x & 15;
    int b = bh >> 2, h = bh & 3;
    int wave = threadIdx.x >> 6, lane = threadIdx.x & 63;
    int g = lane >> 4, c = lane & 15;
    int row = rblk * 16 + wave * 4 + g;

    float s[16];
#pragma unroll
    for (int u = 0; u < 16; u++) s[u] = 0.f;

    const float* kp = Kn + (long)b * LL * DD + h * HD + c * 16;
    const float* vp = Vn + (long)b * LL * DD + h * HD + row;
    const float* bp = beta + (long)b * LL * HH + h;

#pragma unroll 2
    for (int t = 0; t < LL; t++) {
        float kv[16];
        *(float4*)(kv + 0)  = *(const float4*)(kp + 0);
        *(float4*)(kv + 4)  = *(const float4*)(kp + 4);
        *(float4*)(kv + 8)  = *(const float4*)(kp + 8);
        *(float4*)(kv + 12) = *(const float4*)(kp + 12);
        float vt = *vp;
        float bt = *bp;

        float d0 = 0.f, d1 = 0.f, d2 = 0.f, d3 = 0.f;
#pragma unroll
        for (int u = 0; u < 4; u++) {
            d0 += s[u] * kv[u];
            d1 += s[u + 4] * kv[u + 4];
            d2 += s[u + 8] * kv[u + 8];
            d3 += s[u + 12] * kv[u + 12];
        }
        float dot = (d0 + d1) + (d2 + d3);
        dot += __shfl_xor(dot, 1);
        dot += __shfl_xor(dot, 2);
        dot += __shfl_xor(dot, 4);
        dot += __shfl_xor(dot, 8);

        float delta = bt * (dot - vt);
#pragma unroll
        for (int u = 0; u < 16; u++) s[u] -= delta * kv[u];

        kp += DD; vp += DD; bp += HH;
    }

    // o_row = s . q_{L-1}
    const float* qp = Qn + ((long)b * 4 + 3) * DD + h * HD + c * 16;
    float qv[16];
    *(float4*)(qv + 0)  = *(const float4*)(qp + 0);
    *(float4*)(qv + 4)  = *(const float4*)(qp + 4);
    *(float4*)(qv + 8)  = *(const float4*)(qp + 8);
    *(float4*)(qv + 12) = *(const float4*)(qp + 12);
    float dq = 0.f;
#pragma unroll
    for (int u = 0; u < 16; u++) dq += s[u] * qv[u];
    dq += __shfl_xor(dq, 1);
    dq += __shfl_xor(dq, 2);
    dq += __shfl_xor(dq, 4);
    dq += __shfl_xor(dq, 8);
    if (c == 0) o_raw[(long)b * DD + h * HD + row] = dq;

    // S_final -> out (after the o slot of 8192 floats)
    float* so = out + 8192 + (((long)(b * HH + h) * HD + row) * HD) + c * 16;
    *(float4*)(so + 0)  = make_float4(s[0], s[1], s[2], s[3]);
    *(float4*)(so + 4)  = make_float4(s[4], s[5], s[6], s[7]);
    *(float4*)(so + 8)  = make_float4(s[8], s[9], s[10], s[11]);
    *(float4*)(so + 12) = make_float4(s[12], s[13], s[14], s[15]);
}

// ---------------- RMSNorm over D per batch ----------------
__global__ __launch_bounds__(256) void rmsnorm_kernel(const float* __restrict__ o_raw,
                                                      const float* __restrict__ w,
                                                      float* __restrict__ o_norm) {
    int b = blockIdx.x, t = threadIdx.x;
    float4 v = *(const float4*)(o_raw + (long)b * DD + t * 4);
    float ss = v.x * v.x + v.y * v.y + v.z * v.z + v.w * v.w;
#pragma unroll
    for (int m = 1; m < 64; m <<= 1) ss += __shfl_xor(ss, m);
    __shared__ float wsum[4];
    if ((t & 63) == 0) wsum[t >> 6] = ss;
    __syncthreads();
    float tot = wsum[0] + wsum[1] + wsum[2] + wsum[3];
    float sc = rsqrtf(tot / (float)DD + 1e-5f);
    float4 wv = *(const float4*)(w + t * 4);
    float4 r = make_float4(v.x * sc * wv.x, v.y * sc * wv.y, v.z * sc * wv.z, v.w * sc * wv.w);
    *(float4*)(o_norm + (long)b * DD + t * 4) = r;
}

// ---------------- out projection: out[b][n] = o_norm[b] . Wout[n], wave per (b,n) ----------------
__global__ __launch_bounds__(256) void outproj_kernel(const float* __restrict__ o_norm,
                                                      const float* __restrict__ Wout,
                                                      float* __restrict__ out) {
    int gid = blockIdx.x * 4 + (threadIdx.x >> 6);
    int lane = threadIdx.x & 63;
    int b = gid >> 10, n = gid & 1023;
    const float* orow = o_norm + (long)b * DD + lane * 16;
    const float* wrow = Wout + (long)n * DD + lane * 16;
    float s = 0.f;
#pragma unroll
    for (int u = 0; u < 4; u++) {
        float4 a = *(const float4*)(orow + u * 4);
        float4 w = *(const float4*)(wrow + u * 4);
        s += a.x * w.x + a.y * w.y + a.z * w.z + a.w * w.w;
    }
#pragma unroll
    for (int m = 1; m < 64; m <<= 1) s += __shfl_xor(s, m);
    if (lane == 0) out[(long)b * DD + n] = s;
}

extern "C" void kernel_launch(void* const* d_in, const int* in_sizes, int n_in,
                              void* d_out, int out_size, void* d_ws, size_t ws_size,
                              hipStream_t stream) {
    const float* x     = (const float*)d_in[0];
    const float* Wq    = (const float*)d_in[1];
    const float* Wk    = (const float*)d_in[2];
    const float* Wv    = (const float*)d_in[3];
    const float* cq    = (const float*)d_in[4];
    const float* ck    = (const float*)d_in[5];
    const float* cv    = (const float*)d_in[6];
    const float* Wbeta = (const float*)d_in[7];
    const float* rms_w = (const float*)d_in[8];
    const float* Wout  = (const float*)d_in[9];
    float* out = (float*)d_out;

    char* ws = (char*)d_ws;
    unsigned short* XB  = (unsigned short*)(ws + 0);          // 32 MB
    unsigned short* WKB = (unsigned short*)(ws + 33554432);   // 2 MB
    unsigned short* WVB = (unsigned short*)(ws + 35651584);   // 2 MB
    float* R    = (float*)(ws + 37748736);                    // 64 MB
    float* KN   = (float*)(ws + 104857600);                   // 64 MB
    float* VN   = (float*)(ws + 171966464);                   // 64 MB
    float* BETA = (float*)(ws + 239075328);                   // 256 KB
    float* RQ   = (float*)(ws + 239337472);                   // 128 KB
    float* QN   = (float*)(ws + 239468544);                   // 128 KB ([8][4][1024], only l=3 valid)
    float* ORAW = (float*)(ws + 239599616);                   // 32 KB
    float* ONRM = (float*)(ws + 239632384);                   // 32 KB

    // converts
    cvt_bf16<<<16777216 / 2048, 256, 0, stream>>>(x, XB, 16777216);
    cvt_bf16<<<1048576 / 2048, 256, 0, stream>>>(Wk, WKB, 1048576);
    cvt_bf16<<<1048576 / 2048, 256, 0, stream>>>(Wv, WVB, 1048576);

    dim3 gg(DD / 64, BB * LL / 256);  // (16, 64)

    // k path
    gemm_bf16<<<gg, 256, 0, stream>>>(XB, WKB, R);
    conv_silu<true><<<BB * LL, 256, 0, stream>>>(R, ck, KN, LL, -1);
    // v path
    gemm_bf16<<<gg, 256, 0, stream>>>(XB, WVB, R);
    conv_silu<false><<<BB * LL, 256, 0, stream>>>(R, cv, VN, LL, -1);
    // q tail (only t = L-1 needed)
    qraw_gemm<<<8192, 256, 0, stream>>>(x, Wq, RQ);
    conv_silu<true><<<BB, 256, 0, stream>>>(RQ, cq, QN, 4, 3);
    // beta
    beta_kernel<<<BB * LL, 64, 0, stream>>>(x, Wbeta, BETA);
    // the recurrence
    scan_kernel<<<32 * 16, 256, 0, stream>>>(KN, VN, BETA, QN, out, ORAW);
    // epilogue
    rmsnorm_kernel<<<BB, 256, 0, stream>>>(ORAW, rms_w, ONRM);
    outproj_kernel<<<2048, 256, 0, stream>>>(ONRM, Wout, out);
}

// Round 2
// 683.056 us; speedup vs baseline: 2.3384x; 2.3384x over previous
//
#include <hip/hip_runtime.h>

#define LL 2048
#define BB 8
#define DD 1024
#define HH 4
#define HD 256

#define AS1 __attribute__((address_space(1)))
#define AS3 __attribute__((address_space(3)))

typedef __attribute__((ext_vector_type(8))) short short8;
typedef __attribute__((ext_vector_type(4))) float f32x4;
typedef unsigned short u16;
typedef unsigned int u32;

static __device__ __forceinline__ u16 f2bf(float f) {
    u32 u = __float_as_uint(f);
    return (u16)((u + 0x7fffu + ((u >> 16) & 1u)) >> 16);
}
static __device__ __forceinline__ float bf2f(u16 v) {
    return __uint_as_float(((u32)v) << 16);
}
static __device__ __forceinline__ float silu_f(float x) { return x / (1.0f + __expf(-x)); }

static __device__ __forceinline__ short8 mk8(uint2 lo, uint2 hi) {
    union { short8 s; u32 u[4]; } r;
    r.u[0] = lo.x; r.u[1] = lo.y; r.u[2] = hi.x; r.u[3] = hi.y;
    return r.s;
}
static __device__ __forceinline__ short8 pk8(f32x4 a, f32x4 b) {
    union { short8 s; u32 u[4]; } r;
    r.u[0] = (u32)f2bf(a[0]) | ((u32)f2bf(a[1]) << 16);
    r.u[1] = (u32)f2bf(a[2]) | ((u32)f2bf(a[3]) << 16);
    r.u[2] = (u32)f2bf(b[0]) | ((u32)f2bf(b[1]) << 16);
    r.u[3] = (u32)f2bf(b[2]) | ((u32)f2bf(b[3]) << 16);
    return r.s;
}

// ---------------- f32 -> bf16 convert ----------------
__global__ __launch_bounds__(256) void cvt_bf16(const float* __restrict__ in,
                                                u16* __restrict__ out, int n) {
    int i = (blockIdx.x * 256 + threadIdx.x) * 8;
    if (i >= n) return;
    float4 a = *(const float4*)(in + i);
    float4 b = *(const float4*)(in + i + 4);
    uint4 pk;
    pk.x = (u32)f2bf(a.x) | ((u32)f2bf(a.y) << 16);
    pk.y = (u32)f2bf(a.z) | ((u32)f2bf(a.w) << 16);
    pk.z = (u32)f2bf(b.x) | ((u32)f2bf(b.y) << 16);
    pk.w = (u32)f2bf(b.z) | ((u32)f2bf(b.w) << 16);
    *(uint4*)(out + i) = pk;
}

// ---------------- bf16 MFMA GEMM: C[m][n] = sum_k A[m][k] * W[n][k] ----------------
__global__ __launch_bounds__(256) void gemm_bf16(const u16* __restrict__ A,
                                                 const u16* __restrict__ W,
                                                 float* __restrict__ C) {
    int wave = threadIdx.x >> 6;
    int lane = threadIdx.x & 63;
    int g = lane >> 4, c = lane & 15;
    int m0 = (blockIdx.y * 4 + wave) * 64;
    int n0 = blockIdx.x * 64;

    f32x4 acc[4][4];
#pragma unroll
    for (int i = 0; i < 4; i++)
#pragma unroll
        for (int j = 0; j < 4; j++) acc[i][j] = (f32x4){0.f, 0.f, 0.f, 0.f};

    const u16* pa = A + (long)(m0 + c) * DD + g * 8;
    const u16* pw = W + (long)(n0 + c) * DD + g * 8;

    for (int k0 = 0; k0 < DD; k0 += 32) {
        short8 a[4], b[4];
#pragma unroll
        for (int i = 0; i < 4; i++) a[i] = *(const short8*)(pa + (long)i * 16 * DD + k0);
#pragma unroll
        for (int j = 0; j < 4; j++) b[j] = *(const short8*)(pw + (long)j * 16 * DD + k0);
#pragma unroll
        for (int i = 0; i < 4; i++)
#pragma unroll
            for (int j = 0; j < 4; j++)
                acc[i][j] = __builtin_amdgcn_mfma_f32_16x16x32_bf16(a[i], b[j], acc[i][j], 0, 0, 0);
    }

#pragma unroll
    for (int i = 0; i < 4; i++)
#pragma unroll
        for (int j = 0; j < 4; j++)
#pragma unroll
            for (int r = 0; r < 4; r++)
                C[(long)(m0 + i * 16 + g * 4 + r) * DD + n0 + j * 16 + c] = acc[i][j][r];
}

// ---------------- causal depthwise conv (K=4) + silu + silu (+ per-head l2norm) ----------------
template <bool NORM>
__global__ __launch_bounds__(256) void conv_silu(const float* __restrict__ in,
                                                 const float* __restrict__ cw,
                                                 float* __restrict__ out, int Lc, int lsel) {
    int b, l;
    if (lsel >= 0) { b = blockIdx.x; l = lsel; }
    else { b = blockIdx.x / Lc; l = blockIdx.x % Lc; }
    int t = threadIdx.x;
    int d = t * 4;

    float w0[4], w1[4], w2[4], w3[4];
    const float4* cw4 = (const float4*)cw;
    *(float4*)w0 = cw4[d + 0];
    *(float4*)w1 = cw4[d + 1];
    *(float4*)w2 = cw4[d + 2];
    *(float4*)w3 = cw4[d + 3];

    const float* base = in + (long)b * Lc * DD + d;
    float a0 = 0.f, a1 = 0.f, a2 = 0.f, a3 = 0.f;
#pragma unroll
    for (int j = 0; j < 4; j++) {
        int r = l - 3 + j;
        if (r >= 0) {
            float4 v = *(const float4*)(base + (long)r * DD);
            a0 += v.x * w0[j];
            a1 += v.y * w1[j];
            a2 += v.z * w2[j];
            a3 += v.w * w3[j];
        }
    }
    float y0 = silu_f(silu_f(a0));
    float y1 = silu_f(silu_f(a1));
    float y2 = silu_f(silu_f(a2));
    float y3 = silu_f(silu_f(a3));

    if (NORM) {
        float ss = y0 * y0 + y1 * y1 + y2 * y2 + y3 * y3;
#pragma unroll
        for (int m = 1; m < 64; m <<= 1) ss += __shfl_xor(ss, m);
        float nrm = sqrtf(ss);
        float sc = 1.0f / fmaxf(nrm, 1e-12f);
        y0 *= sc; y1 *= sc; y2 *= sc; y3 *= sc;
    }
    *(float4*)(out + ((long)b * Lc + l) * DD + d) = make_float4(y0, y1, y2, y3);
}

// ---------------- tiny q raw GEMM (rows l = L-4..L-1 only) ----------------
__global__ __launch_bounds__(256) void qraw_gemm(const float* __restrict__ x,
                                                 const float* __restrict__ Wq,
                                                 float* __restrict__ Rq) {
    int gid = blockIdx.x * 4 + (threadIdx.x >> 6);
    int lane = threadIdx.x & 63;
    int m = gid >> 10;
    int n = gid & 1023;
    int b = m >> 2, j = m & 3;
    int l = LL - 4 + j;
    const float* xr = x + ((long)b * LL + l) * DD + lane * 16;
    const float* wr = Wq + (long)n * DD + lane * 16;
    float s = 0.f;
#pragma unroll
    for (int u = 0; u < 4; u++) {
        float4 a = *(const float4*)(xr + u * 4);
        float4 w = *(const float4*)(wr + u * 4);
        s += a.x * w.x + a.y * w.y + a.z * w.z + a.w * w.w;
    }
#pragma unroll
    for (int mm = 1; mm < 64; mm <<= 1) s += __shfl_xor(s, mm);
    if (lane == 0) Rq[(long)m * DD + n] = s;
}

// ---------------- beta ----------------
__global__ __launch_bounds__(64) void beta_kernel(const float* __restrict__ x,
                                                  const float* __restrict__ Wb,
                                                  float* __restrict__ beta) {
    int bl = blockIdx.x;
    int lane = threadIdx.x;
    const float* xr = x + (long)bl * DD + lane * 16;
    float4 xv[4];
#pragma unroll
    for (int u = 0; u < 4; u++) xv[u] = *(const float4*)(xr + u * 4);
#pragma unroll
    for (int h = 0; h < 4; h++) {
        const float* wr = Wb + (long)h * DD + lane * 16;
        float s = 0.f;
#pragma unroll
        for (int u = 0; u < 4; u++) {
            float4 w = *(const float4*)(wr + u * 4);
            s += xv[u].x * w.x + xv[u].y * w.y + xv[u].z * w.z + xv[u].w * w.w;
        }
#pragma unroll
        for (int m = 1; m < 64; m <<= 1) s += __shfl_xor(s, m);
        if (lane == 0) beta[(long)bl * HH + h] = 1.0f / (1.0f + __expf(-s));
    }
}

// ---------------- prep per (bh, chunk): Kb (swizzled bf16), BKT (b*K transposed,
// swizzled bf16), AIV = (I + tril(A diag(b)))^-1 (swizzled bf16) ----------------
__global__ __launch_bounds__(256) void prep_chunk(
    const float* __restrict__ KN, const float* __restrict__ BETA,
    u16* __restrict__ Kb_g, u16* __restrict__ BKT_g, u16* __restrict__ AIV_g)
{
    __shared__ __align__(16) u16 KL[16384];   // [64][256] col-blk8-swizzled
    __shared__ u16 WL[64 * 68];               // L coeffs bf16
    __shared__ float LI[64 * 65];             // Linv f32
    __shared__ float bv[64];
    const int bh = blockIdx.x >> 5, q = blockIdx.x & 31;
    const int b = bh >> 2, h = bh & 3;
    const int tid = threadIdx.x;
    const int w = tid >> 6, lane = tid & 63, g = lane >> 4, c = lane & 15;

    for (int t = 0; t < 64; t++) {
        float kv = KN[((long)b * LL + 64 * q + t) * DD + h * HD + tid];
        KL[t * 256 + ((((tid >> 2) ^ (t & 15)) << 2) | (tid & 3))] = f2bf(kv);
    }
    if (tid < 64) bv[tid] = BETA[((long)b * LL + 64 * q + tid) * HH + h];
    for (int ii = tid; ii < 4096; ii += 256) {
        int t = ii >> 6, s = ii & 63;
        LI[t * 65 + s] = (t == s) ? 1.0f : 0.0f;
    }
    __syncthreads();

    // copy swizzled K image to global (linear)
    {
        const uint4* srcp = (const uint4*)KL;
        uint4* dstp = (uint4*)(Kb_g + ((long)(bh * 32 + q)) * 16384);
#pragma unroll
        for (int i = 0; i < 8; i++) dstp[i * 256 + tid] = srcp[i * 256 + tid];
    }

    // A = K K^T (wave w computes rows [16w,16w+16))
    f32x4 aacc[4];
#pragma unroll
    for (int nt = 0; nt < 4; nt++) aacc[nt] = (f32x4){0.f, 0.f, 0.f, 0.f};
#pragma unroll
    for (int q8 = 0; q8 < 8; q8++) {
        short8 af;
        {
            const u16* rp = KL + (16 * w + c) * 256;
            uint2 lo = *(const uint2*)(rp + (((8 * q8 + g) ^ c) << 2));
            uint2 hi = *(const uint2*)(rp + (((8 * q8 + 4 + g) ^ c) << 2));
            af = mk8(lo, hi);
        }
#pragma unroll
        for (int nt = 0; nt < 4; nt++) {
            const u16* rp = KL + (16 * nt + c) * 256;
            uint2 lo = *(const uint2*)(rp + (((8 * q8 + g) ^ c) << 2));
            uint2 hi = *(const uint2*)(rp + (((8 * q8 + 4 + g) ^ c) << 2));
            aacc[nt] = __builtin_amdgcn_mfma_f32_16x16x32_bf16(af, mk8(lo, hi), aacc[nt], 0, 0, 0);
        }
    }
#pragma unroll
    for (int nt = 0; nt < 4; nt++)
#pragma unroll
        for (int r = 0; r < 4; r++)
            WL[(16 * w + 4 * g + r) * 68 + 16 * nt + c] = f2bf(aacc[nt][r] * bv[16 * nt + c]);
    __syncthreads();

    // forward substitution: columns are independent; wave w owns cols [16w,16w+16)
    {
        const int col = 16 * w + c;
        for (int t = 1; t < 64; t++) {
            float acc = 0.f;
            for (int s = g; s < t; s += 4)
                acc += bf2f(WL[t * 68 + s]) * LI[s * 65 + col];
            acc += __shfl_xor(acc, 16);
            acc += __shfl_xor(acc, 32);
            if (g == 0) LI[t * 65 + col] = ((t == col) ? 1.0f : 0.0f) - acc;
        }
    }
    __syncthreads();

    for (int ii = tid; ii < 4096; ii += 256) {
        int t = ii >> 6, s = ii & 63;
        AIV_g[((long)(bh * 32 + q)) * 4096 + t * 64 + ((((s >> 2) ^ (t & 15)) << 2) | (s & 3))] =
            f2bf(LI[t * 65 + s]);
    }
    // BKT[j][t] = b_t * K[t][j], transposed + swizzled; thread = j
    {
        const long rb = ((long)(bh * 32 + q) * 256 + tid) * 64;
#pragma unroll
        for (int tb = 0; tb < 16; tb++) {
            int t0 = 4 * tb;
            float v0 = bv[t0 + 0] * bf2f(KL[(t0 + 0) * 256 + ((((tid >> 2) ^ ((t0 + 0) & 15)) << 2) | (tid & 3))]);
            float v1 = bv[t0 + 1] * bf2f(KL[(t0 + 1) * 256 + ((((tid >> 2) ^ ((t0 + 1) & 15)) << 2) | (tid & 3))]);
            float v2 = bv[t0 + 2] * bf2f(KL[(t0 + 2) * 256 + ((((tid >> 2) ^ ((t0 + 2) & 15)) << 2) | (tid & 3))]);
            float v3 = bv[t0 + 3] * bf2f(KL[(t0 + 3) * 256 + ((((tid >> 2) ^ ((t0 + 3) & 15)) << 2) | (tid & 3))]);
            u32 p0 = (u32)f2bf(v0) | ((u32)f2bf(v1) << 16);
            u32 p1 = (u32)f2bf(v2) | ((u32)f2bf(v3) << 16);
            *(uint2*)(BKT_g + rb + ((tb ^ (tid & 15)) << 2)) = make_uint2(p0, p1);
        }
    }
}

// ---------------- chunked delta-rule scan: per chunk 3 MFMA GEMMs ----------------
// grid 256: bh = blk&31 (XCD locality), iblk = blk>>5 -> S rows [32*iblk, +32)
__global__ __launch_bounds__(256, 1) void scan_chunked(
    const float* __restrict__ VN, const float* __restrict__ QN,
    const u16* __restrict__ Kb_g, const u16* __restrict__ BKT_g,
    const u16* __restrict__ AIV_g, float* __restrict__ out,
    float* __restrict__ ORAW)
{
    __shared__ __align__(16) u16 smem[45056];   // Kb 16384 | BKT 16384 | AIV 4096 | TS 8192
    const int blk = blockIdx.x;
    const int bh = blk & 31, iblk = blk >> 5;
    const int b = bh >> 2, h = bh & 3;
    const int row0 = iblk * 32;
    const int tid = threadIdx.x;
    const int w = tid >> 6, lane = tid & 63, g = lane >> 4, c = lane & 15;

    u16* const KbL  = smem;
    u16* const BKTL = smem + 16384;
    u16* const AIVL = smem + 32768;
    u16* const TSL  = smem + 36864;

    f32x4 S[2][4];
#pragma unroll
    for (int si = 0; si < 2; si++)
#pragma unroll
        for (int sjl = 0; sjl < 4; sjl++) S[si][sjl] = (f32x4){0.f, 0.f, 0.f, 0.f};

    for (int q = 0; q < 32; ++q) {
        __syncthreads();   // prior chunk's LDS reads + TS writes complete
        // ---- stage K / BKT / AIV (pre-swizzled global -> linear LDS) ----
        {
            const long cb = (long)(bh * 32 + q);
            const char* gk = (const char*)(Kb_g + cb * 16384);
            const char* gt = (const char*)(BKT_g + cb * 16384);
            const char* ga = (const char*)(AIV_g + cb * 4096);
            const int wb = w * 8192 + lane * 16;
            const int wu = w * 8192;
#pragma unroll
            for (int i = 0; i < 8; i++) {
                __builtin_amdgcn_global_load_lds((const AS1 void*)(gk + wb + i * 1024),
                    (AS3 void*)((AS3 char*)(char*)smem + wu + i * 1024), 16, 0, 0);
                __builtin_amdgcn_global_load_lds((const AS1 void*)(gt + wb + i * 1024),
                    (AS3 void*)((AS3 char*)(char*)smem + 32768 + wu + i * 1024), 16, 0, 0);
            }
#pragma unroll
            for (int i = 0; i < 2; i++) {
                __builtin_amdgcn_global_load_lds((const AS1 void*)(ga + w * 2048 + lane * 16 + i * 1024),
                    (AS3 void*)((AS3 char*)(char*)smem + 65536 + w * 2048 + i * 1024), 16, 0, 0);
            }
        }
        // ---- V prefetch in C/D layout positions ----
        float vv[4][2][4];
#pragma unroll
        for (int mt = 0; mt < 4; mt++)
#pragma unroll
            for (int it = 0; it < 2; it++)
#pragma unroll
                for (int r = 0; r < 4; r++)
                    vv[mt][it][r] = VN[((long)b * LL + 64 * q + 16 * mt + 4 * g + r) * DD
                                       + h * HD + row0 + 16 * it + c];
        __syncthreads();   // staging complete

        // ---- GEMM1: G = K * S^T  (S read from TS; skip at q==0) ----
        f32x4 gacc[4][2];
#pragma unroll
        for (int mt = 0; mt < 4; mt++)
#pragma unroll
            for (int it = 0; it < 2; it++) gacc[mt][it] = (f32x4){0.f, 0.f, 0.f, 0.f};
        if (q > 0) {
#pragma unroll
            for (int q8 = 0; q8 < 8; q8++) {
                short8 af[4], bfr[2];
#pragma unroll
                for (int mt = 0; mt < 4; mt++) {
                    const u16* rp = KbL + (16 * mt + c) * 256;
                    uint2 lo = *(const uint2*)(rp + (((8 * q8 + g) ^ c) << 2));
                    uint2 hi = *(const uint2*)(rp + (((8 * q8 + 4 + g) ^ c) << 2));
                    af[mt] = mk8(lo, hi);
                }
#pragma unroll
                for (int it = 0; it < 2; it++) {
                    const u16* rp = TSL + (16 * it + c) * 256;
                    uint2 lo = *(const uint2*)(rp + (((8 * q8 + g) ^ c) << 2));
                    uint2 hi = *(const uint2*)(rp + (((8 * q8 + 4 + g) ^ c) << 2));
                    bfr[it] = mk8(lo, hi);
                }
#pragma unroll
                for (int mt = 0; mt < 4; mt++)
#pragma unroll
                    for (int it = 0; it < 2; it++)
                        gacc[mt][it] = __builtin_amdgcn_mfma_f32_16x16x32_bf16(af[mt], bfr[it], gacc[mt][it], 0, 0, 0);
            }
        }
        __syncthreads();   // all waves done reading TS; safe to overwrite below

        // RHS = G - V, packed straight from C/D regs as GEMM2 B-operand
#pragma unroll
        for (int mt = 0; mt < 4; mt++)
#pragma unroll
            for (int it = 0; it < 2; it++)
#pragma unroll
                for (int r = 0; r < 4; r++) gacc[mt][it][r] -= vv[mt][it][r];

        short8 b2[2][2];
#pragma unroll
        for (int Q = 0; Q < 2; Q++)
#pragma unroll
            for (int it = 0; it < 2; it++) b2[Q][it] = pk8(gacc[2 * Q][it], gacc[2 * Q + 1][it]);

        // ---- GEMM2: U = Linv * RHS ----
        f32x4 uacc[4][2];
#pragma unroll
        for (int mt = 0; mt < 4; mt++)
#pragma unroll
            for (int it = 0; it < 2; it++) uacc[mt][it] = (f32x4){0.f, 0.f, 0.f, 0.f};
#pragma unroll
        for (int Q = 0; Q < 2; Q++) {
            short8 av[4];
#pragma unroll
            for (int mt = 0; mt < 4; mt++) {
                const u16* rp = AIVL + (16 * mt + c) * 64;
                uint2 lo = *(const uint2*)(rp + (((8 * Q + g) ^ c) << 2));
                uint2 hi = *(const uint2*)(rp + (((8 * Q + 4 + g) ^ c) << 2));
                av[mt] = mk8(lo, hi);
            }
#pragma unroll
            for (int mt = 0; mt < 4; mt++)
#pragma unroll
                for (int it = 0; it < 2; it++)
                    uacc[mt][it] = __builtin_amdgcn_mfma_f32_16x16x32_bf16(av[mt], b2[Q][it], uacc[mt][it], 0, 0, 0);
        }

        short8 a3[2][2];
#pragma unroll
        for (int Qp = 0; Qp < 2; Qp++)
#pragma unroll
            for (int it = 0; it < 2; it++) a3[Qp][it] = pk8(-uacc[2 * Qp][it], -uacc[2 * Qp + 1][it]);

        // ---- GEMM3: S += (-U)^T * (b K)  (wave w owns cols [64w, 64w+64)) ----
#pragma unroll
        for (int Qp = 0; Qp < 2; Qp++) {
            short8 bk[4];
#pragma unroll
            for (int sjl = 0; sjl < 4; sjl++) {
                const u16* rp = BKTL + (64 * w + 16 * sjl + c) * 64;
                uint2 lo = *(const uint2*)(rp + (((8 * Qp + g) ^ c) << 2));
                uint2 hi = *(const uint2*)(rp + (((8 * Qp + 4 + g) ^ c) << 2));
                bk[sjl] = mk8(lo, hi);
            }
#pragma unroll
            for (int si = 0; si < 2; si++)
#pragma unroll
                for (int sjl = 0; sjl < 4; sjl++)
                    S[si][sjl] = __builtin_amdgcn_mfma_f32_16x16x32_bf16(a3[Qp][si], bk[sjl], S[si][sjl], 0, 0, 0);
        }

        // ---- write S as bf16 to TS (row-major, col-blk8 ^ (row&15) swizzle) ----
        if (q < 31) {
#pragma unroll
            for (int si = 0; si < 2; si++)
#pragma unroll
                for (int sjl = 0; sjl < 4; sjl++) {
                    const int jb = 16 * w + 4 * sjl + (c >> 2);
                    const int jo = c & 3;
#pragma unroll
                    for (int r = 0; r < 4; r++) {
                        const int i = 16 * si + 4 * g + r;
                        TSL[i * 256 + ((jb ^ (4 * g + r)) << 2) + jo] = f2bf(S[si][sjl][r]);
                    }
                }
        }
    }

    // ---- epilogue: o = S_final q, and S_final out ----
    float op[2][4];
#pragma unroll
    for (int si = 0; si < 2; si++)
#pragma unroll
        for (int r = 0; r < 4; r++) op[si][r] = 0.f;
#pragma unroll
    for (int sjl = 0; sjl < 4; sjl++) {
        const float qv = QN[((long)b * 4 + 3) * DD + h * HD + 64 * w + 16 * sjl + c];
#pragma unroll
        for (int si = 0; si < 2; si++)
#pragma unroll
            for (int r = 0; r < 4; r++) op[si][r] += S[si][sjl][r] * qv;
    }
#pragma unroll
    for (int si = 0; si < 2; si++)
#pragma unroll
        for (int r = 0; r < 4; r++) {
            float v = op[si][r];
            v += __shfl_xor(v, 1); v += __shfl_xor(v, 2);
            v += __shfl_xor(v, 4); v += __shfl_xor(v, 8);
            op[si][r] = v;
        }
    __syncthreads();
    float* red = (float*)smem;
    if (c == 0) {
#pragma unroll
        for (int si = 0; si < 2; si++)
#pragma unroll
            for (int r = 0; r < 4; r++) red[w * 32 + 16 * si + 4 * g + r] = op[si][r];
    }
    __syncthreads();
    if (tid < 32) {
        float o = red[tid] + red[32 + tid] + red[64 + tid] + red[96 + tid];
        ORAW[(long)b * DD + h * HD + row0 + tid] = o;
    }
#pragma unroll
    for (int si = 0; si < 2; si++)
#pragma unroll
        for (int sjl = 0; sjl < 4; sjl++)
#pragma unroll
            for (int r = 0; r < 4; r++)
                out[8192 + ((long)(bh * 256 + row0 + 16 * si + 4 * g + r)) * 256
                    + 64 * w + 16 * sjl + c] = S[si][sjl][r];
}

// ---------------- RMSNorm ----------------
__global__ __launch_bounds__(256) void rmsnorm_kernel(const float* __restrict__ o_raw,
                                                      const float* __restrict__ w,
                                                      float* __restrict__ o_norm) {
    int b = blockIdx.x, t = threadIdx.x;
    float4 v = *(const float4*)(o_raw + (long)b * DD + t * 4);
    float ss = v.x * v.x + v.y * v.y + v.z * v.z + v.w * v.w;
#pragma unroll
    for (int m = 1; m < 64; m <<= 1) ss += __shfl_xor(ss, m);
    __shared__ float wsum[4];
    if ((t & 63) == 0) wsum[t >> 6] = ss;
    __syncthreads();
    float tot = wsum[0] + wsum[1] + wsum[2] + wsum[3];
    float sc = rsqrtf(tot / (float)DD + 1e-5f);
    float4 wv = *(const float4*)(w + t * 4);
    float4 r = make_float4(v.x * sc * wv.x, v.y * sc * wv.y, v.z * sc * wv.z, v.w * sc * wv.w);
    *(float4*)(o_norm + (long)b * DD + t * 4) = r;
}

// ---------------- out projection ----------------
__global__ __launch_bounds__(256) void outproj_kernel(const float* __restrict__ o_norm,
                                                      const float* __restrict__ Wout,
                                                      float* __restrict__ out) {
    int gid = blockIdx.x * 4 + (threadIdx.x >> 6);
    int lane = threadIdx.x & 63;
    int b = gid >> 10, n = gid & 1023;
    const float* orow = o_norm + (long)b * DD + lane * 16;
    const float* wrow = Wout + (long)n * DD + lane * 16;
    float s = 0.f;
#pragma unroll
    for (int u = 0; u < 4; u++) {
        float4 a = *(const float4*)(orow + u * 4);
        float4 w = *(const float4*)(wrow + u * 4);
        s += a.x * w.x + a.y * w.y + a.z * w.z + a.w * w.w;
    }
#pragma unroll
    for (int m = 1; m < 64; m <<= 1) s += __shfl_xor(s, m);
    if (lane == 0) out[(long)b * DD + n] = s;
}

extern "C" void kernel_launch(void* const* d_in, const int* in_sizes, int n_in,
                              void* d_out, int out_size, void* d_ws, size_t ws_size,
                              hipStream_t stream) {
    const float* x     = (const float*)d_in[0];
    const float* Wq    = (const float*)d_in[1];
    const float* Wk    = (const float*)d_in[2];
    const float* Wv    = (const float*)d_in[3];
    const float* cq    = (const float*)d_in[4];
    const float* ck    = (const float*)d_in[5];
    const float* cv    = (const float*)d_in[6];
    const float* Wbeta = (const float*)d_in[7];
    const float* rms_w = (const float*)d_in[8];
    const float* Wout  = (const float*)d_in[9];
    float* out = (float*)d_out;

    char* ws = (char*)d_ws;
    u16* XB     = (u16*)(ws + 0);              // 32 MB (dead after gemms)
    u16* WKB    = (u16*)(ws + 33554432);
    u16* WVB    = (u16*)(ws + 35651584);
    float* R    = (float*)(ws + 37748736);     // 64 MB (dead after convs)
    u16* Kb_g   = (u16*)(ws + 37748736);       // overlays R: 32 MB
    u16* BKT_g  = (u16*)(ws + 71303168);       // overlays R: 32 MB
    float* KN   = (float*)(ws + 104857600);
    float* VN   = (float*)(ws + 171966464);
    float* BETA = (float*)(ws + 239075328);
    float* RQ   = (float*)(ws + 239337472);
    float* QN   = (float*)(ws + 239468544);
    float* ORAW = (float*)(ws + 239599616);
    float* ONRM = (float*)(ws + 239632384);
    u16* AIV_g  = (u16*)(ws + 0);              // overlays XB (dead by prep time): 8 MB

    cvt_bf16<<<8192, 256, 0, stream>>>(x, XB, 16777216);
    cvt_bf16<<<512, 256, 0, stream>>>(Wk, WKB, 1048576);
    cvt_bf16<<<512, 256, 0, stream>>>(Wv, WVB, 1048576);

    dim3 gg(DD / 64, BB * LL / 256);

    gemm_bf16<<<gg, 256, 0, stream>>>(XB, WKB, R);
    conv_silu<true><<<BB * LL, 256, 0, stream>>>(R, ck, KN, LL, -1);
    gemm_bf16<<<gg, 256, 0, stream>>>(XB, WVB, R);
    conv_silu<false><<<BB * LL, 256, 0, stream>>>(R, cv, VN, LL, -1);
    qraw_gemm<<<8192, 256, 0, stream>>>(x, Wq, RQ);
    conv_silu<true><<<BB, 256, 0, stream>>>(RQ, cq, QN, 4, 3);
    beta_kernel<<<BB * LL, 64, 0, stream>>>(x, Wbeta, BETA);

    prep_chunk<<<1024, 256, 0, stream>>>(KN, BETA, Kb_g, BKT_g, AIV_g);
    scan_chunked<<<256, 256, 0, stream>>>(VN, QN, Kb_g, BKT_g, AIV_g, out, ORAW);

    rmsnorm_kernel<<<BB, 256, 0, stream>>>(ORAW, rms_w, ONRM);
    outproj_kernel<<<2048, 256, 0, stream>>>(ONRM, Wout, out);
}

// Round 3
// 506.557 us; speedup vs baseline: 3.1532x; 1.3484x over previous
//
#include <hip/hip_runtime.h>

#define LL 2048
#define BB 8
#define DD 1024
#define HH 4
#define HD 256

#define AS1 __attribute__((address_space(1)))
#define AS3 __attribute__((address_space(3)))

typedef __attribute__((ext_vector_type(8))) short short8;
typedef __attribute__((ext_vector_type(4))) float f32x4;
typedef unsigned short u16;
typedef unsigned int u32;

static __device__ __forceinline__ u16 f2bf(float f) {
    u32 u = __float_as_uint(f);
    return (u16)((u + 0x7fffu + ((u >> 16) & 1u)) >> 16);
}
static __device__ __forceinline__ float bf2f(u16 v) {
    return __uint_as_float(((u32)v) << 16);
}
static __device__ __forceinline__ float silu_f(float x) { return x / (1.0f + __expf(-x)); }

static __device__ __forceinline__ short8 mk8(uint2 lo, uint2 hi) {
    union { short8 s; u32 u[4]; } r;
    r.u[0] = lo.x; r.u[1] = lo.y; r.u[2] = hi.x; r.u[3] = hi.y;
    return r.s;
}
static __device__ __forceinline__ short8 pk8(f32x4 a, f32x4 b) {
    union { short8 s; u32 u[4]; } r;
    r.u[0] = (u32)f2bf(a[0]) | ((u32)f2bf(a[1]) << 16);
    r.u[1] = (u32)f2bf(a[2]) | ((u32)f2bf(a[3]) << 16);
    r.u[2] = (u32)f2bf(b[0]) | ((u32)f2bf(b[1]) << 16);
    r.u[3] = (u32)f2bf(b[2]) | ((u32)f2bf(b[3]) << 16);
    return r.s;
}

// ---------------- f32 -> bf16 convert ----------------
__global__ __launch_bounds__(256) void cvt_bf16(const float* __restrict__ in,
                                                u16* __restrict__ out, int n) {
    int i = (blockIdx.x * 256 + threadIdx.x) * 8;
    if (i >= n) return;
    float4 a = *(const float4*)(in + i);
    float4 b = *(const float4*)(in + i + 4);
    uint4 pk;
    pk.x = (u32)f2bf(a.x) | ((u32)f2bf(a.y) << 16);
    pk.y = (u32)f2bf(a.z) | ((u32)f2bf(a.w) << 16);
    pk.z = (u32)f2bf(b.x) | ((u32)f2bf(b.y) << 16);
    pk.w = (u32)f2bf(b.z) | ((u32)f2bf(b.w) << 16);
    *(uint4*)(out + i) = pk;
}

// ---------------- m97-style 128x128 LDS GEMM, bf16 in, bf16 out ----------------
// C[m][n] = sum_k A[m][k] * W[n][k]; A [16384x1024], W [1024x1024] row-major bf16.
// 2-phase global_load_lds pipeline; XOR-swizzled via pre-swizzled SOURCE addresses
// (linear LDS dest); swizzled ds_read_b128 fragment reads.
__global__ __launch_bounds__(256, 2) void gemm_bf16(const u16* __restrict__ A,
                                                    const u16* __restrict__ W,
                                                    u16* __restrict__ C) {
    __shared__ __align__(16) u16 sm[32768];  // 64 KB: 2 bufs x (A 16KB + B 16KB)
    const int tid = threadIdx.x;
    const int w = tid >> 6, lane = tid & 63, g = lane >> 4, c = lane & 15;
    const int m0 = blockIdx.y * 128, n0 = blockIdx.x * 128;
    const int wm = (w >> 1) * 64, wn = (w & 1) * 64;

    f32x4 acc[4][4];
#pragma unroll
    for (int i = 0; i < 4; i++)
#pragma unroll
        for (int j = 0; j < 4; j++) acc[i][j] = (f32x4){0.f, 0.f, 0.f, 0.f};

    const int sr = tid >> 3;         // stripe row 0..31
    const int cb = (tid & 7) * 16;   // col byte 0..112

#define GLDSG(gp, lofs) __builtin_amdgcn_global_load_lds((const AS1 void*)(gp), \
        (AS3 void*)((AS3 char*)(char*)sm + (lofs)), 16, 0, 0)

#define GSTAGE(kt, bi)                                                        \
    {                                                                         \
        const char* ab = (const char*)(A + (long)m0 * DD + (kt) * 64);        \
        const char* wb = (const char*)(W + (long)n0 * DD + (kt) * 64);        \
        _Pragma("unroll")                                                     \
        for (int i = 0; i < 4; i++) {                                         \
            int r = i * 32 + sr;                                              \
            int so = r * 2048 + (cb ^ ((r & 7) << 4));                        \
            int dof = (bi) * 32768 + i * 4096 + tid * 16;                     \
            GLDSG(ab + so, dof);                                              \
            GLDSG(wb + so, dof + 16384);                                      \
        }                                                                     \
    }

    GSTAGE(0, 0);
    __syncthreads();

    const int sw = (c & 7) << 4;
    for (int kt = 0; kt < 16; kt++) {
        const int bi = kt & 1;
        if (kt < 15) GSTAGE(kt + 1, bi ^ 1);
        const int ba = bi * 32768;
#pragma unroll
        for (int ks = 0; ks < 2; ks++) {
            short8 av[4], bvv[4];
#pragma unroll
            for (int mt = 0; mt < 4; mt++)
                av[mt] = *(const short8*)((const char*)sm + ba +
                         (wm + 16 * mt + c) * 128 + ((ks * 64 + g * 16) ^ sw));
#pragma unroll
            for (int nt = 0; nt < 4; nt++)
                bvv[nt] = *(const short8*)((const char*)sm + ba + 16384 +
                          (wn + 16 * nt + c) * 128 + ((ks * 64 + g * 16) ^ sw));
#pragma unroll
            for (int mt = 0; mt < 4; mt++)
#pragma unroll
                for (int nt = 0; nt < 4; nt++)
                    acc[mt][nt] = __builtin_amdgcn_mfma_f32_16x16x32_bf16(av[mt], bvv[nt], acc[mt][nt], 0, 0, 0);
        }
        __syncthreads();
    }

#pragma unroll
    for (int mt = 0; mt < 4; mt++)
#pragma unroll
        for (int nt = 0; nt < 4; nt++)
#pragma unroll
            for (int r = 0; r < 4; r++)
                C[(long)(m0 + wm + 16 * mt + 4 * g + r) * DD + n0 + wn + 16 * nt + c] =
                    f2bf(acc[mt][nt][r]);
#undef GSTAGE
#undef GLDSG
}

// ---------------- causal depthwise conv (K=4) + silu + silu (+ l2norm), bf16 io ----------------
template <bool NORM>
__global__ __launch_bounds__(256) void conv_silu(const u16* __restrict__ in,
                                                 const float* __restrict__ cw,
                                                 u16* __restrict__ out, int Lc, int lsel) {
    int b, l;
    if (lsel >= 0) { b = blockIdx.x; l = lsel; }
    else { b = blockIdx.x / Lc; l = blockIdx.x % Lc; }
    int t = threadIdx.x;
    int d = t * 4;

    float w0[4], w1[4], w2[4], w3[4];
    const float4* cw4 = (const float4*)cw;
    *(float4*)w0 = cw4[d + 0];
    *(float4*)w1 = cw4[d + 1];
    *(float4*)w2 = cw4[d + 2];
    *(float4*)w3 = cw4[d + 3];

    const u16* base = in + (long)b * Lc * DD + d;
    float a0 = 0.f, a1 = 0.f, a2 = 0.f, a3 = 0.f;
#pragma unroll
    for (int j = 0; j < 4; j++) {
        int r = l - 3 + j;
        if (r >= 0) {
            uint2 v = *(const uint2*)(base + (long)r * DD);
            a0 += bf2f((u16)(v.x & 0xffff)) * w0[j];
            a1 += bf2f((u16)(v.x >> 16)) * w1[j];
            a2 += bf2f((u16)(v.y & 0xffff)) * w2[j];
            a3 += bf2f((u16)(v.y >> 16)) * w3[j];
        }
    }
    float y0 = silu_f(silu_f(a0));
    float y1 = silu_f(silu_f(a1));
    float y2 = silu_f(silu_f(a2));
    float y3 = silu_f(silu_f(a3));

    if (NORM) {
        float ss = y0 * y0 + y1 * y1 + y2 * y2 + y3 * y3;
#pragma unroll
        for (int m = 1; m < 64; m <<= 1) ss += __shfl_xor(ss, m);
        float nrm = sqrtf(ss);
        float sc = 1.0f / fmaxf(nrm, 1e-12f);
        y0 *= sc; y1 *= sc; y2 *= sc; y3 *= sc;
    }
    uint2 o;
    o.x = (u32)f2bf(y0) | ((u32)f2bf(y1) << 16);
    o.y = (u32)f2bf(y2) | ((u32)f2bf(y3) << 16);
    *(uint2*)(out + ((long)b * Lc + l) * DD + d) = o;
}

// ---------------- tiny q raw GEMM (rows l = L-4..L-1 only), bf16 out ----------------
__global__ __launch_bounds__(256) void qraw_gemm(const float* __restrict__ x,
                                                 const float* __restrict__ Wq,
                                                 u16* __restrict__ Rq) {
    int gid = blockIdx.x * 4 + (threadIdx.x >> 6);
    int lane = threadIdx.x & 63;
    int m = gid >> 10;
    int n = gid & 1023;
    int b = m >> 2, j = m & 3;
    int l = LL - 4 + j;
    const float* xr = x + ((long)b * LL + l) * DD + lane * 16;
    const float* wr = Wq + (long)n * DD + lane * 16;
    float s = 0.f;
#pragma unroll
    for (int u = 0; u < 4; u++) {
        float4 a = *(const float4*)(xr + u * 4);
        float4 w = *(const float4*)(wr + u * 4);
        s += a.x * w.x + a.y * w.y + a.z * w.z + a.w * w.w;
    }
#pragma unroll
    for (int mm = 1; mm < 64; mm <<= 1) s += __shfl_xor(s, mm);
    if (lane == 0) Rq[(long)m * DD + n] = f2bf(s);
}

// ---------------- beta ----------------
__global__ __launch_bounds__(64) void beta_kernel(const float* __restrict__ x,
                                                  const float* __restrict__ Wb,
                                                  float* __restrict__ beta) {
    int bl = blockIdx.x;
    int lane = threadIdx.x;
    const float* xr = x + (long)bl * DD + lane * 16;
    float4 xv[4];
#pragma unroll
    for (int u = 0; u < 4; u++) xv[u] = *(const float4*)(xr + u * 4);
#pragma unroll
    for (int h = 0; h < 4; h++) {
        const float* wr = Wb + (long)h * DD + lane * 16;
        float s = 0.f;
#pragma unroll
        for (int u = 0; u < 4; u++) {
            float4 w = *(const float4*)(wr + u * 4);
            s += xv[u].x * w.x + xv[u].y * w.y + xv[u].z * w.z + xv[u].w * w.w;
        }
#pragma unroll
        for (int m = 1; m < 64; m <<= 1) s += __shfl_xor(s, m);
        if (lane == 0) beta[(long)bl * HH + h] = 1.0f / (1.0f + __expf(-s));
    }
}

// ---------------- prep per (bh, chunk): Kb, BKT, AIV (all swizzled bf16 images) ----------------
__global__ __launch_bounds__(256) void prep_chunk(
    const u16* __restrict__ KN, const float* __restrict__ BETA,
    u16* __restrict__ Kb_g, u16* __restrict__ BKT_g, u16* __restrict__ AIV_g)
{
    __shared__ __align__(16) u16 KL[16384];   // [64][256] col-blk8-swizzled
    __shared__ u16 WL[64 * 68];
    __shared__ float LI[64 * 65];
    __shared__ float bv[64];
    const int bh = blockIdx.x >> 5, q = blockIdx.x & 31;
    const int b = bh >> 2, h = bh & 3;
    const int tid = threadIdx.x;
    const int w = tid >> 6, lane = tid & 63, g = lane >> 4, c = lane & 15;

#pragma unroll
    for (int i = 0; i < 8; i++) {
        int t = i * 8 + (tid >> 5);
        int d0 = (tid & 31) * 8;
        uint4 kv = *(const uint4*)(KN + ((long)b * LL + 64 * q + t) * DD + h * HD + d0);
        int s0 = (((d0 >> 2) ^ (t & 15)) << 2);
        int s1 = ((((d0 >> 2) + 1) ^ (t & 15)) << 2);
        *(uint2*)&KL[t * 256 + s0] = make_uint2(kv.x, kv.y);
        *(uint2*)&KL[t * 256 + s1] = make_uint2(kv.z, kv.w);
    }
    if (tid < 64) bv[tid] = BETA[((long)b * LL + 64 * q + tid) * HH + h];
    for (int ii = tid; ii < 4096; ii += 256) {
        int t = ii >> 6, s = ii & 63;
        LI[t * 65 + s] = (t == s) ? 1.0f : 0.0f;
    }
    __syncthreads();

    // copy swizzled K image to global (linear)
    {
        const uint4* srcp = (const uint4*)KL;
        uint4* dstp = (uint4*)(Kb_g + ((long)(bh * 32 + q)) * 16384);
#pragma unroll
        for (int i = 0; i < 8; i++) dstp[i * 256 + tid] = srcp[i * 256 + tid];
    }

    // A = K K^T (wave w computes rows [16w,16w+16))
    f32x4 aacc[4];
#pragma unroll
    for (int nt = 0; nt < 4; nt++) aacc[nt] = (f32x4){0.f, 0.f, 0.f, 0.f};
#pragma unroll
    for (int q8 = 0; q8 < 8; q8++) {
        short8 af;
        {
            const u16* rp = KL + (16 * w + c) * 256;
            uint2 lo = *(const uint2*)(rp + (((8 * q8 + g) ^ c) << 2));
            uint2 hi = *(const uint2*)(rp + (((8 * q8 + 4 + g) ^ c) << 2));
            af = mk8(lo, hi);
        }
#pragma unroll
        for (int nt = 0; nt < 4; nt++) {
            const u16* rp = KL + (16 * nt + c) * 256;
            uint2 lo = *(const uint2*)(rp + (((8 * q8 + g) ^ c) << 2));
            uint2 hi = *(const uint2*)(rp + (((8 * q8 + 4 + g) ^ c) << 2));
            aacc[nt] = __builtin_amdgcn_mfma_f32_16x16x32_bf16(af, mk8(lo, hi), aacc[nt], 0, 0, 0);
        }
    }
#pragma unroll
    for (int nt = 0; nt < 4; nt++)
#pragma unroll
        for (int r = 0; r < 4; r++)
            WL[(16 * w + 4 * g + r) * 68 + 16 * nt + c] = f2bf(aacc[nt][r] * bv[16 * nt + c]);
    __syncthreads();

    // forward substitution: wave w owns cols [16w,16w+16)
    {
        const int col = 16 * w + c;
        for (int t = 1; t < 64; t++) {
            float acc = 0.f;
            for (int s = g; s < t; s += 4)
                acc += bf2f(WL[t * 68 + s]) * LI[s * 65 + col];
            acc += __shfl_xor(acc, 16);
            acc += __shfl_xor(acc, 32);
            if (g == 0) LI[t * 65 + col] = ((t == col) ? 1.0f : 0.0f) - acc;
        }
    }
    __syncthreads();

    for (int ii = tid; ii < 4096; ii += 256) {
        int t = ii >> 6, s = ii & 63;
        AIV_g[((long)(bh * 32 + q)) * 4096 + t * 64 + ((((s >> 2) ^ (t & 15)) << 2) | (s & 3))] =
            f2bf(LI[t * 65 + s]);
    }
    // BKT[j][t] = b_t * K[t][j], transposed + swizzled; thread = j
    {
        const long rb = ((long)(bh * 32 + q) * 256 + tid) * 64;
#pragma unroll
        for (int tb = 0; tb < 16; tb++) {
            int t0 = 4 * tb;
            float v0 = bv[t0 + 0] * bf2f(KL[(t0 + 0) * 256 + ((((tid >> 2) ^ ((t0 + 0) & 15)) << 2) | (tid & 3))]);
            float v1 = bv[t0 + 1] * bf2f(KL[(t0 + 1) * 256 + ((((tid >> 2) ^ ((t0 + 1) & 15)) << 2) | (tid & 3))]);
            float v2 = bv[t0 + 2] * bf2f(KL[(t0 + 2) * 256 + ((((tid >> 2) ^ ((t0 + 2) & 15)) << 2) | (tid & 3))]);
            float v3 = bv[t0 + 3] * bf2f(KL[(t0 + 3) * 256 + ((((tid >> 2) ^ ((t0 + 3) & 15)) << 2) | (tid & 3))]);
            u32 p0 = (u32)f2bf(v0) | ((u32)f2bf(v1) << 16);
            u32 p1 = (u32)f2bf(v2) | ((u32)f2bf(v3) << 16);
            *(uint2*)(BKT_g + rb + ((tb ^ (tid & 15)) << 2)) = make_uint2(p0, p1);
        }
    }
}

// ---------------- chunked delta-rule scan with 2-phase staged pipeline ----------------
// LDS (bytes): Kb[0,32K) | BKT0[32K,64K) | BKT1[64K,96K) | AIV[96K,104K) |
//              V0[104K,108K) | V1[108K,112K) | TS[112K,128K)   = 128 KB
__global__ __launch_bounds__(256, 1) void scan_chunked(
    const u16* __restrict__ VN, const u16* __restrict__ QN,
    const u16* __restrict__ Kb_g, const u16* __restrict__ BKT_g,
    const u16* __restrict__ AIV_g, float* __restrict__ out,
    float* __restrict__ ORAW)
{
    __shared__ __align__(16) u16 smem[65536];   // 128 KB
    const int blk = blockIdx.x;
    const int bh = blk & 31, iblk = blk >> 5;
    const int b = bh >> 2, h = bh & 3;
    const int row0 = iblk * 32;
    const int tid = threadIdx.x;
    const int w = tid >> 6, lane = tid & 63, g = lane >> 4, c = lane & 15;

    u16* const KbL  = smem;             // 16384 u16
    u16* const AIVL = smem + 49152;     // 4096 u16
    u16* const TSL  = smem + 57344;     // 8192 u16

#define GLDS(gp, lofs) __builtin_amdgcn_global_load_lds((const AS1 void*)(gp), \
        (AS3 void*)((AS3 char*)(char*)smem + (lofs)), 16, 0, 0)
#define STAGE_BKT(qq, bi) { const char* gt = (const char*)(BKT_g + (long)(bh * 32 + (qq)) * 16384); \
    _Pragma("unroll") for (int i_ = 0; i_ < 8; i_++) GLDS(gt + i_ * 4096 + tid * 16, 32768 + (bi) * 32768 + i_ * 4096 + tid * 16); }
#define STAGE_KB(qq) { const char* gk = (const char*)(Kb_g + (long)(bh * 32 + (qq)) * 16384); \
    _Pragma("unroll") for (int i_ = 0; i_ < 8; i_++) GLDS(gk + i_ * 4096 + tid * 16, i_ * 4096 + tid * 16); }
#define STAGE_AIV(qq) { const char* ga = (const char*)(AIV_g + (long)(bh * 32 + (qq)) * 4096); \
    _Pragma("unroll") for (int i_ = 0; i_ < 2; i_++) GLDS(ga + i_ * 4096 + tid * 16, 98304 + i_ * 4096 + tid * 16); }
#define STAGE_V(qq, bi) { const char* gv = (const char*)(VN + ((long)b * LL + 64 * (qq) + (tid >> 2)) * DD + h * HD + row0 + (tid & 3) * 8); \
    GLDS(gv, 106496 + (bi) * 4096 + tid * 16); }

    f32x4 S[2][4];
#pragma unroll
    for (int si = 0; si < 2; si++)
#pragma unroll
        for (int sjl = 0; sjl < 4; sjl++) S[si][sjl] = (f32x4){0.f, 0.f, 0.f, 0.f};

    STAGE_BKT(0, 0); STAGE_V(0, 0); STAGE_KB(0); STAGE_AIV(0);
    __syncthreads();

    for (int q = 0; q < 32; ++q) {
        const int cur = q & 1;
        if (q < 31) { STAGE_BKT(q + 1, cur ^ 1); STAGE_V(q + 1, cur ^ 1); }

        // ---- GEMM1: G = K * S^T (skip at q==0) ----
        f32x4 gacc[4][2];
#pragma unroll
        for (int mt = 0; mt < 4; mt++)
#pragma unroll
            for (int it = 0; it < 2; it++) gacc[mt][it] = (f32x4){0.f, 0.f, 0.f, 0.f};
        if (q > 0) {
#pragma unroll
            for (int q8 = 0; q8 < 8; q8++) {
                short8 af[4], bfr[2];
#pragma unroll
                for (int mt = 0; mt < 4; mt++) {
                    const u16* rp = KbL + (16 * mt + c) * 256;
                    uint2 lo = *(const uint2*)(rp + (((8 * q8 + g) ^ c) << 2));
                    uint2 hi = *(const uint2*)(rp + (((8 * q8 + 4 + g) ^ c) << 2));
                    af[mt] = mk8(lo, hi);
                }
#pragma unroll
                for (int it = 0; it < 2; it++) {
                    const u16* rp = TSL + (16 * it + c) * 256;
                    uint2 lo = *(const uint2*)(rp + (((8 * q8 + g) ^ c) << 2));
                    uint2 hi = *(const uint2*)(rp + (((8 * q8 + 4 + g) ^ c) << 2));
                    bfr[it] = mk8(lo, hi);
                }
#pragma unroll
                for (int mt = 0; mt < 4; mt++)
#pragma unroll
                    for (int it = 0; it < 2; it++)
                        gacc[mt][it] = __builtin_amdgcn_mfma_f32_16x16x32_bf16(af[mt], bfr[it], gacc[mt][it], 0, 0, 0);
            }
        }
        __builtin_amdgcn_s_barrier();          // Kb/TS reads complete across waves
        __builtin_amdgcn_sched_barrier(0);
        if (q < 31) STAGE_KB(q + 1);

        // ---- RHS = G - V (V from LDS), pack as GEMM2 B-operand ----
        {
            const u16* VL = smem + 53248 + cur * 2048;
#pragma unroll
            for (int mt = 0; mt < 4; mt++)
#pragma unroll
                for (int it = 0; it < 2; it++)
#pragma unroll
                    for (int r = 0; r < 4; r++)
                        gacc[mt][it][r] -= bf2f(VL[(16 * mt + 4 * g + r) * 32 + 16 * it + c]);
        }
        short8 b2[2][2];
#pragma unroll
        for (int Q = 0; Q < 2; Q++)
#pragma unroll
            for (int it = 0; it < 2; it++) b2[Q][it] = pk8(gacc[2 * Q][it], gacc[2 * Q + 1][it]);

        // ---- GEMM2: U = Linv * RHS ----
        f32x4 uacc[4][2];
#pragma unroll
        for (int mt = 0; mt < 4; mt++)
#pragma unroll
            for (int it = 0; it < 2; it++) uacc[mt][it] = (f32x4){0.f, 0.f, 0.f, 0.f};
#pragma unroll
        for (int Q = 0; Q < 2; Q++) {
            short8 av[4];
#pragma unroll
            for (int mt = 0; mt < 4; mt++) {
                const u16* rp = AIVL + (16 * mt + c) * 64;
                uint2 lo = *(const uint2*)(rp + (((8 * Q + g) ^ c) << 2));
                uint2 hi = *(const uint2*)(rp + (((8 * Q + 4 + g) ^ c) << 2));
                av[mt] = mk8(lo, hi);
            }
#pragma unroll
            for (int mt = 0; mt < 4; mt++)
#pragma unroll
                for (int it = 0; it < 2; it++)
                    uacc[mt][it] = __builtin_amdgcn_mfma_f32_16x16x32_bf16(av[mt], b2[Q][it], uacc[mt][it], 0, 0, 0);
        }
        __builtin_amdgcn_s_barrier();          // AIV reads complete across waves
        __builtin_amdgcn_sched_barrier(0);
        if (q < 31) STAGE_AIV(q + 1);

        short8 a3[2][2];
#pragma unroll
        for (int Qp = 0; Qp < 2; Qp++)
#pragma unroll
            for (int it = 0; it < 2; it++) a3[Qp][it] = pk8(-uacc[2 * Qp][it], -uacc[2 * Qp + 1][it]);

        // ---- GEMM3: S += (-U)^T * (b K) ----
        {
            const u16* BKTL = smem + 16384 + cur * 16384;
#pragma unroll
            for (int Qp = 0; Qp < 2; Qp++) {
                short8 bk[4];
#pragma unroll
                for (int sjl = 0; sjl < 4; sjl++) {
                    const u16* rp = BKTL + (64 * w + 16 * sjl + c) * 64;
                    uint2 lo = *(const uint2*)(rp + (((8 * Qp + g) ^ c) << 2));
                    uint2 hi = *(const uint2*)(rp + (((8 * Qp + 4 + g) ^ c) << 2));
                    bk[sjl] = mk8(lo, hi);
                }
#pragma unroll
                for (int si = 0; si < 2; si++)
#pragma unroll
                    for (int sjl = 0; sjl < 4; sjl++)
                        S[si][sjl] = __builtin_amdgcn_mfma_f32_16x16x32_bf16(a3[Qp][si], bk[sjl], S[si][sjl], 0, 0, 0);
            }
        }

        // ---- S -> TS (bf16, swizzled) for next chunk's GEMM1 ----
        if (q < 31) {
#pragma unroll
            for (int si = 0; si < 2; si++)
#pragma unroll
                for (int sjl = 0; sjl < 4; sjl++) {
                    const int jb = 16 * w + 4 * sjl + (c >> 2);
                    const int jo = c & 3;
#pragma unroll
                    for (int r = 0; r < 4; r++) {
                        const int i = 16 * si + 4 * g + r;
                        TSL[i * 256 + ((jb ^ (4 * g + r)) << 2) + jo] = f2bf(S[si][sjl][r]);
                    }
                }
        }
        __syncthreads();   // drains vmcnt (all q+1 stages landed) + TS visibility
    }

    // ---- epilogue: o = S_final q ; S_final -> out ----
    float op[2][4];
#pragma unroll
    for (int si = 0; si < 2; si++)
#pragma unroll
        for (int r = 0; r < 4; r++) op[si][r] = 0.f;
#pragma unroll
    for (int sjl = 0; sjl < 4; sjl++) {
        const float qv = bf2f(QN[((long)b * 4 + 3) * DD + h * HD + 64 * w + 16 * sjl + c]);
#pragma unroll
        for (int si = 0; si < 2; si++)
#pragma unroll
            for (int r = 0; r < 4; r++) op[si][r] += S[si][sjl][r] * qv;
    }
#pragma unroll
    for (int si = 0; si < 2; si++)
#pragma unroll
        for (int r = 0; r < 4; r++) {
            float v = op[si][r];
            v += __shfl_xor(v, 1); v += __shfl_xor(v, 2);
            v += __shfl_xor(v, 4); v += __shfl_xor(v, 8);
            op[si][r] = v;
        }
    __syncthreads();
    float* red = (float*)smem;
    if (c == 0) {
#pragma unroll
        for (int si = 0; si < 2; si++)
#pragma unroll
            for (int r = 0; r < 4; r++) red[w * 32 + 16 * si + 4 * g + r] = op[si][r];
    }
    __syncthreads();
    if (tid < 32) {
        float o = red[tid] + red[32 + tid] + red[64 + tid] + red[96 + tid];
        ORAW[(long)b * DD + h * HD + row0 + tid] = o;
    }
#pragma unroll
    for (int si = 0; si < 2; si++)
#pragma unroll
        for (int sjl = 0; sjl < 4; sjl++)
#pragma unroll
            for (int r = 0; r < 4; r++)
                out[8192 + ((long)(bh * 256 + row0 + 16 * si + 4 * g + r)) * 256
                    + 64 * w + 16 * sjl + c] = S[si][sjl][r];
#undef GLDS
#undef STAGE_BKT
#undef STAGE_KB
#undef STAGE_AIV
#undef STAGE_V
}

// ---------------- RMSNorm ----------------
__global__ __launch_bounds__(256) void rmsnorm_kernel(const float* __restrict__ o_raw,
                                                      const float* __restrict__ w,
                                                      float* __restrict__ o_norm) {
    int b = blockIdx.x, t = threadIdx.x;
    float4 v = *(const float4*)(o_raw + (long)b * DD + t * 4);
    float ss = v.x * v.x + v.y * v.y + v.z * v.z + v.w * v.w;
#pragma unroll
    for (int m = 1; m < 64; m <<= 1) ss += __shfl_xor(ss, m);
    __shared__ float wsum[4];
    if ((t & 63) == 0) wsum[t >> 6] = ss;
    __syncthreads();
    float tot = wsum[0] + wsum[1] + wsum[2] + wsum[3];
    float sc = rsqrtf(tot / (float)DD + 1e-5f);
    float4 wv = *(const float4*)(w + t * 4);
    float4 r = make_float4(v.x * sc * wv.x, v.y * sc * wv.y, v.z * sc * wv.z, v.w * sc * wv.w);
    *(float4*)(o_norm + (long)b * DD + t * 4) = r;
}

// ---------------- out projection ----------------
__global__ __launch_bounds__(256) void outproj_kernel(const float* __restrict__ o_norm,
                                                      const float* __restrict__ Wout,
                                                      float* __restrict__ out) {
    int gid = blockIdx.x * 4 + (threadIdx.x >> 6);
    int lane = threadIdx.x & 63;
    int b = gid >> 10, n = gid & 1023;
    const float* orow = o_norm + (long)b * DD + lane * 16;
    const float* wrow = Wout + (long)n * DD + lane * 16;
    float s = 0.f;
#pragma unroll
    for (int u = 0; u < 4; u++) {
        float4 a = *(const float4*)(orow + u * 4);
        float4 w = *(const float4*)(wrow + u * 4);
        s += a.x * w.x + a.y * w.y + a.z * w.z + a.w * w.w;
    }
#pragma unroll
    for (int m = 1; m < 64; m <<= 1) s += __shfl_xor(s, m);
    if (lane == 0) out[(long)b * DD + n] = s;
}

extern "C" void kernel_launch(void* const* d_in, const int* in_sizes, int n_in,
                              void* d_out, int out_size, void* d_ws, size_t ws_size,
                              hipStream_t stream) {
    const float* x     = (const float*)d_in[0];
    const float* Wq    = (const float*)d_in[1];
    const float* Wk    = (const float*)d_in[2];
    const float* Wv    = (const float*)d_in[3];
    const float* cq    = (const float*)d_in[4];
    const float* ck    = (const float*)d_in[5];
    const float* cv    = (const float*)d_in[6];
    const float* Wbeta = (const float*)d_in[7];
    const float* rms_w = (const float*)d_in[8];
    const float* Wout  = (const float*)d_in[9];
    float* out = (float*)d_out;

    char* ws = (char*)d_ws;
    u16* XB     = (u16*)(ws + 0);           // 32 MB
    u16* WKB    = (u16*)(ws + 33554432);    // 2 MB
    u16* WVB    = (u16*)(ws + 35651584);    // 2 MB
    u16* R      = (u16*)(ws + 37748736);    // 32 MB (bf16 now)
    u16* KN     = (u16*)(ws + 71303168);    // 32 MB
    u16* VN     = (u16*)(ws + 104857600);   // 32 MB
    u16* Kb_g   = (u16*)(ws + 138412032);   // 32 MB
    u16* BKT_g  = (u16*)(ws + 171966464);   // 32 MB
    u16* AIV_g  = (u16*)(ws + 205520896);   // 8 MB
    float* BETA = (float*)(ws + 213909504); // 256 KB
    u16* RQ     = (u16*)(ws + 214171648);   // 64 KB
    u16* QN     = (u16*)(ws + 214237184);   // 64 KB
    float* ORAW = (float*)(ws + 214302720); // 32 KB
    float* ONRM = (float*)(ws + 214335488); // 32 KB

    cvt_bf16<<<8192, 256, 0, stream>>>(x, XB, 16777216);
    cvt_bf16<<<512, 256, 0, stream>>>(Wk, WKB, 1048576);
    cvt_bf16<<<512, 256, 0, stream>>>(Wv, WVB, 1048576);

    dim3 gg(8, 128);  // N/128, M/128

    gemm_bf16<<<gg, 256, 0, stream>>>(XB, WKB, R);
    conv_silu<true><<<BB * LL, 256, 0, stream>>>(R, ck, KN, LL, -1);
    gemm_bf16<<<gg, 256, 0, stream>>>(XB, WVB, R);
    conv_silu<false><<<BB * LL, 256, 0, stream>>>(R, cv, VN, LL, -1);
    qraw_gemm<<<8192, 256, 0, stream>>>(x, Wq, RQ);
    conv_silu<true><<<BB, 256, 0, stream>>>(RQ, cq, QN, 4, 3);
    beta_kernel<<<BB * LL, 64, 0, stream>>>(x, Wbeta, BETA);

    prep_chunk<<<1024, 256, 0, stream>>>(KN, BETA, Kb_g, BKT_g, AIV_g);
    scan_chunked<<<256, 256, 0, stream>>>(VN, QN, Kb_g, BKT_g, AIV_g, out, ORAW);

    rmsnorm_kernel<<<BB, 256, 0, stream>>>(ORAW, rms_w, ONRM);
    outproj_kernel<<<2048, 256, 0, stream>>>(ONRM, Wout, out);
}

// Round 4
// 474.247 us; speedup vs baseline: 3.3680x; 1.0681x over previous
//
#include <hip/hip_runtime.h>

#define LL 2048
#define BB 8
#define DD 1024
#define HH 4
#define HD 256

#define AS1 __attribute__((address_space(1)))
#define AS3 __attribute__((address_space(3)))

typedef __attribute__((ext_vector_type(8))) short short8;
typedef __attribute__((ext_vector_type(4))) float f32x4;
typedef unsigned short u16;
typedef unsigned int u32;

static __device__ __forceinline__ u16 f2bf(float f) {
    u32 u = __float_as_uint(f);
    return (u16)((u + 0x7fffu + ((u >> 16) & 1u)) >> 16);
}
static __device__ __forceinline__ float bf2f(u16 v) {
    return __uint_as_float(((u32)v) << 16);
}
static __device__ __forceinline__ float silu_f(float x) { return x / (1.0f + __expf(-x)); }

// ---------------- f32 -> bf16 convert ----------------
__global__ __launch_bounds__(256) void cvt_bf16(const float* __restrict__ in,
                                                u16* __restrict__ out, int n) {
    int i = (blockIdx.x * 256 + threadIdx.x) * 8;
    if (i >= n) return;
    float4 a = *(const float4*)(in + i);
    float4 b = *(const float4*)(in + i + 4);
    uint4 pk;
    pk.x = (u32)f2bf(a.x) | ((u32)f2bf(a.y) << 16);
    pk.y = (u32)f2bf(a.z) | ((u32)f2bf(a.w) << 16);
    pk.z = (u32)f2bf(b.x) | ((u32)f2bf(b.y) << 16);
    pk.w = (u32)f2bf(b.z) | ((u32)f2bf(b.w) << 16);
    *(uint4*)(out + i) = pk;
}

// ---------------- m97-style 128x128 LDS GEMM, bf16 in, bf16 out ----------------
__global__ __launch_bounds__(256, 2) void gemm_bf16(const u16* __restrict__ A,
                                                    const u16* __restrict__ W,
                                                    u16* __restrict__ C) {
    __shared__ __align__(16) u16 sm[32768];  // 64 KB: 2 bufs x (A 16KB + B 16KB)
    const int tid = threadIdx.x;
    const int w = tid >> 6, lane = tid & 63, g = lane >> 4, c = lane & 15;
    const int m0 = blockIdx.y * 128, n0 = blockIdx.x * 128;
    const int wm = (w >> 1) * 64, wn = (w & 1) * 64;

    f32x4 acc[4][4];
#pragma unroll
    for (int i = 0; i < 4; i++)
#pragma unroll
        for (int j = 0; j < 4; j++) acc[i][j] = (f32x4){0.f, 0.f, 0.f, 0.f};

    const int sr = tid >> 3;
    const int cb = (tid & 7) * 16;

#define GLDSG(gp, lofs) __builtin_amdgcn_global_load_lds((const AS1 void*)(gp), \
        (AS3 void*)((AS3 char*)(char*)sm + (lofs)), 16, 0, 0)

#define GSTAGE(kt, bi)                                                        \
    {                                                                         \
        const char* ab = (const char*)(A + (long)m0 * DD + (kt) * 64);        \
        const char* wb = (const char*)(W + (long)n0 * DD + (kt) * 64);        \
        _Pragma("unroll")                                                     \
        for (int i = 0; i < 4; i++) {                                         \
            int r = i * 32 + sr;                                              \
            int so = r * 2048 + (cb ^ ((r & 7) << 4));                        \
            int dof = (bi) * 32768 + i * 4096 + tid * 16;                     \
            GLDSG(ab + so, dof);                                              \
            GLDSG(wb + so, dof + 16384);                                      \
        }                                                                     \
    }

    GSTAGE(0, 0);
    __syncthreads();

    const int sw = (c & 7) << 4;
    for (int kt = 0; kt < 16; kt++) {
        const int bi = kt & 1;
        if (kt < 15) GSTAGE(kt + 1, bi ^ 1);
        const int ba = bi * 32768;
#pragma unroll
        for (int ks = 0; ks < 2; ks++) {
            short8 av[4], bvv[4];
#pragma unroll
            for (int mt = 0; mt < 4; mt++)
                av[mt] = *(const short8*)((const char*)sm + ba +
                         (wm + 16 * mt + c) * 128 + ((ks * 64 + g * 16) ^ sw));
#pragma unroll
            for (int nt = 0; nt < 4; nt++)
                bvv[nt] = *(const short8*)((const char*)sm + ba + 16384 +
                          (wn + 16 * nt + c) * 128 + ((ks * 64 + g * 16) ^ sw));
#pragma unroll
            for (int mt = 0; mt < 4; mt++)
#pragma unroll
                for (int nt = 0; nt < 4; nt++)
                    acc[mt][nt] = __builtin_amdgcn_mfma_f32_16x16x32_bf16(av[mt], bvv[nt], acc[mt][nt], 0, 0, 0);
        }
        __syncthreads();
    }

#pragma unroll
    for (int mt = 0; mt < 4; mt++)
#pragma unroll
        for (int nt = 0; nt < 4; nt++)
#pragma unroll
            for (int r = 0; r < 4; r++)
                C[(long)(m0 + wm + 16 * mt + 4 * g + r) * DD + n0 + wn + 16 * nt + c] =
                    f2bf(acc[mt][nt][r]);
#undef GSTAGE
#undef GLDSG
}

// ---------------- causal depthwise conv (K=4) + silu + silu (+ l2norm), bf16 io ----------------
template <bool NORM>
__global__ __launch_bounds__(256) void conv_silu(const u16* __restrict__ in,
                                                 const float* __restrict__ cw,
                                                 u16* __restrict__ out, int Lc, int lsel) {
    int b, l;
    if (lsel >= 0) { b = blockIdx.x; l = lsel; }
    else { b = blockIdx.x / Lc; l = blockIdx.x % Lc; }
    int t = threadIdx.x;
    int d = t * 4;

    float w0[4], w1[4], w2[4], w3[4];
    const float4* cw4 = (const float4*)cw;
    *(float4*)w0 = cw4[d + 0];
    *(float4*)w1 = cw4[d + 1];
    *(float4*)w2 = cw4[d + 2];
    *(float4*)w3 = cw4[d + 3];

    const u16* base = in + (long)b * Lc * DD + d;
    float a0 = 0.f, a1 = 0.f, a2 = 0.f, a3 = 0.f;
#pragma unroll
    for (int j = 0; j < 4; j++) {
        int r = l - 3 + j;
        if (r >= 0) {
            uint2 v = *(const uint2*)(base + (long)r * DD);
            a0 += bf2f((u16)(v.x & 0xffff)) * w0[j];
            a1 += bf2f((u16)(v.x >> 16)) * w1[j];
            a2 += bf2f((u16)(v.y & 0xffff)) * w2[j];
            a3 += bf2f((u16)(v.y >> 16)) * w3[j];
        }
    }
    float y0 = silu_f(silu_f(a0));
    float y1 = silu_f(silu_f(a1));
    float y2 = silu_f(silu_f(a2));
    float y3 = silu_f(silu_f(a3));

    if (NORM) {
        float ss = y0 * y0 + y1 * y1 + y2 * y2 + y3 * y3;
#pragma unroll
        for (int m = 1; m < 64; m <<= 1) ss += __shfl_xor(ss, m);
        float nrm = sqrtf(ss);
        float sc = 1.0f / fmaxf(nrm, 1e-12f);
        y0 *= sc; y1 *= sc; y2 *= sc; y3 *= sc;
    }
    uint2 o;
    o.x = (u32)f2bf(y0) | ((u32)f2bf(y1) << 16);
    o.y = (u32)f2bf(y2) | ((u32)f2bf(y3) << 16);
    *(uint2*)(out + ((long)b * Lc + l) * DD + d) = o;
}

// ---------------- tiny q raw GEMM (rows l = L-4..L-1 only), bf16 out ----------------
__global__ __launch_bounds__(256) void qraw_gemm(const float* __restrict__ x,
                                                 const float* __restrict__ Wq,
                                                 u16* __restrict__ Rq) {
    int gid = blockIdx.x * 4 + (threadIdx.x >> 6);
    int lane = threadIdx.x & 63;
    int m = gid >> 10;
    int n = gid & 1023;
    int b = m >> 2, j = m & 3;
    int l = LL - 4 + j;
    const float* xr = x + ((long)b * LL + l) * DD + lane * 16;
    const float* wr = Wq + (long)n * DD + lane * 16;
    float s = 0.f;
#pragma unroll
    for (int u = 0; u < 4; u++) {
        float4 a = *(const float4*)(xr + u * 4);
        float4 w = *(const float4*)(wr + u * 4);
        s += a.x * w.x + a.y * w.y + a.z * w.z + a.w * w.w;
    }
#pragma unroll
    for (int mm = 1; mm < 64; mm <<= 1) s += __shfl_xor(s, mm);
    if (lane == 0) Rq[(long)m * DD + n] = f2bf(s);
}

// ---------------- beta ----------------
__global__ __launch_bounds__(64) void beta_kernel(const float* __restrict__ x,
                                                  const float* __restrict__ Wb,
                                                  float* __restrict__ beta) {
    int bl = blockIdx.x;
    int lane = threadIdx.x;
    const float* xr = x + (long)bl * DD + lane * 16;
    float4 xv[4];
#pragma unroll
    for (int u = 0; u < 4; u++) xv[u] = *(const float4*)(xr + u * 4);
#pragma unroll
    for (int h = 0; h < 4; h++) {
        const float* wr = Wb + (long)h * DD + lane * 16;
        float s = 0.f;
#pragma unroll
        for (int u = 0; u < 4; u++) {
            float4 w = *(const float4*)(wr + u * 4);
            s += xv[u].x * w.x + xv[u].y * w.y + xv[u].z * w.z + xv[u].w * w.w;
        }
#pragma unroll
        for (int m = 1; m < 64; m <<= 1) s += __shfl_xor(s, m);
        if (lane == 0) beta[(long)bl * HH + h] = 1.0f / (1.0f + __expf(-s));
    }
}

// ---------------- prep per (bh, chunk): LK' = -Linv*K [t][d], BKT = (b*K)^T [d][t],
// LV' = +Linv*V in scan-tid-linear planes. All bf16, swizzle: 16B-block ^ (row&7). ----------------
__global__ __launch_bounds__(256) void prep_chunk(
    const u16* __restrict__ KN, const u16* __restrict__ VN, const float* __restrict__ BETA,
    u16* __restrict__ LK_g, u16* __restrict__ BKT_g, u16* __restrict__ LV_g)
{
    __shared__ __align__(16) u16 R1[16384];   // 32KB: KTL [256][64] swz, then VT
    __shared__ __align__(16) u16 R2[16384];   // 32KB: LI f32 [64][65], then LK/LV stage
    __shared__ __align__(16) u16 R3[4608];    // 9KB: WL [64][68], then LIbf [64][64] swz
    __shared__ float bv[64];
    const int bh = blockIdx.x >> 5, q = blockIdx.x & 31;
    const int b = bh >> 2, h = bh & 3;
    const int tid = threadIdx.x;
    const int w = tid >> 6, lane = tid & 63, g = lane >> 4, c = lane & 15;
    const long cb = (long)(bh * 32 + q);
    const long kbase = ((long)b * LL + 64 * q) * DD + h * HD;
    float* LI = (float*)R2;

    // ---- phase 0: KTL (K transposed, swizzled) + bv + LI init ----
    for (int ii = tid; ii < 2048; ii += 256) {
        int t = ii >> 5, d0 = (ii & 31) * 8;
        uint4 kv = *(const uint4*)(KN + kbase + (long)t * DD + d0);
        u16 vals[8];
        *(uint4*)vals = kv;
#pragma unroll
        for (int j = 0; j < 8; j++) {
            int d = d0 + j;
            *(u16*)((char*)R1 + d * 128 + ((((t >> 3) ^ (d & 7)) << 4) + (t & 7) * 2)) = vals[j];
        }
    }
    if (tid < 64) bv[tid] = BETA[((long)b * LL + 64 * q + tid) * HH + h];
    for (int ii = tid; ii < 4160; ii += 256) {
        int t = ii / 65, s = ii - 65 * t;
        LI[ii] = (t == s) ? 1.0f : 0.0f;
    }
    __syncthreads();

    // ---- phase 0.5: BKT out (KTL * b_t, same layout) ----
    for (int ii = tid; ii < 2048; ii += 256) {
        int d = ii >> 3, bl = ii & 7;
        u16 vals[8];
        *(uint4*)vals = *(const uint4*)((const char*)R1 + d * 128 + bl * 16);
        int tb = (bl ^ (d & 7)) << 3;
#pragma unroll
        for (int j = 0; j < 8; j++) vals[j] = f2bf(bf2f(vals[j]) * bv[tb + j]);
        *(uint4*)((char*)(BKT_g + cb * 16384) + d * 128 + bl * 16) = *(uint4*)vals;
    }

    // ---- phase 1: A = K K^T (frags straight from global KN), WL = A*diag(b) bf16 ----
    {
        f32x4 aacc[4];
#pragma unroll
        for (int nt = 0; nt < 4; nt++) aacc[nt] = (f32x4){0.f, 0.f, 0.f, 0.f};
#pragma unroll
        for (int q8 = 0; q8 < 8; q8++) {
            short8 af = *(const short8*)(KN + kbase + (long)(16 * w + c) * DD + 32 * q8 + 8 * g);
#pragma unroll
            for (int nt = 0; nt < 4; nt++) {
                short8 bf = *(const short8*)(KN + kbase + (long)(16 * nt + c) * DD + 32 * q8 + 8 * g);
                aacc[nt] = __builtin_amdgcn_mfma_f32_16x16x32_bf16(af, bf, aacc[nt], 0, 0, 0);
            }
        }
#pragma unroll
        for (int nt = 0; nt < 4; nt++)
#pragma unroll
            for (int r = 0; r < 4; r++)
                R3[(16 * w + 4 * g + r) * 68 + 16 * nt + c] = f2bf(aacc[nt][r] * bv[16 * nt + c]);
    }
    __syncthreads();

    // ---- phase 2: forward substitution (cols 16w+c per wave) ----
    {
        const int col = 16 * w + c;
        for (int t = 1; t < 64; t++) {
            float acc = 0.f;
            for (int s = g; s < t; s += 4)
                acc += bf2f(R3[t * 68 + s]) * LI[s * 65 + col];
            acc += __shfl_xor(acc, 16);
            acc += __shfl_xor(acc, 32);
            if (g == 0) LI[t * 65 + col] = ((t == col) ? 1.0f : 0.0f) - acc;
        }
    }
    __syncthreads();

    // ---- phase 3: LIbf [64][64] swizzled into R3 (overwrites WL) ----
    for (int ii = tid; ii < 4096; ii += 256) {
        int t = ii >> 6, s = ii & 63;
        float v = LI[t * 65 + s];
        *(u16*)((char*)R3 + t * 128 + ((((s >> 3) ^ (t & 7)) << 4) + (s & 7) * 2)) = f2bf(v);
    }
    __syncthreads();

    // ---- phase 4: LK' = -Linv*K  (A = KTL, B = LIbf), stage [64 t][256 d] swz -> out ----
    {
        f32x4 lk[4][4];
#pragma unroll
        for (int i = 0; i < 4; i++)
#pragma unroll
            for (int j = 0; j < 4; j++) lk[i][j] = (f32x4){0.f, 0.f, 0.f, 0.f};
        const int sw = (c & 7) << 4;
#pragma unroll
        for (int qs = 0; qs < 2; qs++) {
            short8 aT[4], bT[4];
#pragma unroll
            for (int dm = 0; dm < 4; dm++)
                aT[dm] = *(const short8*)((const char*)R1 + (16 * (4 * w + dm) + c) * 128 +
                                          (((qs * 4 + g) << 4) ^ sw));
#pragma unroll
            for (int tm = 0; tm < 4; tm++)
                bT[tm] = *(const short8*)((const char*)R3 + (16 * tm + c) * 128 +
                                          (((qs * 4 + g) << 4) ^ sw));
#pragma unroll
            for (int dm = 0; dm < 4; dm++)
#pragma unroll
                for (int tm = 0; tm < 4; tm++)
                    lk[dm][tm] = __builtin_amdgcn_mfma_f32_16x16x32_bf16(aT[dm], bT[tm], lk[dm][tm], 0, 0, 0);
        }
#pragma unroll
        for (int dm = 0; dm < 4; dm++)
#pragma unroll
            for (int tm = 0; tm < 4; tm++)
#pragma unroll
                for (int r = 0; r < 4; r++) {
                    int d = 16 * (4 * w + dm) + 4 * g + r;
                    int t = 16 * tm + c;
                    *(u16*)((char*)R2 + t * 512 + ((((d >> 3) ^ (t & 7)) << 4) + (d & 7) * 2)) =
                        f2bf(-lk[dm][tm][r]);
                }
    }
    __syncthreads();
    for (int ii = tid; ii < 2048; ii += 256)
        ((uint4*)(LK_g + cb * 16384))[ii] = ((const uint4*)R2)[ii];

    // ---- phase 5: VT (V transposed, swizzled) into R1 ----
    for (int ii = tid; ii < 2048; ii += 256) {
        int t = ii >> 5, d0 = (ii & 31) * 8;
        uint4 vvu = *(const uint4*)(VN + kbase + (long)t * DD + d0);
        u16 vals[8];
        *(uint4*)vals = vvu;
#pragma unroll
        for (int j = 0; j < 8; j++) {
            int i = d0 + j;
            *(u16*)((char*)R1 + i * 128 + ((((t >> 3) ^ (i & 7)) << 4) + (t & 7) * 2)) = vals[j];
        }
    }
    __syncthreads();

    // ---- phase 6: LV' = +Linv*V (A = VT, B = LIbf), stage plain [64 t][256 i] ----
    {
        f32x4 lv[4][4];
#pragma unroll
        for (int i = 0; i < 4; i++)
#pragma unroll
            for (int j = 0; j < 4; j++) lv[i][j] = (f32x4){0.f, 0.f, 0.f, 0.f};
        const int sw = (c & 7) << 4;
#pragma unroll
        for (int qs = 0; qs < 2; qs++) {
            short8 aV[4], bT[4];
#pragma unroll
            for (int im = 0; im < 4; im++)
                aV[im] = *(const short8*)((const char*)R1 + (16 * (4 * w + im) + c) * 128 +
                                          (((qs * 4 + g) << 4) ^ sw));
#pragma unroll
            for (int tm = 0; tm < 4; tm++)
                bT[tm] = *(const short8*)((const char*)R3 + (16 * tm + c) * 128 +
                                          (((qs * 4 + g) << 4) ^ sw));
#pragma unroll
            for (int im = 0; im < 4; im++)
#pragma unroll
                for (int tm = 0; tm < 4; tm++)
                    lv[im][tm] = __builtin_amdgcn_mfma_f32_16x16x32_bf16(aV[im], bT[tm], lv[im][tm], 0, 0, 0);
        }
        __syncthreads();
#pragma unroll
        for (int im = 0; im < 4; im++)
#pragma unroll
            for (int tm = 0; tm < 4; tm++)
#pragma unroll
                for (int r = 0; r < 4; r++) {
                    int i = 16 * (4 * w + im) + 4 * g + r;
                    int t = 16 * tm + c;
                    R2[t * 256 + i] = f2bf(lv[im][tm][r]);
                }
    }
    __syncthreads();

    // ---- phase 7: LV out in scan-tid-linear planes ----
    {
        u32* lvout = (u32*)(LV_g + cb * 16384);
        for (int jj = tid; jj < 8192; jj += 256) {
            int iblk = jj >> 10, rem = jj & 1023, plane = rem >> 9, ts = rem & 511;
            int ws = ts >> 6, gs = (ts >> 4) & 3, cs = ts & 15;
            int mt = ws >> 1, it = ws & 1;
            int t0 = 16 * mt + 4 * gs + 2 * plane;
            int i = 32 * iblk + 16 * it + cs;
            u16 lo = R2[t0 * 256 + i];
            u16 hi = R2[(t0 + 1) * 256 + i];
            lvout[jj] = (u32)lo | ((u32)hi << 16);
        }
    }
}

// ---------------- chunked scan: 8 waves, 2 GEMMs/chunk, all-b128 LDS frags ----------------
// LDS bytes: LK dbuf [0,64K) | BKT dbuf [64K,128K) | LV dbuf [128K,136K) |
//            WLDS [136K,140K) | TS [140K,156K)
__global__ __launch_bounds__(512, 1) void scan_chunked(
    const u16* __restrict__ LK_g, const u16* __restrict__ BKT_g,
    const u16* __restrict__ LV_g, const u16* __restrict__ QN,
    float* __restrict__ out, float* __restrict__ ORAW)
{
    __shared__ __align__(16) char smem[159744];
    const int blk = blockIdx.x;
    const int bh = blk & 31, iblk = blk >> 5;
    const int b = bh >> 2, h = bh & 3;
    const int row0 = iblk * 32;
    const int tid = threadIdx.x;
    const int w = tid >> 6, lane = tid & 63, g = lane >> 4, c = lane & 15;
    const int mt = w >> 1, it = w & 1;
    const int sw = (c & 7) << 4;

#define GLDS16(gp, lofs) __builtin_amdgcn_global_load_lds((const AS1 void*)(gp), \
        (AS3 void*)((AS3 char*)smem + (lofs)), 16, 0, 0)
#define GLDS4(gp, lofs) __builtin_amdgcn_global_load_lds((const AS1 void*)(gp), \
        (AS3 void*)((AS3 char*)smem + (lofs)), 4, 0, 0)
#define STAGE_LK(qq, bi) { const char* gp = (const char*)(LK_g + (long)(bh * 32 + (qq)) * 16384); \
    _Pragma("unroll") for (int i_ = 0; i_ < 4; i_++) GLDS16(gp + i_ * 8192 + tid * 16, (bi) * 32768 + i_ * 8192 + tid * 16); }
#define STAGE_BKT(qq, bi) { const char* gp = (const char*)(BKT_g + (long)(bh * 32 + (qq)) * 16384); \
    _Pragma("unroll") for (int i_ = 0; i_ < 4; i_++) GLDS16(gp + i_ * 8192 + tid * 16, 65536 + (bi) * 32768 + i_ * 8192 + tid * 16); }
#define STAGE_LV(qq, bi) { const char* gp = (const char*)LV_g + (long)(bh * 32 + (qq)) * 32768 + iblk * 4096; \
    GLDS4(gp + tid * 4, 131072 + (bi) * 4096 + tid * 4); \
    GLDS4(gp + 2048 + tid * 4, 131072 + (bi) * 4096 + 2048 + tid * 4); }

    f32x4 S[2][2];
#pragma unroll
    for (int si = 0; si < 2; si++)
#pragma unroll
        for (int sj = 0; sj < 2; sj++) S[si][sj] = (f32x4){0.f, 0.f, 0.f, 0.f};

    STAGE_LK(0, 0); STAGE_BKT(0, 0); STAGE_LV(0, 0);

    for (int q = 0; q < 32; ++q) {
        const int cur = q & 1;
        if (q < 31) {
            STAGE_LK(q + 1, cur ^ 1); STAGE_BKT(q + 1, cur ^ 1); STAGE_LV(q + 1, cur ^ 1);
            asm volatile("s_waitcnt vmcnt(10)" ::: "memory");
        } else {
            asm volatile("s_waitcnt vmcnt(0)" ::: "memory");
        }
        __builtin_amdgcn_sched_barrier(0);

        const char* lkb = smem + cur * 32768;
        const char* bkb = smem + 65536 + cur * 32768;
        const char* lvb = smem + 131072 + cur * 4096;

        // ---- W = LK' * S^T + LV'  (wave tile: t-rows 16mt.., i-cols 16it..) ----
        u32 l0 = *(const u32*)(lvb + tid * 4);
        u32 l1 = *(const u32*)(lvb + 2048 + tid * 4);
        f32x4 w0, w1;
        w0[0] = bf2f((u16)(l0 & 0xffff)); w0[1] = bf2f((u16)(l0 >> 16));
        w0[2] = bf2f((u16)(l1 & 0xffff)); w0[3] = bf2f((u16)(l1 >> 16));
        w1 = (f32x4){0.f, 0.f, 0.f, 0.f};
        if (q > 0) {
            const int arow = (16 * mt + c) * 512;
            const int brow = (16 * it + c) * 512;
#pragma unroll
            for (int q8 = 0; q8 < 8; q8++) {
                short8 av = *(const short8*)(lkb + arow + (((q8 * 4 + g) << 4) ^ sw));
                short8 bv8 = *(const short8*)(smem + 143360 + brow + (((q8 * 4 + g) << 4) ^ sw));
                if (q8 & 1) w1 = __builtin_amdgcn_mfma_f32_16x16x32_bf16(av, bv8, w1, 0, 0, 0);
                else        w0 = __builtin_amdgcn_mfma_f32_16x16x32_bf16(av, bv8, w0, 0, 0, 0);
            }
#pragma unroll
            for (int r = 0; r < 4; r++) w0[r] += w1[r];
        }

        // ---- all-gather W into WLDS [32 i][64 t] swz ----
        {
            char* ub = smem + 139264 + (16 * it + c) * 128;
#pragma unroll
            for (int r = 0; r < 4; r++) {
                int t = 16 * mt + 4 * g + r;
                *(u16*)(ub + ((((t >> 3) << 4) ^ sw) + (t & 7) * 2)) = f2bf(w0[r]);
            }
        }
        asm volatile("s_waitcnt lgkmcnt(0)" ::: "memory");
        __builtin_amdgcn_s_barrier();
        __builtin_amdgcn_sched_barrier(0);

        // ---- S += W^T * (bK)  (wave owns cols j in [32w, 32w+32)) ----
#pragma unroll
        for (int Qp = 0; Qp < 2; Qp++) {
            const int tof = ((Qp * 4 + g) << 4) ^ sw;
            short8 a0 = *(const short8*)(smem + 139264 + c * 128 + tof);
            short8 a1 = *(const short8*)(smem + 139264 + (16 + c) * 128 + tof);
            short8 b0 = *(const short8*)(bkb + (32 * w + c) * 128 + tof);
            short8 b1 = *(const short8*)(bkb + (32 * w + 16 + c) * 128 + tof);
            S[0][0] = __builtin_amdgcn_mfma_f32_16x16x32_bf16(a0, b0, S[0][0], 0, 0, 0);
            S[0][1] = __builtin_amdgcn_mfma_f32_16x16x32_bf16(a0, b1, S[0][1], 0, 0, 0);
            S[1][0] = __builtin_amdgcn_mfma_f32_16x16x32_bf16(a1, b0, S[1][0], 0, 0, 0);
            S[1][1] = __builtin_amdgcn_mfma_f32_16x16x32_bf16(a1, b1, S[1][1], 0, 0, 0);
        }

        // ---- S -> TS [32 i][256 j] swz bf16 for next chunk ----
        if (q < 31) {
#pragma unroll
            for (int si = 0; si < 2; si++)
#pragma unroll
                for (int sj = 0; sj < 2; sj++)
#pragma unroll
                    for (int r = 0; r < 4; r++) {
                        int i = 16 * si + 4 * g + r;
                        *(u16*)(smem + 143360 + i * 512 +
                                ((((4 * w + 2 * sj + (c >> 3)) << 4) ^ ((i & 7) << 4)) + (c & 7) * 2)) =
                            f2bf(S[si][sj][r]);
                    }
        }
        asm volatile("s_waitcnt lgkmcnt(0)" ::: "memory");
        __builtin_amdgcn_s_barrier();
        __builtin_amdgcn_sched_barrier(0);
    }

    // ---- epilogue: o = S_final q ; S_final -> out ----
    float op[2][4];
#pragma unroll
    for (int si = 0; si < 2; si++)
#pragma unroll
        for (int r = 0; r < 4; r++) op[si][r] = 0.f;
#pragma unroll
    for (int sj = 0; sj < 2; sj++) {
        const float qv = bf2f(QN[((long)b * 4 + 3) * DD + h * HD + 32 * w + 16 * sj + c]);
#pragma unroll
        for (int si = 0; si < 2; si++)
#pragma unroll
            for (int r = 0; r < 4; r++) op[si][r] += S[si][sj][r] * qv;
    }
#pragma unroll
    for (int si = 0; si < 2; si++)
#pragma unroll
        for (int r = 0; r < 4; r++) {
            float v = op[si][r];
            v += __shfl_xor(v, 1); v += __shfl_xor(v, 2);
            v += __shfl_xor(v, 4); v += __shfl_xor(v, 8);
            op[si][r] = v;
        }
    float* red = (float*)smem;
    if (c == 0) {
#pragma unroll
        for (int si = 0; si < 2; si++)
#pragma unroll
            for (int r = 0; r < 4; r++) red[w * 32 + 16 * si + 4 * g + r] = op[si][r];
    }
    __syncthreads();
    if (tid < 32) {
        float o = 0.f;
#pragma unroll
        for (int ww = 0; ww < 8; ww++) o += red[ww * 32 + tid];
        ORAW[(long)b * DD + h * HD + row0 + tid] = o;
    }
#pragma unroll
    for (int si = 0; si < 2; si++)
#pragma unroll
        for (int sj = 0; sj < 2; sj++)
#pragma unroll
            for (int r = 0; r < 4; r++)
                out[8192 + ((long)(bh * 256 + row0 + 16 * si + 4 * g + r)) * 256
                    + 32 * w + 16 * sj + c] = S[si][sj][r];
#undef GLDS16
#undef GLDS4
#undef STAGE_LK
#undef STAGE_BKT
#undef STAGE_LV
}

// ---------------- RMSNorm ----------------
__global__ __launch_bounds__(256) void rmsnorm_kernel(const float* __restrict__ o_raw,
                                                      const float* __restrict__ w,
                                                      float* __restrict__ o_norm) {
    int b = blockIdx.x, t = threadIdx.x;
    float4 v = *(const float4*)(o_raw + (long)b * DD + t * 4);
    float ss = v.x * v.x + v.y * v.y + v.z * v.z + v.w * v.w;
#pragma unroll
    for (int m = 1; m < 64; m <<= 1) ss += __shfl_xor(ss, m);
    __shared__ float wsum[4];
    if ((t & 63) == 0) wsum[t >> 6] = ss;
    __syncthreads();
    float tot = wsum[0] + wsum[1] + wsum[2] + wsum[3];
    float sc = rsqrtf(tot / (float)DD + 1e-5f);
    float4 wv = *(const float4*)(w + t * 4);
    float4 r = make_float4(v.x * sc * wv.x, v.y * sc * wv.y, v.z * sc * wv.z, v.w * sc * wv.w);
    *(float4*)(o_norm + (long)b * DD + t * 4) = r;
}

// ---------------- out projection ----------------
__global__ __launch_bounds__(256) void outproj_kernel(const float* __restrict__ o_norm,
                                                      const float* __restrict__ Wout,
                                                      float* __restrict__ out) {
    int gid = blockIdx.x * 4 + (threadIdx.x >> 6);
    int lane = threadIdx.x & 63;
    int b = gid >> 10, n = gid & 1023;
    const float* orow = o_norm + (long)b * DD + lane * 16;
    const float* wrow = Wout + (long)n * DD + lane * 16;
    float s = 0.f;
#pragma unroll
    for (int u = 0; u < 4; u++) {
        float4 a = *(const float4*)(orow + u * 4);
        float4 w = *(const float4*)(wrow + u * 4);
        s += a.x * w.x + a.y * w.y + a.z * w.z + a.w * w.w;
    }
#pragma unroll
    for (int m = 1; m < 64; m <<= 1) s += __shfl_xor(s, m);
    if (lane == 0) out[(long)b * DD + n] = s;
}

extern "C" void kernel_launch(void* const* d_in, const int* in_sizes, int n_in,
                              void* d_out, int out_size, void* d_ws, size_t ws_size,
                              hipStream_t stream) {
    const float* x     = (const float*)d_in[0];
    const float* Wq    = (const float*)d_in[1];
    const float* Wk    = (const float*)d_in[2];
    const float* Wv    = (const float*)d_in[3];
    const float* cq    = (const float*)d_in[4];
    const float* ck    = (const float*)d_in[5];
    const float* cv    = (const float*)d_in[6];
    const float* Wbeta = (const float*)d_in[7];
    const float* rms_w = (const float*)d_in[8];
    const float* Wout  = (const float*)d_in[9];
    float* out = (float*)d_out;

    char* ws = (char*)d_ws;
    u16* XB     = (u16*)(ws + 0);           // 32 MB (dead after 2nd gemm)
    u16* BKT_g  = (u16*)(ws + 0);           // overlays XB (prep runs later)
    u16* WKB    = (u16*)(ws + 33554432);    // 2 MB
    u16* WVB    = (u16*)(ws + 35651584);    // 2 MB
    u16* R      = (u16*)(ws + 37748736);    // 32 MB (dead after convs)
    u16* LK_g   = (u16*)(ws + 37748736);    // overlays R
    u16* KN     = (u16*)(ws + 71303168);    // 32 MB
    u16* VN     = (u16*)(ws + 104857600);   // 32 MB
    u16* LV_g   = (u16*)(ws + 138412032);   // 32 MB
    float* BETA = (float*)(ws + 171966464); // 256 KB
    u16* RQ     = (u16*)(ws + 172228608);   // 64 KB
    u16* QN     = (u16*)(ws + 172294144);   // 64 KB
    float* ORAW = (float*)(ws + 172359680); // 32 KB
    float* ONRM = (float*)(ws + 172392448); // 32 KB

    cvt_bf16<<<8192, 256, 0, stream>>>(x, XB, 16777216);
    cvt_bf16<<<512, 256, 0, stream>>>(Wk, WKB, 1048576);
    cvt_bf16<<<512, 256, 0, stream>>>(Wv, WVB, 1048576);

    dim3 gg(8, 128);

    gemm_bf16<<<gg, 256, 0, stream>>>(XB, WKB, R);
    conv_silu<true><<<BB * LL, 256, 0, stream>>>(R, ck, KN, LL, -1);
    gemm_bf16<<<gg, 256, 0, stream>>>(XB, WVB, R);
    conv_silu<false><<<BB * LL, 256, 0, stream>>>(R, cv, VN, LL, -1);
    qraw_gemm<<<8192, 256, 0, stream>>>(x, Wq, RQ);
    conv_silu<true><<<BB, 256, 0, stream>>>(RQ, cq, QN, 4, 3);
    beta_kernel<<<BB * LL, 64, 0, stream>>>(x, Wbeta, BETA);

    prep_chunk<<<1024, 256, 0, stream>>>(KN, VN, BETA, LK_g, BKT_g, LV_g);
    scan_chunked<<<256, 512, 0, stream>>>(LK_g, BKT_g, LV_g, QN, out, ORAW);

    rmsnorm_kernel<<<BB, 256, 0, stream>>>(ORAW, rms_w, ONRM);
    outproj_kernel<<<2048, 256, 0, stream>>>(ONRM, Wout, out);
}

// Round 5
// 429.119 us; speedup vs baseline: 3.7222x; 1.1052x over previous
//
#include <hip/hip_runtime.h>

#define LL 2048
#define BB 8
#define DD 1024
#define HH 4
#define HD 256

#define AS1 __attribute__((address_space(1)))
#define AS3 __attribute__((address_space(3)))

typedef __attribute__((ext_vector_type(8))) short short8;
typedef __attribute__((ext_vector_type(4))) float f32x4;
typedef unsigned short u16;
typedef unsigned int u32;

static __device__ __forceinline__ u16 f2bf(float f) {
    u32 u = __float_as_uint(f);
    return (u16)((u + 0x7fffu + ((u >> 16) & 1u)) >> 16);
}
static __device__ __forceinline__ float bf2f(u16 v) {
    return __uint_as_float(((u32)v) << 16);
}
static __device__ __forceinline__ float silu_f(float x) { return x / (1.0f + __expf(-x)); }

// ---------------- f32 -> bf16 convert ----------------
__global__ __launch_bounds__(256) void cvt_bf16(const float* __restrict__ in,
                                                u16* __restrict__ out, int n) {
    int i = (blockIdx.x * 256 + threadIdx.x) * 8;
    if (i >= n) return;
    float4 a = *(const float4*)(in + i);
    float4 b = *(const float4*)(in + i + 4);
    uint4 pk;
    pk.x = (u32)f2bf(a.x) | ((u32)f2bf(a.y) << 16);
    pk.y = (u32)f2bf(a.z) | ((u32)f2bf(a.w) << 16);
    pk.z = (u32)f2bf(b.x) | ((u32)f2bf(b.y) << 16);
    pk.w = (u32)f2bf(b.z) | ((u32)f2bf(b.w) << 16);
    *(uint4*)(out + i) = pk;
}

// ---------------- m97-style 128x128 LDS GEMM, bf16 in, bf16 out ----------------
__global__ __launch_bounds__(256, 2) void gemm_bf16(const u16* __restrict__ A,
                                                    const u16* __restrict__ W,
                                                    u16* __restrict__ C, int ldc) {
    __shared__ __align__(16) u16 sm[32768];  // 64 KB: 2 bufs x (A 16KB + B 16KB)
    const int tid = threadIdx.x;
    const int w = tid >> 6, lane = tid & 63, g = lane >> 4, c = lane & 15;
    const int m0 = blockIdx.y * 128, n0 = blockIdx.x * 128;
    const int wm = (w >> 1) * 64, wn = (w & 1) * 64;

    f32x4 acc[4][4];
#pragma unroll
    for (int i = 0; i < 4; i++)
#pragma unroll
        for (int j = 0; j < 4; j++) acc[i][j] = (f32x4){0.f, 0.f, 0.f, 0.f};

    const int sr = tid >> 3;
    const int cb = (tid & 7) * 16;

#define GLDSG(gp, lofs) __builtin_amdgcn_global_load_lds((const AS1 void*)(gp), \
        (AS3 void*)((AS3 char*)(char*)sm + (lofs)), 16, 0, 0)

#define GSTAGE(kt, bi)                                                        \
    {                                                                         \
        const char* ab = (const char*)(A + (long)m0 * DD + (kt) * 64);        \
        const char* wb = (const char*)(W + (long)n0 * DD + (kt) * 64);        \
        _Pragma("unroll")                                                     \
        for (int i = 0; i < 4; i++) {                                         \
            int r = i * 32 + sr;                                              \
            int so = r * 2048 + (cb ^ ((r & 7) << 4));                        \
            int dof = (bi) * 32768 + i * 4096 + tid * 16;                     \
            GLDSG(ab + so, dof);                                              \
            GLDSG(wb + so, dof + 16384);                                      \
        }                                                                     \
    }

    GSTAGE(0, 0);
    __syncthreads();

    const int sw = (c & 7) << 4;
    for (int kt = 0; kt < 16; kt++) {
        const int bi = kt & 1;
        if (kt < 15) GSTAGE(kt + 1, bi ^ 1);
        const int ba = bi * 32768;
#pragma unroll
        for (int ks = 0; ks < 2; ks++) {
            short8 av[4], bvv[4];
#pragma unroll
            for (int mt = 0; mt < 4; mt++)
                av[mt] = *(const short8*)((const char*)sm + ba +
                         (wm + 16 * mt + c) * 128 + ((ks * 64 + g * 16) ^ sw));
#pragma unroll
            for (int nt = 0; nt < 4; nt++)
                bvv[nt] = *(const short8*)((const char*)sm + ba + 16384 +
                          (wn + 16 * nt + c) * 128 + ((ks * 64 + g * 16) ^ sw));
#pragma unroll
            for (int mt = 0; mt < 4; mt++)
#pragma unroll
                for (int nt = 0; nt < 4; nt++)
                    acc[mt][nt] = __builtin_amdgcn_mfma_f32_16x16x32_bf16(av[mt], bvv[nt], acc[mt][nt], 0, 0, 0);
        }
        __syncthreads();
    }

#pragma unroll
    for (int mt = 0; mt < 4; mt++)
#pragma unroll
        for (int nt = 0; nt < 4; nt++)
#pragma unroll
            for (int r = 0; r < 4; r++)
                C[(long)(m0 + wm + 16 * mt + 4 * g + r) * ldc + n0 + wn + 16 * nt + c] =
                    f2bf(acc[mt][nt][r]);
#undef GSTAGE
#undef GLDSG
}

// ---------------- causal depthwise conv (K=4) + silu + silu (+ l2norm), bf16 io ----------------
template <bool NORM>
__global__ __launch_bounds__(256) void conv_silu(const u16* __restrict__ in,
                                                 const float* __restrict__ cw,
                                                 u16* __restrict__ out, int Lc, int lsel,
                                                 int istride, int ioff) {
    int b, l;
    if (lsel >= 0) { b = blockIdx.x; l = lsel; }
    else { b = blockIdx.x / Lc; l = blockIdx.x % Lc; }
    int t = threadIdx.x;
    int d = t * 4;

    float w0[4], w1[4], w2[4], w3[4];
    const float4* cw4 = (const float4*)cw;
    *(float4*)w0 = cw4[d + 0];
    *(float4*)w1 = cw4[d + 1];
    *(float4*)w2 = cw4[d + 2];
    *(float4*)w3 = cw4[d + 3];

    const u16* base = in + (long)b * Lc * istride + ioff + d;
    float a0 = 0.f, a1 = 0.f, a2 = 0.f, a3 = 0.f;
#pragma unroll
    for (int j = 0; j < 4; j++) {
        int r = l - 3 + j;
        if (r >= 0) {
            uint2 v = *(const uint2*)(base + (long)r * istride);
            a0 += bf2f((u16)(v.x & 0xffff)) * w0[j];
            a1 += bf2f((u16)(v.x >> 16)) * w1[j];
            a2 += bf2f((u16)(v.y & 0xffff)) * w2[j];
            a3 += bf2f((u16)(v.y >> 16)) * w3[j];
        }
    }
    float y0 = silu_f(silu_f(a0));
    float y1 = silu_f(silu_f(a1));
    float y2 = silu_f(silu_f(a2));
    float y3 = silu_f(silu_f(a3));

    if (NORM) {
        float ss = y0 * y0 + y1 * y1 + y2 * y2 + y3 * y3;
#pragma unroll
        for (int m = 1; m < 64; m <<= 1) ss += __shfl_xor(ss, m);
        float nrm = sqrtf(ss);
        float sc = 1.0f / fmaxf(nrm, 1e-12f);
        y0 *= sc; y1 *= sc; y2 *= sc; y3 *= sc;
    }
    uint2 o;
    o.x = (u32)f2bf(y0) | ((u32)f2bf(y1) << 16);
    o.y = (u32)f2bf(y2) | ((u32)f2bf(y3) << 16);
    *(uint2*)(out + ((long)b * Lc + l) * DD + d) = o;
}

// ---------------- tiny q raw GEMM (rows l = L-4..L-1 only), bf16 out ----------------
__global__ __launch_bounds__(256) void qraw_gemm(const float* __restrict__ x,
                                                 const float* __restrict__ Wq,
                                                 u16* __restrict__ Rq) {
    int gid = blockIdx.x * 4 + (threadIdx.x >> 6);
    int lane = threadIdx.x & 63;
    int m = gid >> 10;
    int n = gid & 1023;
    int b = m >> 2, j = m & 3;
    int l = LL - 4 + j;
    const float* xr = x + ((long)b * LL + l) * DD + lane * 16;
    const float* wr = Wq + (long)n * DD + lane * 16;
    float s = 0.f;
#pragma unroll
    for (int u = 0; u < 4; u++) {
        float4 a = *(const float4*)(xr + u * 4);
        float4 w = *(const float4*)(wr + u * 4);
        s += a.x * w.x + a.y * w.y + a.z * w.z + a.w * w.w;
    }
#pragma unroll
    for (int mm = 1; mm < 64; mm <<= 1) s += __shfl_xor(s, mm);
    if (lane == 0) Rq[(long)m * DD + n] = f2bf(s);
}

// ---------------- beta (reads bf16 x) ----------------
__global__ __launch_bounds__(64) void beta_kernel(const u16* __restrict__ xb,
                                                  const float* __restrict__ Wb,
                                                  float* __restrict__ beta) {
    int bl = blockIdx.x;
    int lane = threadIdx.x;
    const u16* xr = xb + (long)bl * DD + lane * 16;
    uint4 p0 = *(const uint4*)xr;
    uint4 p1 = *(const uint4*)(xr + 8);
    u32 pw[8] = {p0.x, p0.y, p0.z, p0.w, p1.x, p1.y, p1.z, p1.w};
    float xv[16];
#pragma unroll
    for (int u = 0; u < 8; u++) {
        xv[2 * u]     = bf2f((u16)(pw[u] & 0xffff));
        xv[2 * u + 1] = bf2f((u16)(pw[u] >> 16));
    }
#pragma unroll
    for (int h = 0; h < 4; h++) {
        const float* wr = Wb + (long)h * DD + lane * 16;
        float s = 0.f;
#pragma unroll
        for (int u = 0; u < 4; u++) {
            float4 w = *(const float4*)(wr + u * 4);
            s += xv[4 * u] * w.x + xv[4 * u + 1] * w.y + xv[4 * u + 2] * w.z + xv[4 * u + 3] * w.w;
        }
#pragma unroll
        for (int m = 1; m < 64; m <<= 1) s += __shfl_xor(s, m);
        if (lane == 0) beta[(long)bl * HH + h] = 1.0f / (1.0f + __expf(-s));
    }
}

// ---------------- prep per (bh, chunk) — bank-conflict-free rewrite ----------------
// Outputs: LK_g = -Linv*K  [64 t][256 d] swz ; BKT_g = (b K)^T [256 d][64 t] swz ;
//          LV_g = +Linv*V  in scan u32-plane layout.
// LDS map: [0,32768) KT then VT ; [32768,65536) LI f32 then LK/LV stage ; [65536,74240) WL then LIbf.
__global__ __launch_bounds__(256, 2) void prep_chunk(
    const u16* __restrict__ KN, const u16* __restrict__ VN, const float* __restrict__ BETA,
    u16* __restrict__ LK_g, u16* __restrict__ BKT_g, u16* __restrict__ LV_g)
{
    __shared__ __align__(16) char pm[74240];
    __shared__ float bv[64];
    const int bh = blockIdx.x >> 5, q = blockIdx.x & 31;
    const int b = bh >> 2, h = bh & 3;
    const int tid = threadIdx.x;
    const int w = tid >> 6, lane = tid & 63, g = lane >> 4, c = lane & 15;
    const long cb = (long)(bh * 32 + q);
    const long kbase = ((long)b * LL + 64 * q) * DD + h * HD;
    float* LI = (float*)(pm + 32768);   // [64][65]
    u16* WL = (u16*)(pm + 65536);       // [64][68]

    // ---- phase 0: bv + KT build (global column reads -> swizzled b128 writes) + LI init ----
    if (tid < 64) bv[tid] = BETA[((long)b * LL + 64 * q + tid) * HH + h];
    {
        const u16* kp = KN + kbase + tid;   // column d = tid
#pragma unroll
        for (int tb = 0; tb < 8; tb++) {
            u16 vals[8];
#pragma unroll
            for (int j = 0; j < 8; j++) vals[j] = kp[(long)(8 * tb + j) * DD];
            *(uint4*)(pm + tid * 128 + ((tb ^ (tid & 7)) << 4)) = *(uint4*)vals;
        }
    }
    for (int ii = tid; ii < 4160; ii += 256) LI[ii] = (ii % 66 == 0) ? 1.0f : 0.0f;
    __syncthreads();

    // ---- phase 1: A = K K^T (fragments from global), WL = A*diag(b) ----
    {
        f32x4 aacc[4];
#pragma unroll
        for (int nt = 0; nt < 4; nt++) aacc[nt] = (f32x4){0.f, 0.f, 0.f, 0.f};
#pragma unroll
        for (int q8 = 0; q8 < 8; q8++) {
            short8 af = *(const short8*)(KN + kbase + (long)(16 * w + c) * DD + 32 * q8 + 8 * g);
#pragma unroll
            for (int nt = 0; nt < 4; nt++) {
                short8 bf = *(const short8*)(KN + kbase + (long)(16 * nt + c) * DD + 32 * q8 + 8 * g);
                aacc[nt] = __builtin_amdgcn_mfma_f32_16x16x32_bf16(af, bf, aacc[nt], 0, 0, 0);
            }
        }
#pragma unroll
        for (int nt = 0; nt < 4; nt++)
#pragma unroll
            for (int r = 0; r < 4; r++)
                WL[(16 * w + 4 * g + r) * 68 + 16 * nt + c] = f2bf(aacc[nt][r] * bv[16 * nt + c]);
    }
    __syncthreads();

    // ---- phase 2: forward substitution (wave w owns cols [16w,16w+16)) ----
    {
        const int col = 16 * w + c;
        for (int t = 1; t < 64; t++) {
            float acc = 0.f;
            for (int s = g; s < t; s += 4)
                acc += bf2f(WL[t * 68 + s]) * LI[s * 65 + col];
            acc += __shfl_xor(acc, 16);
            acc += __shfl_xor(acc, 32);
            if (g == 0) LI[t * 65 + col] = ((t == col) ? 1.0f : 0.0f) - acc;
        }
    }
    __syncthreads();

    // ---- phase 3: LIbf [64 t][64 s] swz (overwrites WL) ; BKT out (reads KT) ----
    for (int ii = tid; ii < 4096; ii += 256) {
        int t = ii >> 6, s = ii & 63;
        float v = LI[t * 65 + s];
        *(u16*)(pm + 65536 + t * 128 + ((((s >> 3) ^ (t & 7)) << 4) + (s & 7) * 2)) = f2bf(v);
    }
    for (int ii = tid; ii < 2048; ii += 256) {
        int d = ii >> 3, bl = ii & 7;
        u16 vals[8];
        *(uint4*)vals = *(const uint4*)(pm + d * 128 + bl * 16);
        int t0 = (bl ^ (d & 7)) << 3;
#pragma unroll
        for (int j = 0; j < 8; j++) vals[j] = f2bf(bf2f(vals[j]) * bv[t0 + j]);
        *(uint4*)((char*)(BKT_g + cb * 16384) + d * 128 + bl * 16) = *(uint4*)vals;
    }
    __syncthreads();

    // ---- phase 4: LK' = -Linv*K, m=t orientation (A=LIbf rows, B=KT rows) ----
    {
        f32x4 lk[4][4];  // [mt][dn]
#pragma unroll
        for (int i = 0; i < 4; i++)
#pragma unroll
            for (int j = 0; j < 4; j++) lk[i][j] = (f32x4){0.f, 0.f, 0.f, 0.f};
#pragma unroll
        for (int qs = 0; qs < 2; qs++) {
            short8 aL[4], bK[4];
#pragma unroll
            for (int mt = 0; mt < 4; mt++)
                aL[mt] = *(const short8*)(pm + 65536 + (16 * mt + c) * 128 +
                                          (((qs * 4 + g) ^ (c & 7)) << 4));
#pragma unroll
            for (int dn = 0; dn < 4; dn++)
                bK[dn] = *(const short8*)(pm + (64 * w + 16 * dn + c) * 128 +
                                          (((qs * 4 + g) ^ (c & 7)) << 4));
#pragma unroll
            for (int mt = 0; mt < 4; mt++)
#pragma unroll
                for (int dn = 0; dn < 4; dn++)
                    lk[mt][dn] = __builtin_amdgcn_mfma_f32_16x16x32_bf16(aL[mt], bK[dn], lk[mt][dn], 0, 0, 0);
        }
#pragma unroll
        for (int mt = 0; mt < 4; mt++)
#pragma unroll
            for (int dn = 0; dn < 4; dn++)
#pragma unroll
                for (int r = 0; r < 4; r++) {
                    int t = 16 * mt + 4 * g + r;
                    int d = 64 * w + 16 * dn + c;
                    *(u16*)(pm + 32768 + t * 512 +
                            ((((d >> 3) ^ (t & 7)) << 4) + (d & 7) * 2)) = f2bf(-lk[mt][dn][r]);
                }
    }
    __syncthreads();

    // ---- phase 5: copy LK stage -> global ; VT build (overwrites KT) ----
    for (int ii = tid; ii < 2048; ii += 256)
        ((uint4*)(LK_g + cb * 16384))[ii] = ((const uint4*)(pm + 32768))[ii];
    {
        const u16* vp = VN + kbase + tid;
#pragma unroll
        for (int tb = 0; tb < 8; tb++) {
            u16 vals[8];
#pragma unroll
            for (int j = 0; j < 8; j++) vals[j] = vp[(long)(8 * tb + j) * DD];
            *(uint4*)(pm + tid * 128 + ((tb ^ (tid & 7)) << 4)) = *(uint4*)vals;
        }
    }
    __syncthreads();

    // ---- phase 6: LV' = +Linv*V, m=t orientation; epilogue direct to u32 scan planes ----
    {
        f32x4 lv[4][4];
#pragma unroll
        for (int i = 0; i < 4; i++)
#pragma unroll
            for (int j = 0; j < 4; j++) lv[i][j] = (f32x4){0.f, 0.f, 0.f, 0.f};
#pragma unroll
        for (int qs = 0; qs < 2; qs++) {
            short8 aL[4], bV[4];
#pragma unroll
            for (int mt = 0; mt < 4; mt++)
                aL[mt] = *(const short8*)(pm + 65536 + (16 * mt + c) * 128 +
                                          (((qs * 4 + g) ^ (c & 7)) << 4));
#pragma unroll
            for (int dn = 0; dn < 4; dn++)
                bV[dn] = *(const short8*)(pm + (64 * w + 16 * dn + c) * 128 +
                                          (((qs * 4 + g) ^ (c & 7)) << 4));
#pragma unroll
            for (int mt = 0; mt < 4; mt++)
#pragma unroll
                for (int dn = 0; dn < 4; dn++)
                    lv[mt][dn] = __builtin_amdgcn_mfma_f32_16x16x32_bf16(aL[mt], bV[dn], lv[mt][dn], 0, 0, 0);
        }
        u32* LVs = (u32*)(pm + 32768);
#pragma unroll
        for (int mt = 0; mt < 4; mt++)
#pragma unroll
            for (int dn = 0; dn < 4; dn++) {
                int iblk = 2 * w + (dn >> 1);
                int it = dn & 1;
                int base = iblk * 1024 + 64 * (2 * mt + it) + 16 * g + c;
                LVs[base]       = (u32)f2bf(lv[mt][dn][0]) | ((u32)f2bf(lv[mt][dn][1]) << 16);
                LVs[base + 512] = (u32)f2bf(lv[mt][dn][2]) | ((u32)f2bf(lv[mt][dn][3]) << 16);
            }
    }
    __syncthreads();

    // ---- phase 7: copy LV stage -> global ----
    for (int ii = tid; ii < 2048; ii += 256)
        ((uint4*)(LV_g + cb * 16384))[ii] = ((const uint4*)(pm + 32768))[ii];
}

// ---------------- chunked scan: 8 waves, 2 GEMMs/chunk, all-b128 LDS frags ----------------
__global__ __launch_bounds__(512, 1) void scan_chunked(
    const u16* __restrict__ LK_g, const u16* __restrict__ BKT_g,
    const u16* __restrict__ LV_g, const u16* __restrict__ QN,
    float* __restrict__ out, float* __restrict__ ORAW)
{
    __shared__ __align__(16) char smem[159744];
    const int blk = blockIdx.x;
    const int bh = blk & 31, iblk = blk >> 5;
    const int b = bh >> 2, h = bh & 3;
    const int row0 = iblk * 32;
    const int tid = threadIdx.x;
    const int w = tid >> 6, lane = tid & 63, g = lane >> 4, c = lane & 15;
    const int mt = w >> 1, it = w & 1;
    const int sw = (c & 7) << 4;

#define GLDS16(gp, lofs) __builtin_amdgcn_global_load_lds((const AS1 void*)(gp), \
        (AS3 void*)((AS3 char*)smem + (lofs)), 16, 0, 0)
#define GLDS4(gp, lofs) __builtin_amdgcn_global_load_lds((const AS1 void*)(gp), \
        (AS3 void*)((AS3 char*)smem + (lofs)), 4, 0, 0)
#define STAGE_LK(qq, bi) { const char* gp = (const char*)(LK_g + (long)(bh * 32 + (qq)) * 16384); \
    _Pragma("unroll") for (int i_ = 0; i_ < 4; i_++) GLDS16(gp + i_ * 8192 + tid * 16, (bi) * 32768 + i_ * 8192 + tid * 16); }
#define STAGE_BKT(qq, bi) { const char* gp = (const char*)(BKT_g + (long)(bh * 32 + (qq)) * 16384); \
    _Pragma("unroll") for (int i_ = 0; i_ < 4; i_++) GLDS16(gp + i_ * 8192 + tid * 16, 65536 + (bi) * 32768 + i_ * 8192 + tid * 16); }
#define STAGE_LV(qq, bi) { const char* gp = (const char*)LV_g + (long)(bh * 32 + (qq)) * 32768 + iblk * 4096; \
    GLDS4(gp + tid * 4, 131072 + (bi) * 4096 + tid * 4); \
    GLDS4(gp + 2048 + tid * 4, 131072 + (bi) * 4096 + 2048 + tid * 4); }

    f32x4 S[2][2];
#pragma unroll
    for (int si = 0; si < 2; si++)
#pragma unroll
        for (int sj = 0; sj < 2; sj++) S[si][sj] = (f32x4){0.f, 0.f, 0.f, 0.f};

    STAGE_LK(0, 0); STAGE_BKT(0, 0); STAGE_LV(0, 0);

    for (int q = 0; q < 32; ++q) {
        const int cur = q & 1;
        if (q < 31) {
            STAGE_LK(q + 1, cur ^ 1); STAGE_BKT(q + 1, cur ^ 1); STAGE_LV(q + 1, cur ^ 1);
            asm volatile("s_waitcnt vmcnt(10)" ::: "memory");
        } else {
            asm volatile("s_waitcnt vmcnt(0)" ::: "memory");
        }
        __builtin_amdgcn_s_barrier();   // all waves' cur-buffer loads landed (race fix)
        __builtin_amdgcn_sched_barrier(0);

        const char* lkb = smem + cur * 32768;
        const char* bkb = smem + 65536 + cur * 32768;
        const char* lvb = smem + 131072 + cur * 4096;

        // ---- W = LK' * S^T + LV'  (wave tile: t-rows 16mt.., i-cols 16it..) ----
        u32 l0 = *(const u32*)(lvb + tid * 4);
        u32 l1 = *(const u32*)(lvb + 2048 + tid * 4);
        f32x4 w0, w1;
        w0[0] = bf2f((u16)(l0 & 0xffff)); w0[1] = bf2f((u16)(l0 >> 16));
        w0[2] = bf2f((u16)(l1 & 0xffff)); w0[3] = bf2f((u16)(l1 >> 16));
        w1 = (f32x4){0.f, 0.f, 0.f, 0.f};
        if (q > 0) {
            const int arow = (16 * mt + c) * 512;
            const int brow = (16 * it + c) * 512;
#pragma unroll
            for (int q8 = 0; q8 < 8; q8++) {
                short8 av = *(const short8*)(lkb + arow + (((q8 * 4 + g) << 4) ^ sw));
                short8 bv8 = *(const short8*)(smem + 143360 + brow + (((q8 * 4 + g) << 4) ^ sw));
                if (q8 & 1) w1 = __builtin_amdgcn_mfma_f32_16x16x32_bf16(av, bv8, w1, 0, 0, 0);
                else        w0 = __builtin_amdgcn_mfma_f32_16x16x32_bf16(av, bv8, w0, 0, 0, 0);
            }
#pragma unroll
            for (int r = 0; r < 4; r++) w0[r] += w1[r];
        }

        // ---- all-gather W into WLDS [32 i][64 t] swz ----
        {
            char* ub = smem + 139264 + (16 * it + c) * 128;
#pragma unroll
            for (int r = 0; r < 4; r++) {
                int t = 16 * mt + 4 * g + r;
                *(u16*)(ub + ((((t >> 3) << 4) ^ sw) + (t & 7) * 2)) = f2bf(w0[r]);
            }
        }
        asm volatile("s_waitcnt lgkmcnt(0)" ::: "memory");
        __builtin_amdgcn_s_barrier();
        __builtin_amdgcn_sched_barrier(0);

        // ---- S += W^T * (bK)  (wave owns cols j in [32w, 32w+32)) ----
#pragma unroll
        for (int Qp = 0; Qp < 2; Qp++) {
            const int tof = ((Qp * 4 + g) << 4) ^ sw;
            short8 a0 = *(const short8*)(smem + 139264 + c * 128 + tof);
            short8 a1 = *(const short8*)(smem + 139264 + (16 + c) * 128 + tof);
            short8 b0 = *(const short8*)(bkb + (32 * w + c) * 128 + tof);
            short8 b1 = *(const short8*)(bkb + (32 * w + 16 + c) * 128 + tof);
            S[0][0] = __builtin_amdgcn_mfma_f32_16x16x32_bf16(a0, b0, S[0][0], 0, 0, 0);
            S[0][1] = __builtin_amdgcn_mfma_f32_16x16x32_bf16(a0, b1, S[0][1], 0, 0, 0);
            S[1][0] = __builtin_amdgcn_mfma_f32_16x16x32_bf16(a1, b0, S[1][0], 0, 0, 0);
            S[1][1] = __builtin_amdgcn_mfma_f32_16x16x32_bf16(a1, b1, S[1][1], 0, 0, 0);
        }

        // ---- S -> TS [32 i][256 j] swz bf16 for next chunk ----
        if (q < 31) {
#pragma unroll
            for (int si = 0; si < 2; si++)
#pragma unroll
                for (int sj = 0; sj < 2; sj++)
#pragma unroll
                    for (int r = 0; r < 4; r++) {
                        int i = 16 * si + 4 * g + r;
                        *(u16*)(smem + 143360 + i * 512 +
                                ((((4 * w + 2 * sj + (c >> 3)) << 4) ^ ((i & 7) << 4)) + (c & 7) * 2)) =
                            f2bf(S[si][sj][r]);
                    }
        }
        asm volatile("s_waitcnt lgkmcnt(0)" ::: "memory");
        __builtin_amdgcn_s_barrier();
        __builtin_amdgcn_sched_barrier(0);
    }

    // ---- epilogue: o = S_final q ; S_final -> out ----
    float op[2][4];
#pragma unroll
    for (int si = 0; si < 2; si++)
#pragma unroll
        for (int r = 0; r < 4; r++) op[si][r] = 0.f;
#pragma unroll
    for (int sj = 0; sj < 2; sj++) {
        const float qv = bf2f(QN[((long)b * 4 + 3) * DD + h * HD + 32 * w + 16 * sj + c]);
#pragma unroll
        for (int si = 0; si < 2; si++)
#pragma unroll
            for (int r = 0; r < 4; r++) op[si][r] += S[si][sj][r] * qv;
    }
#pragma unroll
    for (int si = 0; si < 2; si++)
#pragma unroll
        for (int r = 0; r < 4; r++) {
            float v = op[si][r];
            v += __shfl_xor(v, 1); v += __shfl_xor(v, 2);
            v += __shfl_xor(v, 4); v += __shfl_xor(v, 8);
            op[si][r] = v;
        }
    float* red = (float*)smem;
    if (c == 0) {
#pragma unroll
        for (int si = 0; si < 2; si++)
#pragma unroll
            for (int r = 0; r < 4; r++) red[w * 32 + 16 * si + 4 * g + r] = op[si][r];
    }
    __syncthreads();
    if (tid < 32) {
        float o = 0.f;
#pragma unroll
        for (int ww = 0; ww < 8; ww++) o += red[ww * 32 + tid];
        ORAW[(long)b * DD + h * HD + row0 + tid] = o;
    }
#pragma unroll
    for (int si = 0; si < 2; si++)
#pragma unroll
        for (int sj = 0; sj < 2; sj++)
#pragma unroll
            for (int r = 0; r < 4; r++)
                out[8192 + ((long)(bh * 256 + row0 + 16 * si + 4 * g + r)) * 256
                    + 32 * w + 16 * sj + c] = S[si][sj][r];
#undef GLDS16
#undef GLDS4
#undef STAGE_LK
#undef STAGE_BKT
#undef STAGE_LV
}

// ---------------- RMSNorm ----------------
__global__ __launch_bounds__(256) void rmsnorm_kernel(const float* __restrict__ o_raw,
                                                      const float* __restrict__ w,
                                                      float* __restrict__ o_norm) {
    int b = blockIdx.x, t = threadIdx.x;
    float4 v = *(const float4*)(o_raw + (long)b * DD + t * 4);
    float ss = v.x * v.x + v.y * v.y + v.z * v.z + v.w * v.w;
#pragma unroll
    for (int m = 1; m < 64; m <<= 1) ss += __shfl_xor(ss, m);
    __shared__ float wsum[4];
    if ((t & 63) == 0) wsum[t >> 6] = ss;
    __syncthreads();
    float tot = wsum[0] + wsum[1] + wsum[2] + wsum[3];
    float sc = rsqrtf(tot / (float)DD + 1e-5f);
    float4 wv = *(const float4*)(w + t * 4);
    float4 r = make_float4(v.x * sc * wv.x, v.y * sc * wv.y, v.z * sc * wv.z, v.w * sc * wv.w);
    *(float4*)(o_norm + (long)b * DD + t * 4) = r;
}

// ---------------- out projection ----------------
__global__ __launch_bounds__(256) void outproj_kernel(const float* __restrict__ o_norm,
                                                      const float* __restrict__ Wout,
                                                      float* __restrict__ out) {
    int gid = blockIdx.x * 4 + (threadIdx.x >> 6);
    int lane = threadIdx.x & 63;
    int b = gid >> 10, n = gid & 1023;
    const float* orow = o_norm + (long)b * DD + lane * 16;
    const float* wrow = Wout + (long)n * DD + lane * 16;
    float s = 0.f;
#pragma unroll
    for (int u = 0; u < 4; u++) {
        float4 a = *(const float4*)(orow + u * 4);
        float4 w = *(const float4*)(wrow + u * 4);
        s += a.x * w.x + a.y * w.y + a.z * w.z + a.w * w.w;
    }
#pragma unroll
    for (int m = 1; m < 64; m <<= 1) s += __shfl_xor(s, m);
    if (lane == 0) out[(long)b * DD + n] = s;
}

extern "C" void kernel_launch(void* const* d_in, const int* in_sizes, int n_in,
                              void* d_out, int out_size, void* d_ws, size_t ws_size,
                              hipStream_t stream) {
    const float* x     = (const float*)d_in[0];
    const float* Wq    = (const float*)d_in[1];
    const float* Wk    = (const float*)d_in[2];
    const float* Wv    = (const float*)d_in[3];
    const float* cq    = (const float*)d_in[4];
    const float* ck    = (const float*)d_in[5];
    const float* cv    = (const float*)d_in[6];
    const float* Wbeta = (const float*)d_in[7];
    const float* rms_w = (const float*)d_in[8];
    const float* Wout  = (const float*)d_in[9];
    float* out = (float*)d_out;

    char* ws = (char*)d_ws;
    u16* XB     = (u16*)(ws + 0);           // 32 MB (dead after gemm+beta)
    u16* BKT_g  = (u16*)(ws + 0);           // overlays XB
    u16* WKVB   = (u16*)(ws + 33554432);    // 4 MB [Wk;Wv]
    u16* R      = (u16*)(ws + 37748736);    // 64 MB [16384][2048] (dead after convs)
    u16* LK_g   = (u16*)(ws + 37748736);    // overlays R (32 MB)
    u16* LV_g   = (u16*)(ws + 71303168);    // overlays R (32 MB)
    u16* KN     = (u16*)(ws + 104857600);   // 32 MB
    u16* VN     = (u16*)(ws + 138412032);   // 32 MB
    float* BETA = (float*)(ws + 171966464); // 256 KB
    u16* RQ     = (u16*)(ws + 172228608);   // 64 KB
    u16* QN     = (u16*)(ws + 172294144);   // 64 KB
    float* ORAW = (float*)(ws + 172359680); // 32 KB
    float* ONRM = (float*)(ws + 172392448); // 32 KB

    cvt_bf16<<<8192, 256, 0, stream>>>(x, XB, 16777216);
    cvt_bf16<<<512, 256, 0, stream>>>(Wk, WKVB, 1048576);
    cvt_bf16<<<512, 256, 0, stream>>>(Wv, WKVB + 1048576, 1048576);

    // fused k|v projection: C = [16384][2048]
    gemm_bf16<<<dim3(16, 128), 256, 0, stream>>>(XB, WKVB, R, 2048);
    conv_silu<true><<<BB * LL, 256, 0, stream>>>(R, ck, KN, LL, -1, 2048, 0);
    conv_silu<false><<<BB * LL, 256, 0, stream>>>(R, cv, VN, LL, -1, 2048, 1024);
    qraw_gemm<<<8192, 256, 0, stream>>>(x, Wq, RQ);
    conv_silu<true><<<BB, 256, 0, stream>>>(RQ, cq, QN, 4, 3, 1024, 0);
    beta_kernel<<<BB * LL, 64, 0, stream>>>(XB, Wbeta, BETA);

    prep_chunk<<<1024, 256, 0, stream>>>(KN, VN, BETA, LK_g, BKT_g, LV_g);
    scan_chunked<<<256, 512, 0, stream>>>(LK_g, BKT_g, LV_g, QN, out, ORAW);

    rmsnorm_kernel<<<BB, 256, 0, stream>>>(ORAW, rms_w, ONRM);
    outproj_kernel<<<2048, 256, 0, stream>>>(ONRM, Wout, out);
}

// Round 6
// 326.946 us; speedup vs baseline: 4.8854x; 1.3125x over previous
//
#include <hip/hip_runtime.h>

#define LL 2048
#define BB 8
#define DD 1024
#define HH 4
#define HD 256

#define AS1 __attribute__((address_space(1)))
#define AS3 __attribute__((address_space(3)))

typedef __attribute__((ext_vector_type(8))) short short8;
typedef __attribute__((ext_vector_type(4))) float f32x4;
typedef unsigned short u16;
typedef unsigned int u32;

static __device__ __forceinline__ u16 f2bf(float f) {
    u32 u = __float_as_uint(f);
    return (u16)((u + 0x7fffu + ((u >> 16) & 1u)) >> 16);
}
static __device__ __forceinline__ float bf2f(u16 v) {
    return __uint_as_float(((u32)v) << 16);
}
static __device__ __forceinline__ float silu_f(float x) { return x / (1.0f + __expf(-x)); }

// ---------------- f32 -> bf16 convert ----------------
__global__ __launch_bounds__(256) void cvt_bf16(const float* __restrict__ in,
                                                u16* __restrict__ out, int n) {
    int i = (blockIdx.x * 256 + threadIdx.x) * 8;
    if (i >= n) return;
    float4 a = *(const float4*)(in + i);
    float4 b = *(const float4*)(in + i + 4);
    uint4 pk;
    pk.x = (u32)f2bf(a.x) | ((u32)f2bf(a.y) << 16);
    pk.y = (u32)f2bf(a.z) | ((u32)f2bf(a.w) << 16);
    pk.z = (u32)f2bf(b.x) | ((u32)f2bf(b.y) << 16);
    pk.w = (u32)f2bf(b.z) | ((u32)f2bf(b.w) << 16);
    *(uint4*)(out + i) = pk;
}

// ---------------- m97-style 128x128 LDS GEMM, bf16 in, bf16 out ----------------
__global__ __launch_bounds__(256, 2) void gemm_bf16(const u16* __restrict__ A,
                                                    const u16* __restrict__ W,
                                                    u16* __restrict__ C, int ldc) {
    __shared__ __align__(16) u16 sm[32768];  // 64 KB: 2 bufs x (A 16KB + B 16KB)
    const int tid = threadIdx.x;
    const int w = tid >> 6, lane = tid & 63, g = lane >> 4, c = lane & 15;
    const int m0 = blockIdx.y * 128, n0 = blockIdx.x * 128;
    const int wm = (w >> 1) * 64, wn = (w & 1) * 64;

    f32x4 acc[4][4];
#pragma unroll
    for (int i = 0; i < 4; i++)
#pragma unroll
        for (int j = 0; j < 4; j++) acc[i][j] = (f32x4){0.f, 0.f, 0.f, 0.f};

    const int sr = tid >> 3;
    const int cb = (tid & 7) * 16;

#define GLDSG(gp, lofs) __builtin_amdgcn_global_load_lds((const AS1 void*)(gp), \
        (AS3 void*)((AS3 char*)(char*)sm + (lofs)), 16, 0, 0)

#define GSTAGE(kt, bi)                                                        \
    {                                                                         \
        const char* ab = (const char*)(A + (long)m0 * DD + (kt) * 64);        \
        const char* wb = (const char*)(W + (long)n0 * DD + (kt) * 64);        \
        _Pragma("unroll")                                                     \
        for (int i = 0; i < 4; i++) {                                         \
            int r = i * 32 + sr;                                              \
            int so = r * 2048 + (cb ^ ((r & 7) << 4));                        \
            int dof = (bi) * 32768 + i * 4096 + tid * 16;                     \
            GLDSG(ab + so, dof);                                              \
            GLDSG(wb + so, dof + 16384);                                      \
        }                                                                     \
    }

    GSTAGE(0, 0);
    __syncthreads();

    const int sw = (c & 7) << 4;
    for (int kt = 0; kt < 16; kt++) {
        const int bi = kt & 1;
        if (kt < 15) GSTAGE(kt + 1, bi ^ 1);
        const int ba = bi * 32768;
#pragma unroll
        for (int ks = 0; ks < 2; ks++) {
            short8 av[4], bvv[4];
#pragma unroll
            for (int mt = 0; mt < 4; mt++)
                av[mt] = *(const short8*)((const char*)sm + ba +
                         (wm + 16 * mt + c) * 128 + ((ks * 64 + g * 16) ^ sw));
#pragma unroll
            for (int nt = 0; nt < 4; nt++)
                bvv[nt] = *(const short8*)((const char*)sm + ba + 16384 +
                          (wn + 16 * nt + c) * 128 + ((ks * 64 + g * 16) ^ sw));
#pragma unroll
            for (int mt = 0; mt < 4; mt++)
#pragma unroll
                for (int nt = 0; nt < 4; nt++)
                    acc[mt][nt] = __builtin_amdgcn_mfma_f32_16x16x32_bf16(av[mt], bvv[nt], acc[mt][nt], 0, 0, 0);
        }
        __syncthreads();
    }

#pragma unroll
    for (int mt = 0; mt < 4; mt++)
#pragma unroll
        for (int nt = 0; nt < 4; nt++)
#pragma unroll
            for (int r = 0; r < 4; r++)
                C[(long)(m0 + wm + 16 * mt + 4 * g + r) * ldc + n0 + wn + 16 * nt + c] =
                    f2bf(acc[mt][nt][r]);
#undef GSTAGE
#undef GLDSG
}

// ---------------- strip conv: 32 l's per block, sliding register window ----------------
template <bool NORM>
__global__ __launch_bounds__(256) void conv_strip(const u16* __restrict__ in,
                                                  const float* __restrict__ cw,
                                                  u16* __restrict__ out,
                                                  int istride, int ioff) {
    const int b = blockIdx.x >> 6;
    const int l0 = (blockIdx.x & 63) * 32;
    const int t = threadIdx.x;
    const int d = t * 4;

    float w0[4], w1[4], w2[4], w3[4];
    const float4* cw4 = (const float4*)cw;
    *(float4*)w0 = cw4[d + 0];
    *(float4*)w1 = cw4[d + 1];
    *(float4*)w2 = cw4[d + 2];
    *(float4*)w3 = cw4[d + 3];

    const u16* base = in + (long)b * LL * istride + ioff + d;
    u16* ob = out + ((long)b * LL) * DD + d;

#define DEC(r) ({ uint2 v_ = *(const uint2*)(base + (long)(r) * istride); \
    make_float4(bf2f((u16)(v_.x & 0xffff)), bf2f((u16)(v_.x >> 16)), \
                bf2f((u16)(v_.y & 0xffff)), bf2f((u16)(v_.y >> 16))); })

    float4 a1, a2, a3;
    if (l0 == 0) {
        a1 = make_float4(0.f, 0.f, 0.f, 0.f); a2 = a1; a3 = a1;
    } else {
        a1 = DEC(l0 - 3); a2 = DEC(l0 - 2); a3 = DEC(l0 - 1);
    }

#pragma unroll 2
    for (int i = 0; i < 32; i++) {
        const int l = l0 + i;
        float4 x = DEC(l);
        float y0 = a1.x * w0[0] + a2.x * w0[1] + a3.x * w0[2] + x.x * w0[3];
        float y1 = a1.y * w1[0] + a2.y * w1[1] + a3.y * w1[2] + x.y * w1[3];
        float y2 = a1.z * w2[0] + a2.z * w2[1] + a3.z * w2[2] + x.z * w2[3];
        float y3 = a1.w * w3[0] + a2.w * w3[1] + a3.w * w3[2] + x.w * w3[3];
        y0 = silu_f(silu_f(y0)); y1 = silu_f(silu_f(y1));
        y2 = silu_f(silu_f(y2)); y3 = silu_f(silu_f(y3));
        if (NORM) {
            float ss = y0 * y0 + y1 * y1 + y2 * y2 + y3 * y3;
#pragma unroll
            for (int m = 1; m < 64; m <<= 1) ss += __shfl_xor(ss, m);
            float sc = 1.0f / fmaxf(sqrtf(ss), 1e-12f);
            y0 *= sc; y1 *= sc; y2 *= sc; y3 *= sc;
        }
        uint2 o;
        o.x = (u32)f2bf(y0) | ((u32)f2bf(y1) << 16);
        o.y = (u32)f2bf(y2) | ((u32)f2bf(y3) << 16);
        *(uint2*)(ob + (long)l * DD) = o;
        a1 = a2; a2 = a3; a3 = x;
    }
#undef DEC
}

// ---------------- single-l conv (q tail) ----------------
template <bool NORM>
__global__ __launch_bounds__(256) void conv_silu(const u16* __restrict__ in,
                                                 const float* __restrict__ cw,
                                                 u16* __restrict__ out, int Lc, int lsel,
                                                 int istride, int ioff) {
    int b = blockIdx.x, l = lsel;
    int t = threadIdx.x;
    int d = t * 4;

    float w0[4], w1[4], w2[4], w3[4];
    const float4* cw4 = (const float4*)cw;
    *(float4*)w0 = cw4[d + 0];
    *(float4*)w1 = cw4[d + 1];
    *(float4*)w2 = cw4[d + 2];
    *(float4*)w3 = cw4[d + 3];

    const u16* base = in + (long)b * Lc * istride + ioff + d;
    float a0 = 0.f, a1 = 0.f, a2 = 0.f, a3 = 0.f;
#pragma unroll
    for (int j = 0; j < 4; j++) {
        int r = l - 3 + j;
        if (r >= 0) {
            uint2 v = *(const uint2*)(base + (long)r * istride);
            a0 += bf2f((u16)(v.x & 0xffff)) * w0[j];
            a1 += bf2f((u16)(v.x >> 16)) * w1[j];
            a2 += bf2f((u16)(v.y & 0xffff)) * w2[j];
            a3 += bf2f((u16)(v.y >> 16)) * w3[j];
        }
    }
    float y0 = silu_f(silu_f(a0));
    float y1 = silu_f(silu_f(a1));
    float y2 = silu_f(silu_f(a2));
    float y3 = silu_f(silu_f(a3));

    if (NORM) {
        float ss = y0 * y0 + y1 * y1 + y2 * y2 + y3 * y3;
#pragma unroll
        for (int m = 1; m < 64; m <<= 1) ss += __shfl_xor(ss, m);
        float sc = 1.0f / fmaxf(sqrtf(ss), 1e-12f);
        y0 *= sc; y1 *= sc; y2 *= sc; y3 *= sc;
    }
    uint2 o;
    o.x = (u32)f2bf(y0) | ((u32)f2bf(y1) << 16);
    o.y = (u32)f2bf(y2) | ((u32)f2bf(y3) << 16);
    *(uint2*)(out + ((long)b * Lc + l) * DD + d) = o;
}

// ---------------- tiny q raw GEMM (rows l = L-4..L-1 only), bf16 out ----------------
__global__ __launch_bounds__(256) void qraw_gemm(const float* __restrict__ x,
                                                 const float* __restrict__ Wq,
                                                 u16* __restrict__ Rq) {
    int gid = blockIdx.x * 4 + (threadIdx.x >> 6);
    int lane = threadIdx.x & 63;
    int m = gid >> 10;
    int n = gid & 1023;
    int b = m >> 2, j = m & 3;
    int l = LL - 4 + j;
    const float* xr = x + ((long)b * LL + l) * DD + lane * 16;
    const float* wr = Wq + (long)n * DD + lane * 16;
    float s = 0.f;
#pragma unroll
    for (int u = 0; u < 4; u++) {
        float4 a = *(const float4*)(xr + u * 4);
        float4 w = *(const float4*)(wr + u * 4);
        s += a.x * w.x + a.y * w.y + a.z * w.z + a.w * w.w;
    }
#pragma unroll
    for (int mm = 1; mm < 64; mm <<= 1) s += __shfl_xor(s, mm);
    if (lane == 0) Rq[(long)m * DD + n] = f2bf(s);
}

// ---------------- beta (reads bf16 x) ----------------
__global__ __launch_bounds__(64) void beta_kernel(const u16* __restrict__ xb,
                                                  const float* __restrict__ Wb,
                                                  float* __restrict__ beta) {
    int bl = blockIdx.x;
    int lane = threadIdx.x;
    const u16* xr = xb + (long)bl * DD + lane * 16;
    uint4 p0 = *(const uint4*)xr;
    uint4 p1 = *(const uint4*)(xr + 8);
    u32 pw[8] = {p0.x, p0.y, p0.z, p0.w, p1.x, p1.y, p1.z, p1.w};
    float xv[16];
#pragma unroll
    for (int u = 0; u < 8; u++) {
        xv[2 * u]     = bf2f((u16)(pw[u] & 0xffff));
        xv[2 * u + 1] = bf2f((u16)(pw[u] >> 16));
    }
#pragma unroll
    for (int h = 0; h < 4; h++) {
        const float* wr = Wb + (long)h * DD + lane * 16;
        float s = 0.f;
#pragma unroll
        for (int u = 0; u < 4; u++) {
            float4 w = *(const float4*)(wr + u * 4);
            s += xv[4 * u] * w.x + xv[4 * u + 1] * w.y + xv[4 * u + 2] * w.z + xv[4 * u + 3] * w.w;
        }
#pragma unroll
        for (int m = 1; m < 64; m <<= 1) s += __shfl_xor(s, m);
        if (lane == 0) beta[(long)bl * HH + h] = 1.0f / (1.0f + __expf(-s));
    }
}

// ---------------- prep v3: register-LI substitution, direct-global epilogues, 3 blk/CU ----
// LDS: KT/VT [0,32768) | WL [32768,41472) | LIbf [41472,49664) | bv [49664,49920)
__global__ __launch_bounds__(256, 3) void prep_chunk(
    const u16* __restrict__ KN, const u16* __restrict__ VN, const float* __restrict__ BETA,
    u16* __restrict__ LK_g, u16* __restrict__ BKT_g, u16* __restrict__ LV_g)
{
    __shared__ __align__(16) char pm[50176];
    const int bh = blockIdx.x >> 5, q = blockIdx.x & 31;
    const int b = bh >> 2, h = bh & 3;
    const int tid = threadIdx.x;
    const int w = tid >> 6, lane = tid & 63, g = lane >> 4, c = lane & 15;
    const long cb = (long)(bh * 32 + q);
    const long kbase = ((long)b * LL + 64 * q) * DD + h * HD;
    u16* WLp = (u16*)(pm + 32768);
    float* bv = (float*)(pm + 49664);

    // ---- P0: bv + KT build (coalesced column reads -> swizzled b128 LDS writes) ----
    if (tid < 64) bv[tid] = BETA[((long)b * LL + 64 * q + tid) * HH + h];
    {
        const u16* kp = KN + kbase + tid;   // column d = tid
#pragma unroll
        for (int tb = 0; tb < 8; tb++) {
            u16 vals[8];
#pragma unroll
            for (int j = 0; j < 8; j++) vals[j] = kp[(long)(8 * tb + j) * DD];
            *(uint4*)(pm + tid * 128 + ((tb ^ (tid & 7)) << 4)) = *(uint4*)vals;
        }
    }
    __syncthreads();

    // ---- P1: A = K K^T (fragments from global), WL = A*diag(b) ; BKT out ----
    {
        f32x4 aacc[4];
#pragma unroll
        for (int nt = 0; nt < 4; nt++) aacc[nt] = (f32x4){0.f, 0.f, 0.f, 0.f};
#pragma unroll
        for (int q8 = 0; q8 < 8; q8++) {
            short8 af = *(const short8*)(KN + kbase + (long)(16 * w + c) * DD + 32 * q8 + 8 * g);
#pragma unroll
            for (int nt = 0; nt < 4; nt++) {
                short8 bf = *(const short8*)(KN + kbase + (long)(16 * nt + c) * DD + 32 * q8 + 8 * g);
                aacc[nt] = __builtin_amdgcn_mfma_f32_16x16x32_bf16(af, bf, aacc[nt], 0, 0, 0);
            }
        }
#pragma unroll
        for (int nt = 0; nt < 4; nt++)
#pragma unroll
            for (int r = 0; r < 4; r++)
                WLp[(16 * w + 4 * g + r) * 68 + 16 * nt + c] = f2bf(aacc[nt][r] * bv[16 * nt + c]);
    }
    // BKT: scale KT columns by b_t, vector-coalesced global store (independent work)
    for (int ii = tid; ii < 2048; ii += 256) {
        int d = ii >> 3, bl = ii & 7;
        u16 vals[8];
        *(uint4*)vals = *(const uint4*)(pm + d * 128 + bl * 16);
        int t0 = (bl ^ (d & 7)) << 3;
#pragma unroll
        for (int j = 0; j < 8; j++) vals[j] = f2bf(bf2f(vals[j]) * bv[t0 + j]);
        *(uint4*)((char*)(BKT_g + cb * 16384) + d * 128 + bl * 16) = *(uint4*)vals;
    }
    __syncthreads();

    // ---- P2: register-resident forward substitution ----
    // lane (g,c) of wave w holds LI[s][16w+c] for s = 4u+g (u = 0..15)
    {
        const int col = 16 * w + c;
        float li[16];
#pragma unroll
        for (int u = 0; u < 16; u++) li[u] = (4 * u + g == col) ? 1.0f : 0.0f;
#pragma unroll
        for (int t = 1; t < 64; t++) {
            float acc = 0.f;
#pragma unroll
            for (int u = 0; u <= (t - 1) / 4; u++) {
                int s = 4 * u + g;
                if (s < t) acc += bf2f(WLp[t * 68 + s]) * li[u];
            }
            acc += __shfl_xor(acc, 16);
            acc += __shfl_xor(acc, 32);
            float val = ((t == col) ? 1.0f : 0.0f) - acc;
            if ((t & 3) == g) li[t >> 2] = val;
        }
        // write LIbf [t rows][s cols] swizzled: our li[u] = Linv[4u+g][col] -> row 4u+g, col 'col'
#pragma unroll
        for (int u = 0; u < 16; u++) {
            int s = 4 * u + g;
            *(u16*)(pm + 41472 + s * 128 + ((((col >> 3) ^ (s & 7)) << 4) + (col & 7) * 2)) =
                f2bf(li[u]);
        }
    }
    __syncthreads();

    // ---- P3: LK' = -Linv*K, m=t (A=LIbf, B=KT), direct global scalar stores ----
    {
        f32x4 lk[4][4];  // [mt][dn]
#pragma unroll
        for (int i = 0; i < 4; i++)
#pragma unroll
            for (int j = 0; j < 4; j++) lk[i][j] = (f32x4){0.f, 0.f, 0.f, 0.f};
#pragma unroll
        for (int qs = 0; qs < 2; qs++) {
            short8 aL[4], bK[4];
#pragma unroll
            for (int mt = 0; mt < 4; mt++)
                aL[mt] = *(const short8*)(pm + 41472 + (16 * mt + c) * 128 +
                                          (((qs * 4 + g) ^ (c & 7)) << 4));
#pragma unroll
            for (int dn = 0; dn < 4; dn++)
                bK[dn] = *(const short8*)(pm + (64 * w + 16 * dn + c) * 128 +
                                          (((qs * 4 + g) ^ (c & 7)) << 4));
#pragma unroll
            for (int mt = 0; mt < 4; mt++)
#pragma unroll
                for (int dn = 0; dn < 4; dn++)
                    lk[mt][dn] = __builtin_amdgcn_mfma_f32_16x16x32_bf16(aL[mt], bK[dn], lk[mt][dn], 0, 0, 0);
        }
        char* lkg = (char*)(LK_g + cb * 16384);
#pragma unroll
        for (int mt = 0; mt < 4; mt++)
#pragma unroll
            for (int dn = 0; dn < 4; dn++)
#pragma unroll
                for (int r = 0; r < 4; r++) {
                    int t = 16 * mt + 4 * g + r;
                    int d = 64 * w + 16 * dn + c;
                    *(u16*)(lkg + t * 512 + ((((d >> 3) ^ (t & 7)) << 4) + (d & 7) * 2)) =
                        f2bf(-lk[mt][dn][r]);
                }
    }
    __syncthreads();

    // ---- P4: VT build (overwrites KT) ----
    {
        const u16* vp = VN + kbase + tid;
#pragma unroll
        for (int tb = 0; tb < 8; tb++) {
            u16 vals[8];
#pragma unroll
            for (int j = 0; j < 8; j++) vals[j] = vp[(long)(8 * tb + j) * DD];
            *(uint4*)(pm + tid * 128 + ((tb ^ (tid & 7)) << 4)) = *(uint4*)vals;
        }
    }
    __syncthreads();

    // ---- P5: LV' = +Linv*V, m=t; direct global coalesced u32 plane stores ----
    {
        f32x4 lv[4][4];
#pragma unroll
        for (int i = 0; i < 4; i++)
#pragma unroll
            for (int j = 0; j < 4; j++) lv[i][j] = (f32x4){0.f, 0.f, 0.f, 0.f};
#pragma unroll
        for (int qs = 0; qs < 2; qs++) {
            short8 aL[4], bV[4];
#pragma unroll
            for (int mt = 0; mt < 4; mt++)
                aL[mt] = *(const short8*)(pm + 41472 + (16 * mt + c) * 128 +
                                          (((qs * 4 + g) ^ (c & 7)) << 4));
#pragma unroll
            for (int dn = 0; dn < 4; dn++)
                bV[dn] = *(const short8*)(pm + (64 * w + 16 * dn + c) * 128 +
                                          (((qs * 4 + g) ^ (c & 7)) << 4));
#pragma unroll
            for (int mt = 0; mt < 4; mt++)
#pragma unroll
                for (int dn = 0; dn < 4; dn++)
                    lv[mt][dn] = __builtin_amdgcn_mfma_f32_16x16x32_bf16(aL[mt], bV[dn], lv[mt][dn], 0, 0, 0);
        }
        u32* lvg = (u32*)LV_g + cb * 8192;
#pragma unroll
        for (int mt = 0; mt < 4; mt++)
#pragma unroll
            for (int dn = 0; dn < 4; dn++) {
                int iblk = 2 * w + (dn >> 1);
                int it = dn & 1;
                int base = iblk * 1024 + 64 * (2 * mt + it) + 16 * g + c;
                lvg[base]       = (u32)f2bf(lv[mt][dn][0]) | ((u32)f2bf(lv[mt][dn][1]) << 16);
                lvg[base + 512] = (u32)f2bf(lv[mt][dn][2]) | ((u32)f2bf(lv[mt][dn][3]) << 16);
            }
    }
}

// ---------------- chunked scan: 8 waves, 2 GEMMs/chunk, all-b128 LDS frags ----------------
__global__ __launch_bounds__(512, 1) void scan_chunked(
    const u16* __restrict__ LK_g, const u16* __restrict__ BKT_g,
    const u16* __restrict__ LV_g, const u16* __restrict__ QN,
    float* __restrict__ out, float* __restrict__ ORAW)
{
    __shared__ __align__(16) char smem[159744];
    const int blk = blockIdx.x;
    const int bh = blk & 31, iblk = blk >> 5;
    const int b = bh >> 2, h = bh & 3;
    const int row0 = iblk * 32;
    const int tid = threadIdx.x;
    const int w = tid >> 6, lane = tid & 63, g = lane >> 4, c = lane & 15;
    const int mt = w >> 1, it = w & 1;
    const int sw = (c & 7) << 4;

#define GLDS16(gp, lofs) __builtin_amdgcn_global_load_lds((const AS1 void*)(gp), \
        (AS3 void*)((AS3 char*)smem + (lofs)), 16, 0, 0)
#define GLDS4(gp, lofs) __builtin_amdgcn_global_load_lds((const AS1 void*)(gp), \
        (AS3 void*)((AS3 char*)smem + (lofs)), 4, 0, 0)
#define STAGE_LK(qq, bi) { const char* gp = (const char*)(LK_g + (long)(bh * 32 + (qq)) * 16384); \
    _Pragma("unroll") for (int i_ = 0; i_ < 4; i_++) GLDS16(gp + i_ * 8192 + tid * 16, (bi) * 32768 + i_ * 8192 + tid * 16); }
#define STAGE_BKT(qq, bi) { const char* gp = (const char*)(BKT_g + (long)(bh * 32 + (qq)) * 16384); \
    _Pragma("unroll") for (int i_ = 0; i_ < 4; i_++) GLDS16(gp + i_ * 8192 + tid * 16, 65536 + (bi) * 32768 + i_ * 8192 + tid * 16); }
#define STAGE_LV(qq, bi) { const char* gp = (const char*)LV_g + (long)(bh * 32 + (qq)) * 32768 + iblk * 4096; \
    GLDS4(gp + tid * 4, 131072 + (bi) * 4096 + tid * 4); \
    GLDS4(gp + 2048 + tid * 4, 131072 + (bi) * 4096 + 2048 + tid * 4); }

    f32x4 S[2][2];
#pragma unroll
    for (int si = 0; si < 2; si++)
#pragma unroll
        for (int sj = 0; sj < 2; sj++) S[si][sj] = (f32x4){0.f, 0.f, 0.f, 0.f};

    STAGE_LK(0, 0); STAGE_BKT(0, 0); STAGE_LV(0, 0);

    for (int q = 0; q < 32; ++q) {
        const int cur = q & 1;
        if (q < 31) {
            STAGE_LK(q + 1, cur ^ 1); STAGE_BKT(q + 1, cur ^ 1); STAGE_LV(q + 1, cur ^ 1);
            asm volatile("s_waitcnt vmcnt(10)" ::: "memory");
        } else {
            asm volatile("s_waitcnt vmcnt(0)" ::: "memory");
        }
        __builtin_amdgcn_s_barrier();   // all waves' cur-buffer loads landed
        __builtin_amdgcn_sched_barrier(0);

        const char* lkb = smem + cur * 32768;
        const char* bkb = smem + 65536 + cur * 32768;
        const char* lvb = smem + 131072 + cur * 4096;

        // ---- W = LK' * S^T + LV' ----
        u32 l0 = *(const u32*)(lvb + tid * 4);
        u32 l1 = *(const u32*)(lvb + 2048 + tid * 4);
        f32x4 w0, w1;
        w0[0] = bf2f((u16)(l0 & 0xffff)); w0[1] = bf2f((u16)(l0 >> 16));
        w0[2] = bf2f((u16)(l1 & 0xffff)); w0[3] = bf2f((u16)(l1 >> 16));
        w1 = (f32x4){0.f, 0.f, 0.f, 0.f};
        if (q > 0) {
            const int arow = (16 * mt + c) * 512;
            const int brow = (16 * it + c) * 512;
#pragma unroll
            for (int q8 = 0; q8 < 8; q8++) {
                short8 av = *(const short8*)(lkb + arow + (((q8 * 4 + g) << 4) ^ sw));
                short8 bv8 = *(const short8*)(smem + 143360 + brow + (((q8 * 4 + g) << 4) ^ sw));
                if (q8 & 1) w1 = __builtin_amdgcn_mfma_f32_16x16x32_bf16(av, bv8, w1, 0, 0, 0);
                else        w0 = __builtin_amdgcn_mfma_f32_16x16x32_bf16(av, bv8, w0, 0, 0, 0);
            }
#pragma unroll
            for (int r = 0; r < 4; r++) w0[r] += w1[r];
        }

        // ---- all-gather W into WLDS [32 i][64 t] swz ----
        {
            char* ub = smem + 139264 + (16 * it + c) * 128;
#pragma unroll
            for (int r = 0; r < 4; r++) {
                int t = 16 * mt + 4 * g + r;
                *(u16*)(ub + ((((t >> 3) << 4) ^ sw) + (t & 7) * 2)) = f2bf(w0[r]);
            }
        }
        asm volatile("s_waitcnt lgkmcnt(0)" ::: "memory");
        __builtin_amdgcn_s_barrier();
        __builtin_amdgcn_sched_barrier(0);

        // ---- S += W^T * (bK) ----
#pragma unroll
        for (int Qp = 0; Qp < 2; Qp++) {
            const int tof = ((Qp * 4 + g) << 4) ^ sw;
            short8 a0 = *(const short8*)(smem + 139264 + c * 128 + tof);
            short8 a1 = *(const short8*)(smem + 139264 + (16 + c) * 128 + tof);
            short8 b0 = *(const short8*)(bkb + (32 * w + c) * 128 + tof);
            short8 b1 = *(const short8*)(bkb + (32 * w + 16 + c) * 128 + tof);
            S[0][0] = __builtin_amdgcn_mfma_f32_16x16x32_bf16(a0, b0, S[0][0], 0, 0, 0);
            S[0][1] = __builtin_amdgcn_mfma_f32_16x16x32_bf16(a0, b1, S[0][1], 0, 0, 0);
            S[1][0] = __builtin_amdgcn_mfma_f32_16x16x32_bf16(a1, b0, S[1][0], 0, 0, 0);
            S[1][1] = __builtin_amdgcn_mfma_f32_16x16x32_bf16(a1, b1, S[1][1], 0, 0, 0);
        }

        // ---- S -> TS for next chunk ----
        if (q < 31) {
#pragma unroll
            for (int si = 0; si < 2; si++)
#pragma unroll
                for (int sj = 0; sj < 2; sj++)
#pragma unroll
                    for (int r = 0; r < 4; r++) {
                        int i = 16 * si + 4 * g + r;
                        *(u16*)(smem + 143360 + i * 512 +
                                ((((4 * w + 2 * sj + (c >> 3)) << 4) ^ ((i & 7) << 4)) + (c & 7) * 2)) =
                            f2bf(S[si][sj][r]);
                    }
        }
        asm volatile("s_waitcnt lgkmcnt(0)" ::: "memory");
        __builtin_amdgcn_s_barrier();
        __builtin_amdgcn_sched_barrier(0);
    }

    // ---- epilogue ----
    float op[2][4];
#pragma unroll
    for (int si = 0; si < 2; si++)
#pragma unroll
        for (int r = 0; r < 4; r++) op[si][r] = 0.f;
#pragma unroll
    for (int sj = 0; sj < 2; sj++) {
        const float qv = bf2f(QN[((long)b * 4 + 3) * DD + h * HD + 32 * w + 16 * sj + c]);
#pragma unroll
        for (int si = 0; si < 2; si++)
#pragma unroll
            for (int r = 0; r < 4; r++) op[si][r] += S[si][sj][r] * qv;
    }
#pragma unroll
    for (int si = 0; si < 2; si++)
#pragma unroll
        for (int r = 0; r < 4; r++) {
            float v = op[si][r];
            v += __shfl_xor(v, 1); v += __shfl_xor(v, 2);
            v += __shfl_xor(v, 4); v += __shfl_xor(v, 8);
            op[si][r] = v;
        }
    float* red = (float*)smem;
    if (c == 0) {
#pragma unroll
        for (int si = 0; si < 2; si++)
#pragma unroll
            for (int r = 0; r < 4; r++) red[w * 32 + 16 * si + 4 * g + r] = op[si][r];
    }
    __syncthreads();
    if (tid < 32) {
        float o = 0.f;
#pragma unroll
        for (int ww = 0; ww < 8; ww++) o += red[ww * 32 + tid];
        ORAW[(long)b * DD + h * HD + row0 + tid] = o;
    }
#pragma unroll
    for (int si = 0; si < 2; si++)
#pragma unroll
        for (int sj = 0; sj < 2; sj++)
#pragma unroll
            for (int r = 0; r < 4; r++)
                out[8192 + ((long)(bh * 256 + row0 + 16 * si + 4 * g + r)) * 256
                    + 32 * w + 16 * sj + c] = S[si][sj][r];
#undef GLDS16
#undef GLDS4
#undef STAGE_LK
#undef STAGE_BKT
#undef STAGE_LV
}

// ---------------- RMSNorm ----------------
__global__ __launch_bounds__(256) void rmsnorm_kernel(const float* __restrict__ o_raw,
                                                      const float* __restrict__ w,
                                                      float* __restrict__ o_norm) {
    int b = blockIdx.x, t = threadIdx.x;
    float4 v = *(const float4*)(o_raw + (long)b * DD + t * 4);
    float ss = v.x * v.x + v.y * v.y + v.z * v.z + v.w * v.w;
#pragma unroll
    for (int m = 1; m < 64; m <<= 1) ss += __shfl_xor(ss, m);
    __shared__ float wsum[4];
    if ((t & 63) == 0) wsum[t >> 6] = ss;
    __syncthreads();
    float tot = wsum[0] + wsum[1] + wsum[2] + wsum[3];
    float sc = rsqrtf(tot / (float)DD + 1e-5f);
    float4 wv = *(const float4*)(w + t * 4);
    float4 r = make_float4(v.x * sc * wv.x, v.y * sc * wv.y, v.z * sc * wv.z, v.w * sc * wv.w);
    *(float4*)(o_norm + (long)b * DD + t * 4) = r;
}

// ---------------- out projection ----------------
__global__ __launch_bounds__(256) void outproj_kernel(const float* __restrict__ o_norm,
                                                      const float* __restrict__ Wout,
                                                      float* __restrict__ out) {
    int gid = blockIdx.x * 4 + (threadIdx.x >> 6);
    int lane = threadIdx.x & 63;
    int b = gid >> 10, n = gid & 1023;
    const float* orow = o_norm + (long)b * DD + lane * 16;
    const float* wrow = Wout + (long)n * DD + lane * 16;
    float s = 0.f;
#pragma unroll
    for (int u = 0; u < 4; u++) {
        float4 a = *(const float4*)(orow + u * 4);
        float4 w = *(const float4*)(wrow + u * 4);
        s += a.x * w.x + a.y * w.y + a.z * w.z + a.w * w.w;
    }
#pragma unroll
    for (int m = 1; m < 64; m <<= 1) s += __shfl_xor(s, m);
    if (lane == 0) out[(long)b * DD + n] = s;
}

extern "C" void kernel_launch(void* const* d_in, const int* in_sizes, int n_in,
                              void* d_out, int out_size, void* d_ws, size_t ws_size,
                              hipStream_t stream) {
    const float* x     = (const float*)d_in[0];
    const float* Wq    = (const float*)d_in[1];
    const float* Wk    = (const float*)d_in[2];
    const float* Wv    = (const float*)d_in[3];
    const float* cq    = (const float*)d_in[4];
    const float* ck    = (const float*)d_in[5];
    const float* cv    = (const float*)d_in[6];
    const float* Wbeta = (const float*)d_in[7];
    const float* rms_w = (const float*)d_in[8];
    const float* Wout  = (const float*)d_in[9];
    float* out = (float*)d_out;

    char* ws = (char*)d_ws;
    u16* XB     = (u16*)(ws + 0);           // 32 MB (dead after gemm+beta)
    u16* BKT_g  = (u16*)(ws + 0);           // overlays XB
    u16* WKVB   = (u16*)(ws + 33554432);    // 4 MB [Wk;Wv]
    u16* R      = (u16*)(ws + 37748736);    // 64 MB [16384][2048] (dead after convs)
    u16* LK_g   = (u16*)(ws + 37748736);    // overlays R (32 MB)
    u16* LV_g   = (u16*)(ws + 71303168);    // overlays R (32 MB)
    u16* KN     = (u16*)(ws + 104857600);   // 32 MB
    u16* VN     = (u16*)(ws + 138412032);   // 32 MB
    float* BETA = (float*)(ws + 171966464); // 256 KB
    u16* RQ     = (u16*)(ws + 172228608);   // 64 KB
    u16* QN     = (u16*)(ws + 172294144);   // 64 KB
    float* ORAW = (float*)(ws + 172359680); // 32 KB
    float* ONRM = (float*)(ws + 172392448); // 32 KB

    cvt_bf16<<<8192, 256, 0, stream>>>(x, XB, 16777216);
    cvt_bf16<<<512, 256, 0, stream>>>(Wk, WKVB, 1048576);
    cvt_bf16<<<512, 256, 0, stream>>>(Wv, WKVB + 1048576, 1048576);

    // fused k|v projection: C = [16384][2048]
    gemm_bf16<<<dim3(16, 128), 256, 0, stream>>>(XB, WKVB, R, 2048);
    conv_strip<true><<<BB * 64, 256, 0, stream>>>(R, ck, KN, 2048, 0);
    conv_strip<false><<<BB * 64, 256, 0, stream>>>(R, cv, VN, 2048, 1024);
    qraw_gemm<<<8192, 256, 0, stream>>>(x, Wq, RQ);
    conv_silu<true><<<BB, 256, 0, stream>>>(RQ, cq, QN, 4, 3, 1024, 0);
    beta_kernel<<<BB * LL, 64, 0, stream>>>(XB, Wbeta, BETA);

    prep_chunk<<<1024, 256, 0, stream>>>(KN, VN, BETA, LK_g, BKT_g, LV_g);
    scan_chunked<<<256, 512, 0, stream>>>(LK_g, BKT_g, LV_g, QN, out, ORAW);

    rmsnorm_kernel<<<BB, 256, 0, stream>>>(ORAW, rms_w, ONRM);
    outproj_kernel<<<2048, 256, 0, stream>>>(ONRM, Wout, out);
}

// Round 7
// 312.665 us; speedup vs baseline: 5.1086x; 1.0457x over previous
//
#include <hip/hip_runtime.h>

#define LL 2048
#define BB 8
#define DD 1024
#define HH 4
#define HD 256

#define AS1 __attribute__((address_space(1)))
#define AS3 __attribute__((address_space(3)))

typedef __attribute__((ext_vector_type(8))) short short8;
typedef __attribute__((ext_vector_type(4))) float f32x4;
typedef unsigned short u16;
typedef unsigned int u32;

static __device__ __forceinline__ u16 f2bf(float f) {
    u32 u = __float_as_uint(f);
    return (u16)((u + 0x7fffu + ((u >> 16) & 1u)) >> 16);
}
static __device__ __forceinline__ float bf2f(u16 v) {
    return __uint_as_float(((u32)v) << 16);
}
static __device__ __forceinline__ float silu_f(float x) { return x / (1.0f + __expf(-x)); }

// ---------------- front: cvt x | cvt Wk | cvt Wv | beta | qraw, one launch ----------------
static __device__ __forceinline__ void cvt8_body(const float* __restrict__ in,
                                                 u16* __restrict__ out, int blk, int n) {
    int i = (blk * 256 + (int)threadIdx.x) * 8;
    if (i >= n) return;
    float4 a = *(const float4*)(in + i);
    float4 b = *(const float4*)(in + i + 4);
    uint4 pk;
    pk.x = (u32)f2bf(a.x) | ((u32)f2bf(a.y) << 16);
    pk.y = (u32)f2bf(a.z) | ((u32)f2bf(a.w) << 16);
    pk.z = (u32)f2bf(b.x) | ((u32)f2bf(b.y) << 16);
    pk.w = (u32)f2bf(b.z) | ((u32)f2bf(b.w) << 16);
    *(uint4*)(out + i) = pk;
}

__global__ __launch_bounds__(256) void front_kernel(
    const float* __restrict__ x, const float* __restrict__ Wk, const float* __restrict__ Wv,
    const float* __restrict__ Wbeta, const float* __restrict__ Wq,
    u16* __restrict__ XB, u16* __restrict__ WKVB, float* __restrict__ BETA,
    u16* __restrict__ RQ)
{
    const int blk = blockIdx.x;
    const int tid = threadIdx.x;
    if (blk < 8192) {                       // x -> bf16
        cvt8_body(x, XB, blk, 16777216);
    } else if (blk < 8704) {                // Wk -> bf16
        cvt8_body(Wk, WKVB, blk - 8192, 1048576);
    } else if (blk < 9216) {                // Wv -> bf16
        cvt8_body(Wv, WKVB + 1048576, blk - 8704, 1048576);
    } else if (blk < 13312) {               // beta: 4 rows/block, wave per (b,l)
        const int row = (blk - 9216) * 4 + (tid >> 6);
        const int lane = tid & 63;
        const float* xr = x + (long)row * DD + lane * 16;
        float4 xv[4];
#pragma unroll
        for (int u = 0; u < 4; u++) xv[u] = *(const float4*)(xr + u * 4);
#pragma unroll
        for (int h = 0; h < 4; h++) {
            const float* wr = Wbeta + (long)h * DD + lane * 16;
            float s = 0.f;
#pragma unroll
            for (int u = 0; u < 4; u++) {
                float4 w = *(const float4*)(wr + u * 4);
                s += xv[u].x * w.x + xv[u].y * w.y + xv[u].z * w.z + xv[u].w * w.w;
            }
#pragma unroll
            for (int m = 1; m < 64; m <<= 1) s += __shfl_xor(s, m);
            if (lane == 0) BETA[(long)row * HH + h] = 1.0f / (1.0f + __expf(-s));
        }
    } else {                                // qraw: rows l = L-4..L-1
        const int gid = (blk - 13312) * 4 + (tid >> 6);
        const int lane = tid & 63;
        const int m = gid >> 10;
        const int n = gid & 1023;
        const int b = m >> 2, j = m & 3;
        const int l = LL - 4 + j;
        const float* xr = x + ((long)b * LL + l) * DD + lane * 16;
        const float* wr = Wq + (long)n * DD + lane * 16;
        float s = 0.f;
#pragma unroll
        for (int u = 0; u < 4; u++) {
            float4 a = *(const float4*)(xr + u * 4);
            float4 w = *(const float4*)(wr + u * 4);
            s += a.x * w.x + a.y * w.y + a.z * w.z + a.w * w.w;
        }
#pragma unroll
        for (int mm = 1; mm < 64; mm <<= 1) s += __shfl_xor(s, mm);
        if (lane == 0) RQ[(long)m * DD + n] = f2bf(s);
    }
}

// ---------------- m97-style 128x128 LDS GEMM, bf16 in, bf16 out ----------------
__global__ __launch_bounds__(256, 2) void gemm_bf16(const u16* __restrict__ A,
                                                    const u16* __restrict__ W,
                                                    u16* __restrict__ C, int ldc) {
    __shared__ __align__(16) u16 sm[32768];  // 64 KB: 2 bufs x (A 16KB + B 16KB)
    const int tid = threadIdx.x;
    const int w = tid >> 6, lane = tid & 63, g = lane >> 4, c = lane & 15;
    const int m0 = blockIdx.y * 128, n0 = blockIdx.x * 128;
    const int wm = (w >> 1) * 64, wn = (w & 1) * 64;

    f32x4 acc[4][4];
#pragma unroll
    for (int i = 0; i < 4; i++)
#pragma unroll
        for (int j = 0; j < 4; j++) acc[i][j] = (f32x4){0.f, 0.f, 0.f, 0.f};

    const int sr = tid >> 3;
    const int cb = (tid & 7) * 16;

#define GLDSG(gp, lofs) __builtin_amdgcn_global_load_lds((const AS1 void*)(gp), \
        (AS3 void*)((AS3 char*)(char*)sm + (lofs)), 16, 0, 0)

#define GSTAGE(kt, bi)                                                        \
    {                                                                         \
        const char* ab = (const char*)(A + (long)m0 * DD + (kt) * 64);        \
        const char* wb = (const char*)(W + (long)n0 * DD + (kt) * 64);        \
        _Pragma("unroll")                                                     \
        for (int i = 0; i < 4; i++) {                                         \
            int r = i * 32 + sr;                                              \
            int so = r * 2048 + (cb ^ ((r & 7) << 4));                        \
            int dof = (bi) * 32768 + i * 4096 + tid * 16;                     \
            GLDSG(ab + so, dof);                                              \
            GLDSG(wb + so, dof + 16384);                                      \
        }                                                                     \
    }

    GSTAGE(0, 0);
    __syncthreads();

    const int sw = (c & 7) << 4;
    for (int kt = 0; kt < 16; kt++) {
        const int bi = kt & 1;
        if (kt < 15) GSTAGE(kt + 1, bi ^ 1);
        const int ba = bi * 32768;
#pragma unroll
        for (int ks = 0; ks < 2; ks++) {
            short8 av[4], bvv[4];
#pragma unroll
            for (int mt = 0; mt < 4; mt++)
                av[mt] = *(const short8*)((const char*)sm + ba +
                         (wm + 16 * mt + c) * 128 + ((ks * 64 + g * 16) ^ sw));
#pragma unroll
            for (int nt = 0; nt < 4; nt++)
                bvv[nt] = *(const short8*)((const char*)sm + ba + 16384 +
                          (wn + 16 * nt + c) * 128 + ((ks * 64 + g * 16) ^ sw));
#pragma unroll
            for (int mt = 0; mt < 4; mt++)
#pragma unroll
                for (int nt = 0; nt < 4; nt++)
                    acc[mt][nt] = __builtin_amdgcn_mfma_f32_16x16x32_bf16(av[mt], bvv[nt], acc[mt][nt], 0, 0, 0);
        }
        __syncthreads();
    }

#pragma unroll
    for (int mt = 0; mt < 4; mt++)
#pragma unroll
        for (int nt = 0; nt < 4; nt++)
#pragma unroll
            for (int r = 0; r < 4; r++)
                C[(long)(m0 + wm + 16 * mt + 4 * g + r) * ldc + n0 + wn + 16 * nt + c] =
                    f2bf(acc[mt][nt][r]);
#undef GSTAGE
#undef GLDSG
}

// ---------------- conv_all: k-strip | v-strip | q tail, one launch ----------------
__global__ __launch_bounds__(256) void conv_all(const u16* __restrict__ R,
                                                const float* __restrict__ ck,
                                                const float* __restrict__ cv,
                                                const float* __restrict__ cq,
                                                const u16* __restrict__ RQ,
                                                u16* __restrict__ KN,
                                                u16* __restrict__ VN,
                                                u16* __restrict__ QN) {
    const int blk = blockIdx.x;
    const int t = threadIdx.x;
    const int d = t * 4;

    if (blk < 1024) {
        const bool norm = blk < 512;
        const int sb = norm ? blk : blk - 512;
        const int b = sb >> 6;
        const int l0 = (sb & 63) * 32;
        const float* cw = norm ? ck : cv;
        u16* out = norm ? KN : VN;
        const int ioff = norm ? 0 : 1024;

        float w0[4], w1[4], w2[4], w3[4];
        const float4* cw4 = (const float4*)cw;
        *(float4*)w0 = cw4[d + 0];
        *(float4*)w1 = cw4[d + 1];
        *(float4*)w2 = cw4[d + 2];
        *(float4*)w3 = cw4[d + 3];

        const u16* base = R + (long)b * LL * 2048 + ioff + d;
        u16* ob = out + ((long)b * LL) * DD + d;

#define DEC(r) ({ uint2 v_ = *(const uint2*)(base + (long)(r) * 2048); \
    make_float4(bf2f((u16)(v_.x & 0xffff)), bf2f((u16)(v_.x >> 16)), \
                bf2f((u16)(v_.y & 0xffff)), bf2f((u16)(v_.y >> 16))); })

        float4 a1, a2, a3;
        if (l0 == 0) {
            a1 = make_float4(0.f, 0.f, 0.f, 0.f); a2 = a1; a3 = a1;
        } else {
            a1 = DEC(l0 - 3); a2 = DEC(l0 - 2); a3 = DEC(l0 - 1);
        }

#pragma unroll 2
        for (int i = 0; i < 32; i++) {
            const int l = l0 + i;
            float4 xx = DEC(l);
            float y0 = a1.x * w0[0] + a2.x * w0[1] + a3.x * w0[2] + xx.x * w0[3];
            float y1 = a1.y * w1[0] + a2.y * w1[1] + a3.y * w1[2] + xx.y * w1[3];
            float y2 = a1.z * w2[0] + a2.z * w2[1] + a3.z * w2[2] + xx.z * w2[3];
            float y3 = a1.w * w3[0] + a2.w * w3[1] + a3.w * w3[2] + xx.w * w3[3];
            y0 = silu_f(silu_f(y0)); y1 = silu_f(silu_f(y1));
            y2 = silu_f(silu_f(y2)); y3 = silu_f(silu_f(y3));
            if (norm) {
                float ss = y0 * y0 + y1 * y1 + y2 * y2 + y3 * y3;
#pragma unroll
                for (int m = 1; m < 64; m <<= 1) ss += __shfl_xor(ss, m);
                float sc = 1.0f / fmaxf(sqrtf(ss), 1e-12f);
                y0 *= sc; y1 *= sc; y2 *= sc; y3 *= sc;
            }
            uint2 o;
            o.x = (u32)f2bf(y0) | ((u32)f2bf(y1) << 16);
            o.y = (u32)f2bf(y2) | ((u32)f2bf(y3) << 16);
            *(uint2*)(ob + (long)l * DD) = o;
            a1 = a2; a2 = a3; a3 = xx;
        }
#undef DEC
    } else {
        // q tail: b = blk-1024, conv at l=3 over RQ [32][1024] (rows b*4..b*4+3)
        const int b = blk - 1024;
        float w0[4], w1[4], w2[4], w3[4];
        const float4* cw4 = (const float4*)cq;
        *(float4*)w0 = cw4[d + 0];
        *(float4*)w1 = cw4[d + 1];
        *(float4*)w2 = cw4[d + 2];
        *(float4*)w3 = cw4[d + 3];
        const u16* base = RQ + (long)b * 4 * DD + d;
        float a0 = 0.f, a1 = 0.f, a2 = 0.f, a3 = 0.f;
#pragma unroll
        for (int j = 0; j < 4; j++) {
            uint2 v = *(const uint2*)(base + (long)j * DD);
            a0 += bf2f((u16)(v.x & 0xffff)) * w0[j];
            a1 += bf2f((u16)(v.x >> 16)) * w1[j];
            a2 += bf2f((u16)(v.y & 0xffff)) * w2[j];
            a3 += bf2f((u16)(v.y >> 16)) * w3[j];
        }
        float y0 = silu_f(silu_f(a0));
        float y1 = silu_f(silu_f(a1));
        float y2 = silu_f(silu_f(a2));
        float y3 = silu_f(silu_f(a3));
        float ss = y0 * y0 + y1 * y1 + y2 * y2 + y3 * y3;
#pragma unroll
        for (int m = 1; m < 64; m <<= 1) ss += __shfl_xor(ss, m);
        float sc = 1.0f / fmaxf(sqrtf(ss), 1e-12f);
        y0 *= sc; y1 *= sc; y2 *= sc; y3 *= sc;
        uint2 o;
        o.x = (u32)f2bf(y0) | ((u32)f2bf(y1) << 16);
        o.y = (u32)f2bf(y2) | ((u32)f2bf(y3) << 16);
        *(uint2*)(QN + ((long)b * 4 + 3) * DD + d) = o;
    }
}

// ---------------- prep v3: register-LI substitution, direct-global epilogues, 3 blk/CU ----
__global__ __launch_bounds__(256, 3) void prep_chunk(
    const u16* __restrict__ KN, const u16* __restrict__ VN, const float* __restrict__ BETA,
    u16* __restrict__ LK_g, u16* __restrict__ BKT_g, u16* __restrict__ LV_g)
{
    __shared__ __align__(16) char pm[50176];
    const int bh = blockIdx.x >> 5, q = blockIdx.x & 31;
    const int b = bh >> 2, h = bh & 3;
    const int tid = threadIdx.x;
    const int w = tid >> 6, lane = tid & 63, g = lane >> 4, c = lane & 15;
    const long cb = (long)(bh * 32 + q);
    const long kbase = ((long)b * LL + 64 * q) * DD + h * HD;
    u16* WLp = (u16*)(pm + 32768);
    float* bv = (float*)(pm + 49664);

    // ---- P0: bv + KT build ----
    if (tid < 64) bv[tid] = BETA[((long)b * LL + 64 * q + tid) * HH + h];
    {
        const u16* kp = KN + kbase + tid;
#pragma unroll
        for (int tb = 0; tb < 8; tb++) {
            u16 vals[8];
#pragma unroll
            for (int j = 0; j < 8; j++) vals[j] = kp[(long)(8 * tb + j) * DD];
            *(uint4*)(pm + tid * 128 + ((tb ^ (tid & 7)) << 4)) = *(uint4*)vals;
        }
    }
    __syncthreads();

    // ---- P1: A = K K^T, WL = A*diag(b) ; BKT out ----
    {
        f32x4 aacc[4];
#pragma unroll
        for (int nt = 0; nt < 4; nt++) aacc[nt] = (f32x4){0.f, 0.f, 0.f, 0.f};
#pragma unroll
        for (int q8 = 0; q8 < 8; q8++) {
            short8 af = *(const short8*)(KN + kbase + (long)(16 * w + c) * DD + 32 * q8 + 8 * g);
#pragma unroll
            for (int nt = 0; nt < 4; nt++) {
                short8 bf = *(const short8*)(KN + kbase + (long)(16 * nt + c) * DD + 32 * q8 + 8 * g);
                aacc[nt] = __builtin_amdgcn_mfma_f32_16x16x32_bf16(af, bf, aacc[nt], 0, 0, 0);
            }
        }
#pragma unroll
        for (int nt = 0; nt < 4; nt++)
#pragma unroll
            for (int r = 0; r < 4; r++)
                WLp[(16 * w + 4 * g + r) * 68 + 16 * nt + c] = f2bf(aacc[nt][r] * bv[16 * nt + c]);
    }
    for (int ii = tid; ii < 2048; ii += 256) {
        int d = ii >> 3, bl = ii & 7;
        u16 vals[8];
        *(uint4*)vals = *(const uint4*)(pm + d * 128 + bl * 16);
        int t0 = (bl ^ (d & 7)) << 3;
#pragma unroll
        for (int j = 0; j < 8; j++) vals[j] = f2bf(bf2f(vals[j]) * bv[t0 + j]);
        *(uint4*)((char*)(BKT_g + cb * 16384) + d * 128 + bl * 16) = *(uint4*)vals;
    }
    __syncthreads();

    // ---- P2: register-resident forward substitution ----
    {
        const int col = 16 * w + c;
        float li[16];
#pragma unroll
        for (int u = 0; u < 16; u++) li[u] = (4 * u + g == col) ? 1.0f : 0.0f;
#pragma unroll
        for (int t = 1; t < 64; t++) {
            float acc = 0.f;
#pragma unroll
            for (int u = 0; u <= (t - 1) / 4; u++) {
                int s = 4 * u + g;
                if (s < t) acc += bf2f(WLp[t * 68 + s]) * li[u];
            }
            acc += __shfl_xor(acc, 16);
            acc += __shfl_xor(acc, 32);
            float val = ((t == col) ? 1.0f : 0.0f) - acc;
            if ((t & 3) == g) li[t >> 2] = val;
        }
#pragma unroll
        for (int u = 0; u < 16; u++) {
            int s = 4 * u + g;
            *(u16*)(pm + 41472 + s * 128 + ((((col >> 3) ^ (s & 7)) << 4) + (col & 7) * 2)) =
                f2bf(li[u]);
        }
    }
    __syncthreads();

    // ---- P3: LK' = -Linv*K, direct global stores ----
    {
        f32x4 lk[4][4];
#pragma unroll
        for (int i = 0; i < 4; i++)
#pragma unroll
            for (int j = 0; j < 4; j++) lk[i][j] = (f32x4){0.f, 0.f, 0.f, 0.f};
#pragma unroll
        for (int qs = 0; qs < 2; qs++) {
            short8 aL[4], bK[4];
#pragma unroll
            for (int mt = 0; mt < 4; mt++)
                aL[mt] = *(const short8*)(pm + 41472 + (16 * mt + c) * 128 +
                                          (((qs * 4 + g) ^ (c & 7)) << 4));
#pragma unroll
            for (int dn = 0; dn < 4; dn++)
                bK[dn] = *(const short8*)(pm + (64 * w + 16 * dn + c) * 128 +
                                          (((qs * 4 + g) ^ (c & 7)) << 4));
#pragma unroll
            for (int mt = 0; mt < 4; mt++)
#pragma unroll
                for (int dn = 0; dn < 4; dn++)
                    lk[mt][dn] = __builtin_amdgcn_mfma_f32_16x16x32_bf16(aL[mt], bK[dn], lk[mt][dn], 0, 0, 0);
        }
        char* lkg = (char*)(LK_g + cb * 16384);
#pragma unroll
        for (int mt = 0; mt < 4; mt++)
#pragma unroll
            for (int dn = 0; dn < 4; dn++)
#pragma unroll
                for (int r = 0; r < 4; r++) {
                    int t = 16 * mt + 4 * g + r;
                    int d = 64 * w + 16 * dn + c;
                    *(u16*)(lkg + t * 512 + ((((d >> 3) ^ (t & 7)) << 4) + (d & 7) * 2)) =
                        f2bf(-lk[mt][dn][r]);
                }
    }
    __syncthreads();

    // ---- P4: VT build (overwrites KT) ----
    {
        const u16* vp = VN + kbase + tid;
#pragma unroll
        for (int tb = 0; tb < 8; tb++) {
            u16 vals[8];
#pragma unroll
            for (int j = 0; j < 8; j++) vals[j] = vp[(long)(8 * tb + j) * DD];
            *(uint4*)(pm + tid * 128 + ((tb ^ (tid & 7)) << 4)) = *(uint4*)vals;
        }
    }
    __syncthreads();

    // ---- P5: LV' = +Linv*V, direct global coalesced u32 plane stores ----
    {
        f32x4 lv[4][4];
#pragma unroll
        for (int i = 0; i < 4; i++)
#pragma unroll
            for (int j = 0; j < 4; j++) lv[i][j] = (f32x4){0.f, 0.f, 0.f, 0.f};
#pragma unroll
        for (int qs = 0; qs < 2; qs++) {
            short8 aL[4], bV[4];
#pragma unroll
            for (int mt = 0; mt < 4; mt++)
                aL[mt] = *(const short8*)(pm + 41472 + (16 * mt + c) * 128 +
                                          (((qs * 4 + g) ^ (c & 7)) << 4));
#pragma unroll
            for (int dn = 0; dn < 4; dn++)
                bV[dn] = *(const short8*)(pm + (64 * w + 16 * dn + c) * 128 +
                                          (((qs * 4 + g) ^ (c & 7)) << 4));
#pragma unroll
            for (int mt = 0; mt < 4; mt++)
#pragma unroll
                for (int dn = 0; dn < 4; dn++)
                    lv[mt][dn] = __builtin_amdgcn_mfma_f32_16x16x32_bf16(aL[mt], bV[dn], lv[mt][dn], 0, 0, 0);
        }
        u32* lvg = (u32*)LV_g + cb * 8192;
#pragma unroll
        for (int mt = 0; mt < 4; mt++)
#pragma unroll
            for (int dn = 0; dn < 4; dn++) {
                int iblk = 2 * w + (dn >> 1);
                int it = dn & 1;
                int base = iblk * 1024 + 64 * (2 * mt + it) + 16 * g + c;
                lvg[base]       = (u32)f2bf(lv[mt][dn][0]) | ((u32)f2bf(lv[mt][dn][1]) << 16);
                lvg[base + 512] = (u32)f2bf(lv[mt][dn][2]) | ((u32)f2bf(lv[mt][dn][3]) << 16);
            }
    }
}

// ---------------- chunked scan: 8 waves, 2 GEMMs/chunk, all-b128 LDS frags ----------------
__global__ __launch_bounds__(512, 1) void scan_chunked(
    const u16* __restrict__ LK_g, const u16* __restrict__ BKT_g,
    const u16* __restrict__ LV_g, const u16* __restrict__ QN,
    float* __restrict__ out, float* __restrict__ ORAW)
{
    __shared__ __align__(16) char smem[159744];
    const int blk = blockIdx.x;
    const int bh = blk & 31, iblk = blk >> 5;
    const int b = bh >> 2, h = bh & 3;
    const int row0 = iblk * 32;
    const int tid = threadIdx.x;
    const int w = tid >> 6, lane = tid & 63, g = lane >> 4, c = lane & 15;
    const int mt = w >> 1, it = w & 1;
    const int sw = (c & 7) << 4;

#define GLDS16(gp, lofs) __builtin_amdgcn_global_load_lds((const AS1 void*)(gp), \
        (AS3 void*)((AS3 char*)smem + (lofs)), 16, 0, 0)
#define GLDS4(gp, lofs) __builtin_amdgcn_global_load_lds((const AS1 void*)(gp), \
        (AS3 void*)((AS3 char*)smem + (lofs)), 4, 0, 0)
#define STAGE_LK(qq, bi) { const char* gp = (const char*)(LK_g + (long)(bh * 32 + (qq)) * 16384); \
    _Pragma("unroll") for (int i_ = 0; i_ < 4; i_++) GLDS16(gp + i_ * 8192 + tid * 16, (bi) * 32768 + i_ * 8192 + tid * 16); }
#define STAGE_BKT(qq, bi) { const char* gp = (const char*)(BKT_g + (long)(bh * 32 + (qq)) * 16384); \
    _Pragma("unroll") for (int i_ = 0; i_ < 4; i_++) GLDS16(gp + i_ * 8192 + tid * 16, 65536 + (bi) * 32768 + i_ * 8192 + tid * 16); }
#define STAGE_LV(qq, bi) { const char* gp = (const char*)LV_g + (long)(bh * 32 + (qq)) * 32768 + iblk * 4096; \
    GLDS4(gp + tid * 4, 131072 + (bi) * 4096 + tid * 4); \
    GLDS4(gp + 2048 + tid * 4, 131072 + (bi) * 4096 + 2048 + tid * 4); }

    f32x4 S[2][2];
#pragma unroll
    for (int si = 0; si < 2; si++)
#pragma unroll
        for (int sj = 0; sj < 2; sj++) S[si][sj] = (f32x4){0.f, 0.f, 0.f, 0.f};

    STAGE_LK(0, 0); STAGE_BKT(0, 0); STAGE_LV(0, 0);

    for (int q = 0; q < 32; ++q) {
        const int cur = q & 1;
        if (q < 31) {
            STAGE_LK(q + 1, cur ^ 1); STAGE_BKT(q + 1, cur ^ 1); STAGE_LV(q + 1, cur ^ 1);
            asm volatile("s_waitcnt vmcnt(10)" ::: "memory");
        } else {
            asm volatile("s_waitcnt vmcnt(0)" ::: "memory");
        }
        __builtin_amdgcn_s_barrier();   // all waves' cur-buffer loads landed
        __builtin_amdgcn_sched_barrier(0);

        const char* lkb = smem + cur * 32768;
        const char* bkb = smem + 65536 + cur * 32768;
        const char* lvb = smem + 131072 + cur * 4096;

        // ---- W = LK' * S^T + LV' ----
        u32 l0 = *(const u32*)(lvb + tid * 4);
        u32 l1 = *(const u32*)(lvb + 2048 + tid * 4);
        f32x4 w0, w1;
        w0[0] = bf2f((u16)(l0 & 0xffff)); w0[1] = bf2f((u16)(l0 >> 16));
        w0[2] = bf2f((u16)(l1 & 0xffff)); w0[3] = bf2f((u16)(l1 >> 16));
        w1 = (f32x4){0.f, 0.f, 0.f, 0.f};
        if (q > 0) {
            const int arow = (16 * mt + c) * 512;
            const int brow = (16 * it + c) * 512;
            __builtin_amdgcn_s_setprio(1);
#pragma unroll
            for (int q8 = 0; q8 < 8; q8++) {
                short8 av = *(const short8*)(lkb + arow + (((q8 * 4 + g) << 4) ^ sw));
                short8 bv8 = *(const short8*)(smem + 143360 + brow + (((q8 * 4 + g) << 4) ^ sw));
                if (q8 & 1) w1 = __builtin_amdgcn_mfma_f32_16x16x32_bf16(av, bv8, w1, 0, 0, 0);
                else        w0 = __builtin_amdgcn_mfma_f32_16x16x32_bf16(av, bv8, w0, 0, 0, 0);
            }
            __builtin_amdgcn_s_setprio(0);
#pragma unroll
            for (int r = 0; r < 4; r++) w0[r] += w1[r];
        }

        // ---- all-gather W into WLDS [32 i][64 t] swz ----
        {
            char* ub = smem + 139264 + (16 * it + c) * 128;
#pragma unroll
            for (int r = 0; r < 4; r++) {
                int t = 16 * mt + 4 * g + r;
                *(u16*)(ub + ((((t >> 3) << 4) ^ sw) + (t & 7) * 2)) = f2bf(w0[r]);
            }
        }
        asm volatile("s_waitcnt lgkmcnt(0)" ::: "memory");
        __builtin_amdgcn_s_barrier();
        __builtin_amdgcn_sched_barrier(0);

        // ---- S += W^T * (bK) ----
        __builtin_amdgcn_s_setprio(1);
#pragma unroll
        for (int Qp = 0; Qp < 2; Qp++) {
            const int tof = ((Qp * 4 + g) << 4) ^ sw;
            short8 a0 = *(const short8*)(smem + 139264 + c * 128 + tof);
            short8 a1 = *(const short8*)(smem + 139264 + (16 + c) * 128 + tof);
            short8 b0 = *(const short8*)(bkb + (32 * w + c) * 128 + tof);
            short8 b1 = *(const short8*)(bkb + (32 * w + 16 + c) * 128 + tof);
            S[0][0] = __builtin_amdgcn_mfma_f32_16x16x32_bf16(a0, b0, S[0][0], 0, 0, 0);
            S[0][1] = __builtin_amdgcn_mfma_f32_16x16x32_bf16(a0, b1, S[0][1], 0, 0, 0);
            S[1][0] = __builtin_amdgcn_mfma_f32_16x16x32_bf16(a1, b0, S[1][0], 0, 0, 0);
            S[1][1] = __builtin_amdgcn_mfma_f32_16x16x32_bf16(a1, b1, S[1][1], 0, 0, 0);
        }
        __builtin_amdgcn_s_setprio(0);

        // ---- S -> TS for next chunk ----
        if (q < 31) {
#pragma unroll
            for (int si = 0; si < 2; si++)
#pragma unroll
                for (int sj = 0; sj < 2; sj++)
#pragma unroll
                    for (int r = 0; r < 4; r++) {
                        int i = 16 * si + 4 * g + r;
                        *(u16*)(smem + 143360 + i * 512 +
                                ((((4 * w + 2 * sj + (c >> 3)) << 4) ^ ((i & 7) << 4)) + (c & 7) * 2)) =
                            f2bf(S[si][sj][r]);
                    }
        }
        asm volatile("s_waitcnt lgkmcnt(0)" ::: "memory");
        __builtin_amdgcn_s_barrier();
        __builtin_amdgcn_sched_barrier(0);
    }

    // ---- epilogue ----
    float op[2][4];
#pragma unroll
    for (int si = 0; si < 2; si++)
#pragma unroll
        for (int r = 0; r < 4; r++) op[si][r] = 0.f;
#pragma unroll
    for (int sj = 0; sj < 2; sj++) {
        const float qv = bf2f(QN[((long)b * 4 + 3) * DD + h * HD + 32 * w + 16 * sj + c]);
#pragma unroll
        for (int si = 0; si < 2; si++)
#pragma unroll
            for (int r = 0; r < 4; r++) op[si][r] += S[si][sj][r] * qv;
    }
#pragma unroll
    for (int si = 0; si < 2; si++)
#pragma unroll
        for (int r = 0; r < 4; r++) {
            float v = op[si][r];
            v += __shfl_xor(v, 1); v += __shfl_xor(v, 2);
            v += __shfl_xor(v, 4); v += __shfl_xor(v, 8);
            op[si][r] = v;
        }
    float* red = (float*)smem;
    if (c == 0) {
#pragma unroll
        for (int si = 0; si < 2; si++)
#pragma unroll
            for (int r = 0; r < 4; r++) red[w * 32 + 16 * si + 4 * g + r] = op[si][r];
    }
    __syncthreads();
    if (tid < 32) {
        float o = 0.f;
#pragma unroll
        for (int ww = 0; ww < 8; ww++) o += red[ww * 32 + tid];
        ORAW[(long)b * DD + h * HD + row0 + tid] = o;
    }
#pragma unroll
    for (int si = 0; si < 2; si++)
#pragma unroll
        for (int sj = 0; sj < 2; sj++)
#pragma unroll
            for (int r = 0; r < 4; r++)
                out[8192 + ((long)(bh * 256 + row0 + 16 * si + 4 * g + r)) * 256
                    + 32 * w + 16 * sj + c] = S[si][sj][r];
#undef GLDS16
#undef GLDS4
#undef STAGE_LK
#undef STAGE_BKT
#undef STAGE_LV
}

// ---------------- tail: rmsnorm + out projection fused ----------------
__global__ __launch_bounds__(256) void tail_kernel(const float* __restrict__ ORAW,
                                                   const float* __restrict__ rms_w,
                                                   const float* __restrict__ Wout,
                                                   float* __restrict__ out) {
    const int b = blockIdx.x >> 8;
    const int n = (blockIdx.x & 255) * 4 + (threadIdx.x >> 6);
    const int lane = threadIdx.x & 63;
    const int t = threadIdx.x;

    // block-wide sum of squares over ORAW[b]
    float4 v = *(const float4*)(ORAW + (long)b * DD + t * 4);
    float ss = v.x * v.x + v.y * v.y + v.z * v.z + v.w * v.w;
#pragma unroll
    for (int m = 1; m < 64; m <<= 1) ss += __shfl_xor(ss, m);
    __shared__ float wsum[4];
    if ((t & 63) == 0) wsum[t >> 6] = ss;
    __syncthreads();
    float tot = wsum[0] + wsum[1] + wsum[2] + wsum[3];
    float sc = rsqrtf(tot / (float)DD + 1e-5f);

    const float* orow = ORAW + (long)b * DD + lane * 16;
    const float* grow = rms_w + lane * 16;
    const float* wrow = Wout + (long)n * DD + lane * 16;
    float s = 0.f;
#pragma unroll
    for (int u = 0; u < 4; u++) {
        float4 a = *(const float4*)(orow + u * 4);
        float4 gw = *(const float4*)(grow + u * 4);
        float4 ww = *(const float4*)(wrow + u * 4);
        s += a.x * sc * gw.x * ww.x + a.y * sc * gw.y * ww.y +
             a.z * sc * gw.z * ww.z + a.w * sc * gw.w * ww.w;
    }
#pragma unroll
    for (int m = 1; m < 64; m <<= 1) s += __shfl_xor(s, m);
    if (lane == 0) out[(long)b * DD + n] = s;
}

extern "C" void kernel_launch(void* const* d_in, const int* in_sizes, int n_in,
                              void* d_out, int out_size, void* d_ws, size_t ws_size,
                              hipStream_t stream) {
    const float* x     = (const float*)d_in[0];
    const float* Wq    = (const float*)d_in[1];
    const float* Wk    = (const float*)d_in[2];
    const float* Wv    = (const float*)d_in[3];
    const float* cq    = (const float*)d_in[4];
    const float* ck    = (const float*)d_in[5];
    const float* cv    = (const float*)d_in[6];
    const float* Wbeta = (const float*)d_in[7];
    const float* rms_w = (const float*)d_in[8];
    const float* Wout  = (const float*)d_in[9];
    float* out = (float*)d_out;

    char* ws = (char*)d_ws;
    u16* XB     = (u16*)(ws + 0);           // 32 MB (dead after gemm)
    u16* BKT_g  = (u16*)(ws + 0);           // overlays XB (prep runs later)
    u16* WKVB   = (u16*)(ws + 33554432);    // 4 MB [Wk;Wv]
    u16* R      = (u16*)(ws + 37748736);    // 64 MB [16384][2048] (dead after convs)
    u16* LK_g   = (u16*)(ws + 37748736);    // overlays R (32 MB)
    u16* LV_g   = (u16*)(ws + 71303168);    // overlays R (32 MB)
    u16* KN     = (u16*)(ws + 104857600);   // 32 MB
    u16* VN     = (u16*)(ws + 138412032);   // 32 MB
    float* BETA = (float*)(ws + 171966464); // 256 KB
    u16* RQ     = (u16*)(ws + 172228608);   // 64 KB
    u16* QN     = (u16*)(ws + 172294144);   // 64 KB
    float* ORAW = (float*)(ws + 172359680); // 32 KB

    // 1: all x-dependent elementwise/GEMV work in one launch
    front_kernel<<<21504, 256, 0, stream>>>(x, Wk, Wv, Wbeta, Wq, XB, WKVB, BETA, RQ);
    // 2: fused k|v projection
    gemm_bf16<<<dim3(16, 128), 256, 0, stream>>>(XB, WKVB, R, 2048);
    // 3: all convs
    conv_all<<<1032, 256, 0, stream>>>(R, ck, cv, cq, RQ, KN, VN, QN);
    // 4: per-chunk WY factors
    prep_chunk<<<1024, 256, 0, stream>>>(KN, VN, BETA, LK_g, BKT_g, LV_g);
    // 5: the recurrence
    scan_chunked<<<256, 512, 0, stream>>>(LK_g, BKT_g, LV_g, QN, out, ORAW);
    // 6: rmsnorm + out projection
    tail_kernel<<<2048, 256, 0, stream>>>(ORAW, rms_w, Wout, out);
}